// Round 1
// baseline (829.525 us; speedup 1.0000x reference)
//
#include <hip/hip_runtime.h>
#include <math.h>

#define EPS 1e-8f
#define C   768
#define HW  4096
#define MT  64          // rows (p) per block
#define NT  64          // cols (q) per block
#define KT  16          // k-slice
#define NTILES (HW / NT)  // 64 q-tiles

// ---------------------------------------------------------------------------
// Kernel 1: per-column norm of b: nb[q] = sqrt(sum_c b[c][q]^2 + EPS) + EPS
// ---------------------------------------------------------------------------
__global__ __launch_bounds__(256) void bnorm_kernel(const float* __restrict__ b,
                                                    float* __restrict__ nb) {
    int q = blockIdx.x * blockDim.x + threadIdx.x;
    if (q >= HW) return;
    float s = 0.f;
#pragma unroll 4
    for (int c = 0; c < C; ++c) {
        float v = b[c * HW + q];   // coalesced across q
        s += v * v;
    }
    nb[q] = sqrtf(s + EPS) + EPS;
}

// ---------------------------------------------------------------------------
// Kernel 2: fused fp32 GEMM (A^T B over c) + per-row argmax within q-tile.
// sim[p][q] = dot(a[:,p], b[:,q]) / nb[q]   (skip /na[p]: row-uniform scale,
// argmax invariant). Writes per-(row, q-tile) partial (best_val, best_idx).
// ---------------------------------------------------------------------------
__global__ __launch_bounds__(256) void gemm_argmax_kernel(
    const float* __restrict__ A, const float* __restrict__ B,
    const float* __restrict__ nb,
    float* __restrict__ pval, int* __restrict__ pidx)
{
    __shared__ float As[KT][MT];
    __shared__ float Bs[KT][NT];
    __shared__ float rv[MT][16];
    __shared__ int   ri[MT][16];

    const int m0 = blockIdx.x * MT;
    const int q0 = blockIdx.y * NT;
    const int tid = threadIdx.x;
    const int tx = tid & 15;        // q-group
    const int ty = tid >> 4;        // p-group

    float acc[4][4] = {};

    for (int k0 = 0; k0 < C; k0 += KT) {
#pragma unroll
        for (int i = 0; i < 4; ++i) {
            int idx = tid + i * 256;          // 0..1023
            int r = idx >> 6, col = idx & 63; // coalesced 64-float rows
            As[r][col] = A[(k0 + r) * HW + m0 + col];
            Bs[r][col] = B[(k0 + r) * HW + q0 + col];
        }
        __syncthreads();
#pragma unroll
        for (int kk = 0; kk < KT; ++kk) {
            float a4[4], b4[4];
#pragma unroll
            for (int i = 0; i < 4; ++i) a4[i] = As[kk][ty * 4 + i];
#pragma unroll
            for (int j = 0; j < 4; ++j) b4[j] = Bs[kk][tx * 4 + j];
#pragma unroll
            for (int i = 0; i < 4; ++i)
#pragma unroll
                for (int j = 0; j < 4; ++j) acc[i][j] += a4[i] * b4[j];
        }
        __syncthreads();
    }

    // divide by nb[q], thread-local argmax per row (q ascending -> strict >
    // keeps lowest q on ties, matching np.argmin first-occurrence)
    float nbv[4];
#pragma unroll
    for (int j = 0; j < 4; ++j) nbv[j] = nb[q0 + tx * 4 + j];

#pragma unroll
    for (int i = 0; i < 4; ++i) {
        float bv = -INFINITY; int bi = 0;
#pragma unroll
        for (int j = 0; j < 4; ++j) {
            float s = acc[i][j] / nbv[j];
            int q = q0 + tx * 4 + j;
            if (s > bv) { bv = s; bi = q; }
        }
        rv[ty * 4 + i][tx] = bv;
        ri[ty * 4 + i][tx] = bi;
    }
    __syncthreads();

    if (tid < MT) {
        float bv = rv[tid][0]; int bi = ri[tid][0];
#pragma unroll
        for (int t = 1; t < 16; ++t) {
            float v = rv[tid][t]; int ii = ri[tid][t];
            if (v > bv || (v == bv && ii < bi)) { bv = v; bi = ii; }
        }
        pval[(m0 + tid) * NTILES + blockIdx.y] = bv;
        pidx[(m0 + tid) * NTILES + blockIdx.y] = bi;
    }
}

// ---------------------------------------------------------------------------
// Kernel 3: reduce per-tile partials -> z_best; write float copy to output.
// ---------------------------------------------------------------------------
__global__ __launch_bounds__(256) void reduce_kernel(
    const float* __restrict__ pval, const int* __restrict__ pidx,
    int* __restrict__ zb, float* __restrict__ out_zbest)
{
    int p = blockIdx.x * blockDim.x + threadIdx.x;
    if (p >= HW) return;
    float bv = pval[p * NTILES]; int bi = pidx[p * NTILES];
#pragma unroll 8
    for (int t = 1; t < NTILES; ++t) {
        float v = pval[p * NTILES + t]; int ii = pidx[p * NTILES + t];
        if (v > bv || (v == bv && ii < bi)) { bv = v; bi = ii; }
    }
    zb[p] = bi;
    out_zbest[p] = (float)bi;
}

// ---------------------------------------------------------------------------
// Kernel 4: gather z_new[c][p] = d[c][zb[p]] and cos-loss reduction.
// loss = mean_p (1 - dot(a,t)/((sqrt(a2)+EPS)*(sqrt(t2)+EPS)))
// ---------------------------------------------------------------------------
__global__ __launch_bounds__(256) void loss_gather_kernel(
    const float* __restrict__ a, const float* __restrict__ d,
    const int* __restrict__ zb, float* __restrict__ out)
{
    int p = blockIdx.x * blockDim.x + threadIdx.x;
    float contrib = 0.f;
    if (p < HW) {
        int q = zb[p];
        float dot = 0.f, a2 = 0.f, t2 = 0.f;
#pragma unroll 4
        for (int c = 0; c < C; ++c) {
            float av = a[c * HW + p];   // coalesced
            float tv = d[c * HW + q];   // gather (row resident in L1/L2)
            dot += av * tv; a2 += av * av; t2 += tv * tv;
            out[1 + c * HW + p] = tv;   // z_new, coalesced
        }
        float cs = dot / ((sqrtf(a2) + EPS) * (sqrtf(t2) + EPS));
        contrib = 1.f - cs;
    }
    __shared__ float red[256];
    red[threadIdx.x] = contrib;
    __syncthreads();
    for (int s = 128; s > 0; s >>= 1) {
        if (threadIdx.x < s) red[threadIdx.x] += red[threadIdx.x + s];
        __syncthreads();
    }
    if (threadIdx.x == 0) atomicAdd(out, red[0] * (1.0f / HW));
}

extern "C" void kernel_launch(void* const* d_in, const int* in_sizes, int n_in,
                              void* d_out, int out_size, void* d_ws, size_t ws_size,
                              hipStream_t stream) {
    const float* a = (const float*)d_in[0];
    const float* b = (const float*)d_in[1];
    const float* d = (const float*)d_in[2];
    float* out = (float*)d_out;

    // workspace layout (~2.1 MB)
    float* nb   = (float*)d_ws;                 // HW floats
    float* pval = nb + HW;                      // HW*NTILES floats
    int*   pidx = (int*)(pval + HW * NTILES);   // HW*NTILES ints
    int*   zb   = pidx + HW * NTILES;           // HW ints

    // zero the loss accumulator (d_out is poisoned before every launch)
    hipMemsetAsync(d_out, 0, sizeof(float), stream);

    bnorm_kernel<<<HW / 256, 256, 0, stream>>>(b, nb);
    gemm_argmax_kernel<<<dim3(HW / MT, HW / NT), 256, 0, stream>>>(a, b, nb, pval, pidx);
    reduce_kernel<<<HW / 256, 256, 0, stream>>>(pval, pidx, zb, out + 1 + (size_t)C * HW);
    loss_gather_kernel<<<HW / 256, 256, 0, stream>>>(a, d, zb, out);
}

// Round 2
// 487.571 us; speedup vs baseline: 1.7013x; 1.7013x over previous
//
#include <hip/hip_runtime.h>
#include <math.h>

#define EPS 1e-8f
#define C   768
#define HW  4096
#define MT  128         // rows (p) per block
#define NT  128         // cols (q) per block
#define KT  8           // k-slice
#define NTILES (HW / NT)  // 32 q-tiles
#define NCH_B 12        // bnorm c-chunks (64 c each)
#define NCH_L 24        // loss c-chunks (32 c each)

// ---------------------------------------------------------------------------
// b-norm partials: nbp[ch][q] = sum over 64 c of b^2
// ---------------------------------------------------------------------------
__global__ __launch_bounds__(256) void bnorm_partial_kernel(
    const float* __restrict__ b, float* __restrict__ nbp)
{
    int q = blockIdx.x * 256 + threadIdx.x;
    int c0 = blockIdx.y * (C / NCH_B);
    float s = 0.f;
#pragma unroll 8
    for (int c = c0; c < c0 + C / NCH_B; ++c) {
        float v = b[c * HW + q];
        s += v * v;
    }
    nbp[blockIdx.y * HW + q] = s;
}

__global__ __launch_bounds__(256) void bnorm_finalize_kernel(
    const float* __restrict__ nbp, float* __restrict__ nb)
{
    int q = blockIdx.x * 256 + threadIdx.x;
    float s = 0.f;
#pragma unroll
    for (int ch = 0; ch < NCH_B; ++ch) s += nbp[ch * HW + q];
    nb[q] = sqrtf(s + EPS) + EPS;
}

// ---------------------------------------------------------------------------
// fused fp32 GEMM (A^T B over c) + per-row argmax within the 128-wide q-tile.
// 128x128 tile, 8x8 per thread. sim = dot / nb[q]  (row-uniform /na[p] skipped)
// ---------------------------------------------------------------------------
__global__ __launch_bounds__(256) void gemm_argmax_kernel(
    const float* __restrict__ A, const float* __restrict__ B,
    const float* __restrict__ nb,
    float* __restrict__ pval, int* __restrict__ pidx)
{
    __shared__ __align__(16) char smem[16384];
    float (*As)[MT] = (float (*)[MT])smem;            // [KT][128]  4 KB
    float (*Bs)[NT] = (float (*)[NT])(smem + 4096);   // [KT][128]  4 KB

    const int m0 = blockIdx.x * MT;
    const int q0 = blockIdx.y * NT;
    const int tid = threadIdx.x;
    const int tx = tid & 15;        // q-group (8 q each)
    const int ty = tid >> 4;        // p-group (8 p each)
    const int lr = tid >> 5;        // staging row 0..7
    const int lc = (tid & 31) * 4;  // staging col (float4)

    float acc[8][8] = {};

    for (int k0 = 0; k0 < C; k0 += KT) {
        *(float4*)&As[lr][lc] = *(const float4*)&A[(k0 + lr) * HW + m0 + lc];
        *(float4*)&Bs[lr][lc] = *(const float4*)&B[(k0 + lr) * HW + q0 + lc];
        __syncthreads();
#pragma unroll
        for (int kk = 0; kk < KT; ++kk) {
            float a8[8], b8[8];
            *(float4*)&a8[0] = *(float4*)&As[kk][ty * 8];
            *(float4*)&a8[4] = *(float4*)&As[kk][ty * 8 + 4];
            *(float4*)&b8[0] = *(float4*)&Bs[kk][tx * 8];
            *(float4*)&b8[4] = *(float4*)&Bs[kk][tx * 8 + 4];
#pragma unroll
            for (int i = 0; i < 8; ++i)
#pragma unroll
                for (int j = 0; j < 8; ++j) acc[i][j] += a8[i] * b8[j];
        }
        __syncthreads();
    }

    // per-thread argmax over its 8 q's per row (q ascending, strict > keeps
    // lowest q on ties = np.argmin first-occurrence)
    float nbv[8];
#pragma unroll
    for (int j = 0; j < 8; ++j) nbv[j] = nb[q0 + tx * 8 + j];

    // reuse LDS for the cross-tx reduction (all compute done: last barrier
    // in the k-loop was after the final tile's FMAs)
    float (*rv)[16] = (float (*)[16])smem;            // [128][16]  8 KB
    int   (*ri)[16] = (int   (*)[16])(smem + 8192);   // [128][16]  8 KB

#pragma unroll
    for (int i = 0; i < 8; ++i) {
        float bv = -INFINITY; int bi = 0;
#pragma unroll
        for (int j = 0; j < 8; ++j) {
            float s = acc[i][j] / nbv[j];
            int q = q0 + tx * 8 + j;
            if (s > bv) { bv = s; bi = q; }
        }
        rv[ty * 8 + i][tx] = bv;
        ri[ty * 8 + i][tx] = bi;
    }
    __syncthreads();

    if (tid < MT) {
        float bv = rv[tid][0]; int bi = ri[tid][0];
#pragma unroll
        for (int t = 1; t < 16; ++t) {
            float v = rv[tid][t]; int ii = ri[tid][t];
            if (v > bv || (v == bv && ii < bi)) { bv = v; bi = ii; }
        }
        pval[(m0 + tid) * NTILES + blockIdx.y] = bv;
        pidx[(m0 + tid) * NTILES + blockIdx.y] = bi;
    }
}

// ---------------------------------------------------------------------------
// reduce per-tile partials -> z_best (int) + float copy into output slot 2
// ---------------------------------------------------------------------------
__global__ __launch_bounds__(256) void reduce_kernel(
    const float* __restrict__ pval, const int* __restrict__ pidx,
    int* __restrict__ zb, float* __restrict__ out_zbest)
{
    int p = blockIdx.x * 256 + threadIdx.x;
    float bv = pval[p * NTILES]; int bi = pidx[p * NTILES];
#pragma unroll 8
    for (int t = 1; t < NTILES; ++t) {
        float v = pval[p * NTILES + t]; int ii = pidx[p * NTILES + t];
        if (v > bv || (v == bv && ii < bi)) { bv = v; bi = ii; }
    }
    zb[p] = bi;
    out_zbest[p] = (float)bi;
}

// ---------------------------------------------------------------------------
// gather z_new + per-(chunk,p) partial dot/a2/t2 for the cos loss
// ---------------------------------------------------------------------------
__global__ __launch_bounds__(256) void gather_partial_kernel(
    const float* __restrict__ a, const float* __restrict__ d,
    const int* __restrict__ zb, float* __restrict__ out,
    float* __restrict__ pdot, float* __restrict__ pa2, float* __restrict__ pt2)
{
    int p = blockIdx.x * 256 + threadIdx.x;
    int ch = blockIdx.y;
    int c0 = ch * (C / NCH_L);
    int q = zb[p];
    float dot = 0.f, a2 = 0.f, t2 = 0.f;
#pragma unroll 8
    for (int c = c0; c < c0 + C / NCH_L; ++c) {
        float av = a[c * HW + p];     // coalesced
        float tv = d[c * HW + q];     // gather (L2-resident)
        dot += av * tv; a2 += av * av; t2 += tv * tv;
        out[1 + c * HW + p] = tv;     // z_new, coalesced
    }
    pdot[ch * HW + p] = dot;
    pa2[ch * HW + p] = a2;
    pt2[ch * HW + p] = t2;
}

__global__ __launch_bounds__(256) void loss_finalize_kernel(
    const float* __restrict__ pdot, const float* __restrict__ pa2,
    const float* __restrict__ pt2, float* __restrict__ out)
{
    int p = blockIdx.x * 256 + threadIdx.x;
    float dot = 0.f, a2 = 0.f, t2 = 0.f;
#pragma unroll
    for (int ch = 0; ch < NCH_L; ++ch) {
        dot += pdot[ch * HW + p];
        a2  += pa2[ch * HW + p];
        t2  += pt2[ch * HW + p];
    }
    // _cos_loss: norm = sqrt(sum) (no eps inside), then /(norm + 1e-8)
    float cs = dot / ((sqrtf(a2) + EPS) * (sqrtf(t2) + EPS));
    float contrib = 1.f - cs;

    __shared__ float red[256];
    red[threadIdx.x] = contrib;
    __syncthreads();
    for (int s = 128; s > 0; s >>= 1) {
        if (threadIdx.x < s) red[threadIdx.x] += red[threadIdx.x + s];
        __syncthreads();
    }
    if (threadIdx.x == 0) atomicAdd(out, red[0] * (1.0f / HW));
}

extern "C" void kernel_launch(void* const* d_in, const int* in_sizes, int n_in,
                              void* d_out, int out_size, void* d_ws, size_t ws_size,
                              hipStream_t stream) {
    const float* a = (const float*)d_in[0];
    const float* b = (const float*)d_in[1];
    const float* d = (const float*)d_in[2];
    float* out = (float*)d_out;

    // workspace layout (~2.5 MB)
    float* nb   = (float*)d_ws;                  // HW
    float* nbp  = nb + HW;                       // NCH_B*HW
    float* pval = nbp + NCH_B * HW;              // HW*NTILES
    int*   pidx = (int*)(pval + HW * NTILES);    // HW*NTILES
    int*   zb   = pidx + HW * NTILES;            // HW
    float* pdot = (float*)(zb + HW);             // NCH_L*HW
    float* pa2  = pdot + NCH_L * HW;             // NCH_L*HW
    float* pt2  = pa2 + NCH_L * HW;              // NCH_L*HW

    // zero the loss accumulator (d_out is poisoned before every launch)
    hipMemsetAsync(d_out, 0, sizeof(float), stream);

    bnorm_partial_kernel<<<dim3(HW / 256, NCH_B), 256, 0, stream>>>(b, nbp);
    bnorm_finalize_kernel<<<HW / 256, 256, 0, stream>>>(nbp, nb);
    gemm_argmax_kernel<<<dim3(HW / MT, HW / NT), 256, 0, stream>>>(a, b, nb, pval, pidx);
    reduce_kernel<<<HW / 256, 256, 0, stream>>>(pval, pidx, zb, out + 1 + (size_t)C * HW);
    gather_partial_kernel<<<dim3(HW / 256, NCH_L), 256, 0, stream>>>(a, d, zb, out, pdot, pa2, pt2);
    loss_finalize_kernel<<<HW / 256, 256, 0, stream>>>(pdot, pa2, pt2, out);
}

// Round 3
// 374.321 us; speedup vs baseline: 2.2161x; 1.3025x over previous
//
#include <hip/hip_runtime.h>
#include <math.h>

#define EPS  1e-8f
#define C    768
#define HW   4096
#define NKB  24           // k-blocks of 32 (C/32)
#define NBN  32           // q-tiles of 128 (HW/128)
#define TAU  0.005f       // scaled-sim margin for fp32 recheck
#define NCH_L 48          // loss/gather c-chunks (16 c each)

typedef float  floatx4 __attribute__((ext_vector_type(4)));
typedef short  shortx8 __attribute__((ext_vector_type(8)));
typedef unsigned short ushort_t;
typedef unsigned int   uint_t;
typedef __attribute__((address_space(1))) uint_t as1_uint;
typedef __attribute__((address_space(3))) uint_t as3_uint;

__device__ __forceinline__ ushort_t f2bf(float v) {
    uint_t u = __float_as_uint(v);
    uint_t r = (u + 0x7FFFu + ((u >> 16) & 1u)) >> 16;   // RNE
    return (ushort_t)r;
}
__device__ __forceinline__ float bf2f(ushort_t h) {
    return __uint_as_float(((uint_t)h) << 16);
}
__device__ __forceinline__ void async_cp16(const ushort_t* g, ushort_t* l) {
    __builtin_amdgcn_global_load_lds((const as1_uint*)g, (as3_uint*)l, 16, 0, 0);
}

// ---------------------------------------------------------------------------
// pack: a,b -> bf16 hi/lo in MFMA-staging layout [kb][p][kk] (kk = c&31).
// Each thread owns one p for 32 consecutive c: registers only, coalesced I/O.
// Also emits b-norm partials (from exact fp32) for free.
// ---------------------------------------------------------------------------
__global__ __launch_bounds__(256) void pack_kernel(
    const float* __restrict__ a, const float* __restrict__ b,
    ushort_t* __restrict__ Ah, ushort_t* __restrict__ Al,
    ushort_t* __restrict__ Bh, ushort_t* __restrict__ Bl,
    float* __restrict__ nbp)
{
    const int tid = threadIdx.x;
    const int p   = blockIdx.x * 256 + tid;
    const int kb  = blockIdx.y;
    const int z   = blockIdx.z;
    const float* src = z ? b : a;
    ushort_t* dh = z ? Bh : Ah;
    ushort_t* dl = z ? Bl : Al;

    ushort_t h[32], l[32];
    float s = 0.f;
#pragma unroll
    for (int r = 0; r < 32; ++r) {
        float v = src[(kb * 32 + r) * HW + p];
        s += v * v;
        ushort_t hh = f2bf(v);
        h[r] = hh;
        l[r] = f2bf(v - bf2f(hh));
    }
    if (z) nbp[kb * HW + p] = s;

    uint_t hw_[16], lw_[16];
#pragma unroll
    for (int w = 0; w < 16; ++w) {
        hw_[w] = (uint_t)h[2 * w] | ((uint_t)h[2 * w + 1] << 16);
        lw_[w] = (uint_t)l[2 * w] | ((uint_t)l[2 * w + 1] << 16);
    }
    uint4* oh = (uint4*)(dh + (size_t)(kb * HW + p) * 32);
    uint4* ol = (uint4*)(dl + (size_t)(kb * HW + p) * 32);
#pragma unroll
    for (int w = 0; w < 4; ++w) {
        oh[w] = make_uint4(hw_[4*w], hw_[4*w+1], hw_[4*w+2], hw_[4*w+3]);
        ol[w] = make_uint4(lw_[4*w], lw_[4*w+1], lw_[4*w+2], lw_[4*w+3]);
    }
}

__global__ __launch_bounds__(256) void bnorm_finalize_kernel(
    const float* __restrict__ nbp, float* __restrict__ nb)
{
    int q = blockIdx.x * 256 + threadIdx.x;
    float s = 0.f;
#pragma unroll
    for (int ch = 0; ch < NKB; ++ch) s += nbp[ch * HW + q];
    nb[q] = sqrtf(s + EPS) + EPS;
}

// ---------------------------------------------------------------------------
// MFMA GEMM (bf16 split: hi*hi + lo*hi + hi*lo) + per-row top-2 over the
// 128-q block. m97 structure: 128x128 tile, 4 waves 2x2, 16x16x32 MFMA,
// global_load_lds width 16.
// ---------------------------------------------------------------------------
__global__ __launch_bounds__(256) void gemm_mfma_kernel(
    const ushort_t* __restrict__ Ah, const ushort_t* __restrict__ Al,
    const ushort_t* __restrict__ Bh, const ushort_t* __restrict__ Bl,
    const float* __restrict__ nb,
    float* __restrict__ pv1, int* __restrict__ pi1,
    float* __restrict__ pv2, int* __restrict__ pi2)
{
    __shared__ __align__(16) char smem[16384];
    ushort_t* sA = (ushort_t*)smem;           // 8 KB: [p_local 0..127][kk 0..31]
    ushort_t* sB = (ushort_t*)(smem + 8192);  // 8 KB

    const int tid  = threadIdx.x;
    const int lane = tid & 63;
    const int wave = tid >> 6;
    const int wm = wave >> 1, wn = wave & 1;
    const int bm = blockIdx.x, bn = blockIdx.y;
    const int l15 = lane & 15, l4 = lane >> 4;

    floatx4 acc[4][4];
#pragma unroll
    for (int i = 0; i < 4; ++i)
#pragma unroll
        for (int j = 0; j < 4; ++j) acc[i][j] = (floatx4){0.f, 0.f, 0.f, 0.f};

    for (int seg = 0; seg < 3; ++seg) {
        const ushort_t* pA = (seg == 1) ? Al : Ah;
        const ushort_t* pB = (seg == 2) ? Bl : Bh;
        for (int kb = 0; kb < NKB; ++kb) {
            const ushort_t* ga = pA + (size_t)(kb * HW + bm * 128) * 32 + tid * 8;
            const ushort_t* gb = pB + (size_t)(kb * HW + bn * 128) * 32 + tid * 8;
            async_cp16(ga,        sA + tid * 8);
            async_cp16(ga + 2048, sA + tid * 8 + 2048);
            async_cp16(gb,        sB + tid * 8);
            async_cp16(gb + 2048, sB + tid * 8 + 2048);
            __syncthreads();
            shortx8 af[4], bf_[4];
#pragma unroll
            for (int i = 0; i < 4; ++i)
                af[i] = *(const shortx8*)&sA[(wm * 4 + i) * 512 + l15 * 32 + l4 * 8];
#pragma unroll
            for (int j = 0; j < 4; ++j)
                bf_[j] = *(const shortx8*)&sB[(wn * 4 + j) * 512 + l15 * 32 + l4 * 8];
#pragma unroll
            for (int i = 0; i < 4; ++i)
#pragma unroll
                for (int j = 0; j < 4; ++j)
                    acc[i][j] = __builtin_amdgcn_mfma_f32_16x16x32_bf16(
                        af[i], bf_[j], acc[i][j], 0, 0, 0);
            __syncthreads();
        }
    }

    // ---- epilogue: scaled sim = acc / nb[q]; per-p top-2 over block's 128 q
    float rnb[4];
#pragma unroll
    for (int j = 0; j < 4; ++j)
        rnb[j] = 1.0f / nb[bn * 128 + wn * 64 + j * 16 + l15];

    float* lv1 = (float*)smem;
    int*   li1 = (int*)(smem + 1024);
    float* lv2 = (float*)(smem + 2048);
    int*   li2 = (int*)(smem + 3072);

#pragma unroll
    for (int i = 0; i < 4; ++i) {
#pragma unroll
        for (int r = 0; r < 4; ++r) {
            float v1 = -INFINITY, v2 = -INFINITY; int i1 = 0, i2 = 0;
#pragma unroll
            for (int j = 0; j < 4; ++j) {
                float sv = acc[i][j][r] * rnb[j];
                int q = bn * 128 + wn * 64 + j * 16 + l15;
                if (sv > v1) { v2 = v1; i2 = i1; v1 = sv; i1 = q; }
                else if (sv > v2) { v2 = sv; i2 = q; }
            }
#pragma unroll
            for (int m = 1; m < 16; m <<= 1) {
                float ov1 = __shfl_xor(v1, m, 64);
                int   oi1 = __shfl_xor(i1, m, 64);
                float ov2 = __shfl_xor(v2, m, 64);
                int   oi2 = __shfl_xor(i2, m, 64);
                if (ov1 > v1 || (ov1 == v1 && oi1 < i1)) {
                    if (v1 > ov2 || (v1 == ov2 && i1 < oi2)) { v2 = v1; i2 = i1; }
                    else { v2 = ov2; i2 = oi2; }
                    v1 = ov1; i1 = oi1;
                } else if (ov1 > v2 || (ov1 == v2 && oi1 < i2)) {
                    v2 = ov1; i2 = oi1;
                }
            }
            if (l15 == 0) {
                int pl = wm * 64 + i * 16 + l4 * 4 + r;
                lv1[pl * 2 + wn] = v1; li1[pl * 2 + wn] = i1;
                lv2[pl * 2 + wn] = v2; li2[pl * 2 + wn] = i2;
            }
        }
    }
    __syncthreads();
    if (tid < 128) {
        float v1 = lv1[tid * 2],     v2 = lv2[tid * 2];
        int   i1 = li1[tid * 2],     i2 = li2[tid * 2];
        float w1 = lv1[tid * 2 + 1], w2 = lv2[tid * 2 + 1];
        int   j1 = li1[tid * 2 + 1], j2 = li2[tid * 2 + 1];
        if (w1 > v1 || (w1 == v1 && j1 < i1)) {
            if (v1 > w2 || (v1 == w2 && i1 < j2)) { v2 = v1; i2 = i1; }
            else { v2 = w2; i2 = j2; }
            v1 = w1; i1 = j1;
        } else if (w1 > v2 || (w1 == v2 && j1 < i2)) {
            v2 = w1; i2 = j1;
        }
        int p = bm * 128 + tid;
        pv1[p * NBN + bn] = v1; pi1[p * NBN + bn] = i1;
        pv2[p * NBN + bn] = v2; pi2[p * NBN + bn] = i2;
    }
}

// merge 32 tile top-2s -> z_best + margin flag
__global__ __launch_bounds__(256) void reduce_top2_kernel(
    const float* __restrict__ pv1, const int* __restrict__ pi1,
    const float* __restrict__ pv2,
    int* __restrict__ zb, float* __restrict__ out_zbest, int* __restrict__ flag)
{
    int p = blockIdx.x * 256 + threadIdx.x;
    float v1 = pv1[p * NBN]; int i1 = pi1[p * NBN];
    float v2 = pv2[p * NBN];
#pragma unroll 8
    for (int t = 1; t < NBN; ++t) {
        float a1 = pv1[p * NBN + t]; int b1 = pi1[p * NBN + t];
        float a2 = pv2[p * NBN + t];
        if (a1 > v1 || (a1 == v1 && b1 < i1)) {
            if (v1 > v2) v2 = v1;
            v1 = a1; i1 = b1;
        } else if (a1 > v2) v2 = a1;
        if (a2 > v2) v2 = a2;
    }
    zb[p] = i1;
    out_zbest[p] = (float)i1;
    flag[p] = (v1 - v2 < TAU) ? 1 : 0;
}

// exact fp32 recheck over the 64 per-tile top-2 candidates of flagged rows
__global__ __launch_bounds__(64) void recheck_kernel(
    const float* __restrict__ a, const float* __restrict__ b,
    const float* __restrict__ nb,
    const int* __restrict__ pi1, const int* __restrict__ pi2,
    const int* __restrict__ flag,
    int* __restrict__ zb, float* __restrict__ out_zbest)
{
    int p = blockIdx.x;
    if (!flag[p]) return;
    int t = threadIdx.x;
    int q = (t & 1) ? pi2[p * NBN + (t >> 1)] : pi1[p * NBN + (t >> 1)];
    float dot = 0.f;
#pragma unroll 8
    for (int c = 0; c < C; ++c)
        dot += a[c * HW + p] * b[c * HW + q];
    float s = dot / nb[q];
#pragma unroll
    for (int m = 1; m < 64; m <<= 1) {
        float os = __shfl_xor(s, m, 64);
        int   oq = __shfl_xor(q, m, 64);
        if (os > s || (os == s && oq < q)) { s = os; q = oq; }
    }
    if (t == 0) { zb[p] = q; out_zbest[p] = (float)q; }
}

// ---------------------------------------------------------------------------
// gather z_new + cos-loss partials / finalize
// ---------------------------------------------------------------------------
__global__ __launch_bounds__(256) void gather_partial_kernel(
    const float* __restrict__ a, const float* __restrict__ d,
    const int* __restrict__ zb, float* __restrict__ out,
    float* __restrict__ pdot, float* __restrict__ pa2, float* __restrict__ pt2)
{
    int p = blockIdx.x * 256 + threadIdx.x;
    int ch = blockIdx.y;
    int c0 = ch * (C / NCH_L);
    int q = zb[p];
    float dot = 0.f, a2 = 0.f, t2 = 0.f;
#pragma unroll
    for (int c = c0; c < c0 + C / NCH_L; ++c) {
        float av = a[c * HW + p];
        float tv = d[c * HW + q];
        dot += av * tv; a2 += av * av; t2 += tv * tv;
        out[1 + c * HW + p] = tv;
    }
    pdot[ch * HW + p] = dot;
    pa2[ch * HW + p] = a2;
    pt2[ch * HW + p] = t2;
}

__global__ __launch_bounds__(256) void loss_finalize_kernel(
    const float* __restrict__ pdot, const float* __restrict__ pa2,
    const float* __restrict__ pt2, float* __restrict__ out)
{
    int p = blockIdx.x * 256 + threadIdx.x;
    float dot = 0.f, a2 = 0.f, t2 = 0.f;
#pragma unroll
    for (int ch = 0; ch < NCH_L; ++ch) {
        dot += pdot[ch * HW + p];
        a2  += pa2[ch * HW + p];
        t2  += pt2[ch * HW + p];
    }
    float cs = dot / ((sqrtf(a2) + EPS) * (sqrtf(t2) + EPS));
    float contrib = 1.f - cs;
    __shared__ float red[256];
    red[threadIdx.x] = contrib;
    __syncthreads();
    for (int s = 128; s > 0; s >>= 1) {
        if (threadIdx.x < s) red[threadIdx.x] += red[threadIdx.x + s];
        __syncthreads();
    }
    if (threadIdx.x == 0) atomicAdd(out, red[0] * (1.0f / HW));
}

// ---------------------------------------------------------------------------
// fallback fp32 path (used only if ws too small for the bf16 packs)
// ---------------------------------------------------------------------------
__global__ __launch_bounds__(256) void bnorm_partial_fb_kernel(
    const float* __restrict__ b, float* __restrict__ nbp)
{
    int q = blockIdx.x * 256 + threadIdx.x;
    int c0 = blockIdx.y * 32;
    float s = 0.f;
#pragma unroll 8
    for (int c = c0; c < c0 + 32; ++c) { float v = b[c * HW + q]; s += v * v; }
    nbp[blockIdx.y * HW + q] = s;
}

__global__ __launch_bounds__(256) void gemm_argmax_fb_kernel(
    const float* __restrict__ A, const float* __restrict__ B,
    const float* __restrict__ nb,
    float* __restrict__ pval, int* __restrict__ pidx)
{
    __shared__ __align__(16) char smem[16384];
    float (*As)[128] = (float (*)[128])smem;
    float (*Bs)[128] = (float (*)[128])(smem + 4096);
    const int m0 = blockIdx.x * 128, q0 = blockIdx.y * 128;
    const int tid = threadIdx.x;
    const int tx = tid & 15, ty = tid >> 4;
    const int lr = tid >> 5, lc = (tid & 31) * 4;
    float acc[8][8] = {};
    for (int k0 = 0; k0 < C; k0 += 8) {
        *(float4*)&As[lr][lc] = *(const float4*)&A[(k0 + lr) * HW + m0 + lc];
        *(float4*)&Bs[lr][lc] = *(const float4*)&B[(k0 + lr) * HW + q0 + lc];
        __syncthreads();
#pragma unroll
        for (int kk = 0; kk < 8; ++kk) {
            float a8[8], b8[8];
            *(float4*)&a8[0] = *(float4*)&As[kk][ty * 8];
            *(float4*)&a8[4] = *(float4*)&As[kk][ty * 8 + 4];
            *(float4*)&b8[0] = *(float4*)&Bs[kk][tx * 8];
            *(float4*)&b8[4] = *(float4*)&Bs[kk][tx * 8 + 4];
#pragma unroll
            for (int i = 0; i < 8; ++i)
#pragma unroll
                for (int j = 0; j < 8; ++j) acc[i][j] += a8[i] * b8[j];
        }
        __syncthreads();
    }
    float nbv[8];
#pragma unroll
    for (int j = 0; j < 8; ++j) nbv[j] = nb[q0 + tx * 8 + j];
    float (*rv)[16] = (float (*)[16])smem;
    int   (*ri)[16] = (int   (*)[16])(smem + 8192);
#pragma unroll
    for (int i = 0; i < 8; ++i) {
        float bv = -INFINITY; int bi = 0;
#pragma unroll
        for (int j = 0; j < 8; ++j) {
            float s = acc[i][j] / nbv[j];
            int q = q0 + tx * 8 + j;
            if (s > bv) { bv = s; bi = q; }
        }
        rv[ty * 8 + i][tx] = bv;
        ri[ty * 8 + i][tx] = bi;
    }
    __syncthreads();
    if (tid < 128) {
        float bv = rv[tid][0]; int bi = ri[tid][0];
#pragma unroll
        for (int t = 1; t < 16; ++t) {
            float v = rv[tid][t]; int ii = ri[tid][t];
            if (v > bv || (v == bv && ii < bi)) { bv = v; bi = ii; }
        }
        pval[(m0 + tid) * NBN + blockIdx.y] = bv;
        pidx[(m0 + tid) * NBN + blockIdx.y] = bi;
    }
}

__global__ __launch_bounds__(256) void reduce_fb_kernel(
    const float* __restrict__ pval, const int* __restrict__ pidx,
    int* __restrict__ zb, float* __restrict__ out_zbest)
{
    int p = blockIdx.x * 256 + threadIdx.x;
    float bv = pval[p * NBN]; int bi = pidx[p * NBN];
#pragma unroll 8
    for (int t = 1; t < NBN; ++t) {
        float v = pval[p * NBN + t]; int ii = pidx[p * NBN + t];
        if (v > bv || (v == bv && ii < bi)) { bv = v; bi = ii; }
    }
    zb[p] = bi;
    out_zbest[p] = (float)bi;
}

extern "C" void kernel_launch(void* const* d_in, const int* in_sizes, int n_in,
                              void* d_out, int out_size, void* d_ws, size_t ws_size,
                              hipStream_t stream) {
    const float* a = (const float*)d_in[0];
    const float* b = (const float*)d_in[1];
    const float* d = (const float*)d_in[2];
    float* out = (float*)d_out;
    float* out_zbest = out + 1 + (size_t)C * HW;

    char* ws = (char*)d_ws;
    size_t off = 0;
    auto alloc = [&](size_t bytes) { void* p = ws + off; off = (off + bytes + 255) & ~(size_t)255; return p; };

    const size_t PACK = (size_t)C * HW * 2;  // 6.29 MB
    ushort_t* Ah = (ushort_t*)alloc(PACK);
    ushort_t* Al = (ushort_t*)alloc(PACK);
    ushort_t* Bh = (ushort_t*)alloc(PACK);
    ushort_t* Bl = (ushort_t*)alloc(PACK);
    float* nb  = (float*)alloc(HW * 4);
    float* nbp = (float*)alloc((size_t)NKB * HW * 4);
    float* pv1 = (float*)alloc((size_t)HW * NBN * 4);
    int*   pi1 = (int*)alloc((size_t)HW * NBN * 4);
    float* pv2 = (float*)alloc((size_t)HW * NBN * 4);
    int*   pi2 = (int*)alloc((size_t)HW * NBN * 4);
    int*   zb  = (int*)alloc(HW * 4);
    int*   flag = (int*)alloc(HW * 4);
    float* pdot = (float*)alloc((size_t)NCH_L * HW * 4);
    float* pa2  = (float*)alloc((size_t)NCH_L * HW * 4);
    float* pt2  = (float*)alloc((size_t)NCH_L * HW * 4);
    bool fast = off <= ws_size;

    hipMemsetAsync(d_out, 0, sizeof(float), stream);

    if (fast) {
        pack_kernel<<<dim3(HW / 256, NKB, 2), 256, 0, stream>>>(a, b, Ah, Al, Bh, Bl, nbp);
        bnorm_finalize_kernel<<<HW / 256, 256, 0, stream>>>(nbp, nb);
        gemm_mfma_kernel<<<dim3(HW / 128, HW / 128), 256, 0, stream>>>(
            Ah, Al, Bh, Bl, nb, pv1, pi1, pv2, pi2);
        reduce_top2_kernel<<<HW / 256, 256, 0, stream>>>(pv1, pi1, pv2, zb, out_zbest, flag);
        recheck_kernel<<<HW, 64, 0, stream>>>(a, b, nb, pi1, pi2, flag, zb, out_zbest);
    } else {
        // compact fp32 fallback layout
        off = 0;
        nb  = (float*)alloc(HW * 4);
        nbp = (float*)alloc((size_t)NKB * HW * 4);
        pv1 = (float*)alloc((size_t)HW * NBN * 4);
        pi1 = (int*)alloc((size_t)HW * NBN * 4);
        zb  = (int*)alloc(HW * 4);
        pdot = (float*)alloc((size_t)NCH_L * HW * 4);
        pa2  = (float*)alloc((size_t)NCH_L * HW * 4);
        pt2  = (float*)alloc((size_t)NCH_L * HW * 4);
        bnorm_partial_fb_kernel<<<dim3(HW / 256, NKB), 256, 0, stream>>>(b, nbp);
        bnorm_finalize_kernel<<<HW / 256, 256, 0, stream>>>(nbp, nb);
        gemm_argmax_fb_kernel<<<dim3(HW / 128, HW / 128), 256, 0, stream>>>(a, b, nb, pv1, pi1);
        reduce_fb_kernel<<<HW / 256, 256, 0, stream>>>(pv1, pi1, zb, out_zbest);
    }
    gather_partial_kernel<<<dim3(HW / 256, NCH_L), 256, 0, stream>>>(a, d, zb, out, pdot, pa2, pt2);
    loss_finalize_kernel<<<HW / 256, 256, 0, stream>>>(pdot, pa2, pt2, out);
}

// Round 4
// 289.577 us; speedup vs baseline: 2.8646x; 1.2926x over previous
//
#include <hip/hip_runtime.h>
#include <math.h>

#define EPS  1e-8f
#define C    768
#define HW   4096
#define NKB  24           // k-blocks of 32 (C/32)
#define NBN  32           // q-tiles of 128 (HW/128)
#define TAU  0.005f       // scaled-sim margin for fp32 recheck
#define NCH_NEW 12        // c-tiles of 64 for transpose-gather
#define NCH_OLD 48        // c-chunks for backup gather

typedef float  floatx4 __attribute__((ext_vector_type(4)));
typedef short  shortx8 __attribute__((ext_vector_type(8)));
typedef unsigned short ushort_t;
typedef unsigned int   uint_t;
typedef __attribute__((address_space(1))) uint_t as1_uint;
typedef __attribute__((address_space(3))) uint_t as3_uint;

__device__ __forceinline__ ushort_t f2bf(float v) {
    uint_t u = __float_as_uint(v);
    uint_t r = (u + 0x7FFFu + ((u >> 16) & 1u)) >> 16;   // RNE
    return (ushort_t)r;
}
__device__ __forceinline__ float bf2f(ushort_t h) {
    return __uint_as_float(((uint_t)h) << 16);
}
__device__ __forceinline__ void async_cp16(const ushort_t* g, ushort_t* l) {
    __builtin_amdgcn_global_load_lds((const as1_uint*)g, (as3_uint*)l, 16, 0, 0);
}

// ---------------------------------------------------------------------------
// pack: a,b -> bf16 hi/lo in MFMA-staging layout [kb][p][kk]; b-norm partials.
// ---------------------------------------------------------------------------
__global__ __launch_bounds__(256) void pack_kernel(
    const float* __restrict__ a, const float* __restrict__ b,
    ushort_t* __restrict__ Ah, ushort_t* __restrict__ Al,
    ushort_t* __restrict__ Bh, ushort_t* __restrict__ Bl,
    float* __restrict__ nbp)
{
    const int tid = threadIdx.x;
    const int p   = blockIdx.x * 256 + tid;
    const int kb  = blockIdx.y;
    const int z   = blockIdx.z;
    const float* src = z ? b : a;
    ushort_t* dh = z ? Bh : Ah;
    ushort_t* dl = z ? Bl : Al;

    ushort_t h[32], l[32];
    float s = 0.f;
#pragma unroll
    for (int r = 0; r < 32; ++r) {
        float v = src[(kb * 32 + r) * HW + p];
        s += v * v;
        ushort_t hh = f2bf(v);
        h[r] = hh;
        l[r] = f2bf(v - bf2f(hh));
    }
    if (z) nbp[kb * HW + p] = s;

    uint_t hw_[16], lw_[16];
#pragma unroll
    for (int w = 0; w < 16; ++w) {
        hw_[w] = (uint_t)h[2 * w] | ((uint_t)h[2 * w + 1] << 16);
        lw_[w] = (uint_t)l[2 * w] | ((uint_t)l[2 * w + 1] << 16);
    }
    uint4* oh = (uint4*)(dh + (size_t)(kb * HW + p) * 32);
    uint4* ol = (uint4*)(dl + (size_t)(kb * HW + p) * 32);
#pragma unroll
    for (int w = 0; w < 4; ++w) {
        oh[w] = make_uint4(hw_[4*w], hw_[4*w+1], hw_[4*w+2], hw_[4*w+3]);
        ol[w] = make_uint4(lw_[4*w], lw_[4*w+1], lw_[4*w+2], lw_[4*w+3]);
    }
}

__global__ __launch_bounds__(256) void bnorm_finalize_kernel(
    const float* __restrict__ nbp, float* __restrict__ nb)
{
    int q = blockIdx.x * 256 + threadIdx.x;
    float s = 0.f;
#pragma unroll
    for (int ch = 0; ch < NKB; ++ch) s += nbp[ch * HW + q];
    nb[q] = sqrtf(s + EPS) + EPS;
}

// ---------------------------------------------------------------------------
// transpose d [c][hw] -> dT [hw][c] (LDS 64x64 tiles, both sides coalesced)
// ---------------------------------------------------------------------------
__global__ __launch_bounds__(256) void transpose_kernel(
    const float* __restrict__ d, float* __restrict__ dT)
{
    __shared__ float tile[64][65];
    const int t = threadIdx.x;
    const int c0 = blockIdx.x * 64;   // 12 c-tiles
    const int p0 = blockIdx.y * 64;   // 64 p-tiles
    const int x = t & 63, y4 = t >> 6;
#pragma unroll
    for (int i = 0; i < 16; ++i) {
        int c = y4 * 16 + i;
        tile[c][x] = d[(size_t)(c0 + c) * HW + p0 + x];
    }
    __syncthreads();
#pragma unroll
    for (int i = 0; i < 16; ++i) {
        int p = y4 * 16 + i;
        dT[(size_t)(p0 + p) * C + c0 + x] = tile[x][p];
    }
}

// ---------------------------------------------------------------------------
// fused-3-segment MFMA GEMM: per kb stage Ah,Al,Bh,Bl (32 KB), one barrier
// pair, 48 MFMA/wave (hihi + hilo + lohi; lo*lo dropped). Top-2 epilogue.
// ---------------------------------------------------------------------------
__global__ __launch_bounds__(256, 4) void gemm_mfma_kernel(
    const ushort_t* __restrict__ Ah, const ushort_t* __restrict__ Al,
    const ushort_t* __restrict__ Bh, const ushort_t* __restrict__ Bl,
    const float* __restrict__ nb,
    float* __restrict__ pv1, int* __restrict__ pi1,
    float* __restrict__ pv2, int* __restrict__ pi2)
{
    __shared__ __align__(16) char smem[32768];
    ushort_t* sAh = (ushort_t*)smem;            // 8 KB [p 0..127][kk 0..31]
    ushort_t* sAl = (ushort_t*)(smem + 8192);
    ushort_t* sBh = (ushort_t*)(smem + 16384);
    ushort_t* sBl = (ushort_t*)(smem + 24576);

    const int tid  = threadIdx.x;
    const int lane = tid & 63;
    const int wave = tid >> 6;
    const int wm = wave >> 1, wn = wave & 1;
    const int bm = blockIdx.x, bn = blockIdx.y;
    const int l15 = lane & 15, l4 = lane >> 4;
    const int fo = l15 * 32 + l4 * 8;           // frag element offset

    floatx4 acc[4][4];
#pragma unroll
    for (int i = 0; i < 4; ++i)
#pragma unroll
        for (int j = 0; j < 4; ++j) acc[i][j] = (floatx4){0.f, 0.f, 0.f, 0.f};

    for (int kb = 0; kb < NKB; ++kb) {
        const size_t aoff = (size_t)(kb * HW + bm * 128) * 32 + tid * 8;
        const size_t boff = (size_t)(kb * HW + bn * 128) * 32 + tid * 8;
        async_cp16(Ah + aoff,        sAh + tid * 8);
        async_cp16(Ah + aoff + 2048, sAh + tid * 8 + 2048);
        async_cp16(Al + aoff,        sAl + tid * 8);
        async_cp16(Al + aoff + 2048, sAl + tid * 8 + 2048);
        async_cp16(Bh + boff,        sBh + tid * 8);
        async_cp16(Bh + boff + 2048, sBh + tid * 8 + 2048);
        async_cp16(Bl + boff,        sBl + tid * 8);
        async_cp16(Bl + boff + 2048, sBl + tid * 8 + 2048);
        __syncthreads();

        shortx8 af[4], bf_[4];
        // phase 1: hi*hi
#pragma unroll
        for (int i = 0; i < 4; ++i) af[i]  = *(const shortx8*)&sAh[(wm * 4 + i) * 512 + fo];
#pragma unroll
        for (int j = 0; j < 4; ++j) bf_[j] = *(const shortx8*)&sBh[(wn * 4 + j) * 512 + fo];
#pragma unroll
        for (int i = 0; i < 4; ++i)
#pragma unroll
            for (int j = 0; j < 4; ++j)
                acc[i][j] = __builtin_amdgcn_mfma_f32_16x16x32_bf16(af[i], bf_[j], acc[i][j], 0, 0, 0);
        // phase 2: hi*lo (Ah kept)
#pragma unroll
        for (int j = 0; j < 4; ++j) bf_[j] = *(const shortx8*)&sBl[(wn * 4 + j) * 512 + fo];
#pragma unroll
        for (int i = 0; i < 4; ++i)
#pragma unroll
            for (int j = 0; j < 4; ++j)
                acc[i][j] = __builtin_amdgcn_mfma_f32_16x16x32_bf16(af[i], bf_[j], acc[i][j], 0, 0, 0);
        // phase 3: lo*hi
#pragma unroll
        for (int i = 0; i < 4; ++i) af[i]  = *(const shortx8*)&sAl[(wm * 4 + i) * 512 + fo];
#pragma unroll
        for (int j = 0; j < 4; ++j) bf_[j] = *(const shortx8*)&sBh[(wn * 4 + j) * 512 + fo];
#pragma unroll
        for (int i = 0; i < 4; ++i)
#pragma unroll
            for (int j = 0; j < 4; ++j)
                acc[i][j] = __builtin_amdgcn_mfma_f32_16x16x32_bf16(af[i], bf_[j], acc[i][j], 0, 0, 0);
        __syncthreads();
    }

    // ---- epilogue: sim = acc / nb[q]; per-p top-2 over the block's 128 q
    float rnb[4];
#pragma unroll
    for (int j = 0; j < 4; ++j)
        rnb[j] = 1.0f / nb[bn * 128 + wn * 64 + j * 16 + l15];

    float* lv1 = (float*)smem;
    int*   li1 = (int*)(smem + 1024);
    float* lv2 = (float*)(smem + 2048);
    int*   li2 = (int*)(smem + 3072);

#pragma unroll
    for (int i = 0; i < 4; ++i) {
#pragma unroll
        for (int r = 0; r < 4; ++r) {
            float v1 = -INFINITY, v2 = -INFINITY; int i1 = 0, i2 = 0;
#pragma unroll
            for (int j = 0; j < 4; ++j) {
                float sv = acc[i][j][r] * rnb[j];
                int q = bn * 128 + wn * 64 + j * 16 + l15;
                if (sv > v1) { v2 = v1; i2 = i1; v1 = sv; i1 = q; }
                else if (sv > v2) { v2 = sv; i2 = q; }
            }
#pragma unroll
            for (int m = 1; m < 16; m <<= 1) {
                float ov1 = __shfl_xor(v1, m, 64);
                int   oi1 = __shfl_xor(i1, m, 64);
                float ov2 = __shfl_xor(v2, m, 64);
                int   oi2 = __shfl_xor(i2, m, 64);
                if (ov1 > v1 || (ov1 == v1 && oi1 < i1)) {
                    if (v1 > ov2 || (v1 == ov2 && i1 < oi2)) { v2 = v1; i2 = i1; }
                    else { v2 = ov2; i2 = oi2; }
                    v1 = ov1; i1 = oi1;
                } else if (ov1 > v2 || (ov1 == v2 && oi1 < i2)) {
                    v2 = ov1; i2 = oi1;
                }
            }
            if (l15 == 0) {
                int pl = wm * 64 + i * 16 + l4 * 4 + r;
                lv1[pl * 2 + wn] = v1; li1[pl * 2 + wn] = i1;
                lv2[pl * 2 + wn] = v2; li2[pl * 2 + wn] = i2;
            }
        }
    }
    __syncthreads();
    if (tid < 128) {
        float v1 = lv1[tid * 2],     v2 = lv2[tid * 2];
        int   i1 = li1[tid * 2],     i2 = li2[tid * 2];
        float w1 = lv1[tid * 2 + 1], w2 = lv2[tid * 2 + 1];
        int   j1 = li1[tid * 2 + 1], j2 = li2[tid * 2 + 1];
        if (w1 > v1 || (w1 == v1 && j1 < i1)) {
            if (v1 > w2 || (v1 == w2 && i1 < j2)) { v2 = v1; i2 = i1; }
            else { v2 = w2; i2 = j2; }
            v1 = w1; i1 = j1;
        } else if (w1 > v2 || (w1 == v2 && j1 < i2)) {
            v2 = w1; i2 = j1;
        }
        int p = bm * 128 + tid;
        pv1[p * NBN + bn] = v1; pi1[p * NBN + bn] = i1;
        pv2[p * NBN + bn] = v2; pi2[p * NBN + bn] = i2;
    }
}

// merge 32 tile top-2s -> z_best + margin flag
__global__ __launch_bounds__(256) void reduce_top2_kernel(
    const float* __restrict__ pv1, const int* __restrict__ pi1,
    const float* __restrict__ pv2,
    int* __restrict__ zb, float* __restrict__ out_zbest, int* __restrict__ flag)
{
    int p = blockIdx.x * 256 + threadIdx.x;
    float v1 = pv1[p * NBN]; int i1 = pi1[p * NBN];
    float v2 = pv2[p * NBN];
#pragma unroll 8
    for (int t = 1; t < NBN; ++t) {
        float a1 = pv1[p * NBN + t]; int b1 = pi1[p * NBN + t];
        float a2 = pv2[p * NBN + t];
        if (a1 > v1 || (a1 == v1 && b1 < i1)) {
            if (v1 > v2) v2 = v1;
            v1 = a1; i1 = b1;
        } else if (a1 > v2) v2 = a1;
        if (a2 > v2) v2 = a2;
    }
    zb[p] = i1;
    out_zbest[p] = (float)i1;
    flag[p] = (v1 - v2 < TAU) ? 1 : 0;
}

// exact fp32 recheck over the 64 per-tile top-2 candidates of flagged rows
__global__ __launch_bounds__(64) void recheck_kernel(
    const float* __restrict__ a, const float* __restrict__ b,
    const float* __restrict__ nb,
    const int* __restrict__ pi1, const int* __restrict__ pi2,
    const int* __restrict__ flag,
    int* __restrict__ zb, float* __restrict__ out_zbest)
{
    int p = blockIdx.x;
    if (!flag[p]) return;
    int t = threadIdx.x;
    int q = (t & 1) ? pi2[p * NBN + (t >> 1)] : pi1[p * NBN + (t >> 1)];
    float dot = 0.f;
#pragma unroll 8
    for (int c = 0; c < C; ++c)
        dot += a[c * HW + p] * b[c * HW + q];
    float s = dot / nb[q];
#pragma unroll
    for (int m = 1; m < 64; m <<= 1) {
        float os = __shfl_xor(s, m, 64);
        int   oq = __shfl_xor(q, m, 64);
        if (os > s || (os == s && oq < q)) { s = os; q = oq; }
    }
    if (t == 0) { zb[p] = q; out_zbest[p] = (float)q; }
}

// ---------------------------------------------------------------------------
// transpose-gather: block = 64 p x 64 c tile. Read dT rows coalesced (64 B
// runs), LDS-transpose, write z_new coalesced, fused loss partials.
// ---------------------------------------------------------------------------
__global__ __launch_bounds__(256) void gather_loss_kernel(
    const float* __restrict__ a, const float* __restrict__ dT,
    const int* __restrict__ zb, float* __restrict__ out,
    float* __restrict__ pdot, float* __restrict__ pa2, float* __restrict__ pt2)
{
    __shared__ float tile[64][65];
    __shared__ int qs[64];
    const int t = threadIdx.x;
    const int p0 = blockIdx.x * 64;   // 64 p-tiles
    const int c0 = blockIdx.y * 64;   // 12 c-tiles
    if (t < 64) qs[t] = zb[p0 + t];
    __syncthreads();

    {   // load: thread t -> row pl = t>>2, 16 floats at col sub*16
        const int pl = t >> 2, sub = t & 3;
        const float* src = dT + (size_t)qs[pl] * C + c0 + sub * 16;
        float4 v0 = *(const float4*)(src);
        float4 v1 = *(const float4*)(src + 4);
        float4 v2 = *(const float4*)(src + 8);
        float4 v3 = *(const float4*)(src + 12);
        float* dst = &tile[pl][sub * 16];
        dst[0] = v0.x; dst[1] = v0.y; dst[2]  = v0.z; dst[3]  = v0.w;
        dst[4] = v1.x; dst[5] = v1.y; dst[6]  = v1.z; dst[7]  = v1.w;
        dst[8] = v2.x; dst[9] = v2.y; dst[10] = v2.z; dst[11] = v2.w;
        dst[12] = v3.x; dst[13] = v3.y; dst[14] = v3.z; dst[15] = v3.w;
    }
    __syncthreads();

    // write z_new coalesced + loss partials; thread t: p = t&63, c-group t>>6
    const int p = t & 63, cg = t >> 6;
    float dot = 0.f, a2 = 0.f, t2 = 0.f;
#pragma unroll
    for (int i = 0; i < 16; ++i) {
        int cc = cg * 16 + i;
        float tv = tile[p][cc];
        float av = a[(size_t)(c0 + cc) * HW + p0 + p];
        out[1 + (size_t)(c0 + cc) * HW + p0 + p] = tv;
        dot += av * tv; a2 += av * av; t2 += tv * tv;
    }
    __shared__ float r1[256], r2[256], r3[256];
    r1[t] = dot; r2[t] = a2; r3[t] = t2;
    __syncthreads();
    if (t < 64) {
        dot = r1[t] + r1[t + 64] + r1[t + 128] + r1[t + 192];
        a2  = r2[t] + r2[t + 64] + r2[t + 128] + r2[t + 192];
        t2  = r3[t] + r3[t + 64] + r3[t + 128] + r3[t + 192];
        pdot[blockIdx.y * HW + p0 + t] = dot;
        pa2[blockIdx.y * HW + p0 + t]  = a2;
        pt2[blockIdx.y * HW + p0 + t]  = t2;
    }
}

// backup gather (no dT) — only if workspace too small
__global__ __launch_bounds__(256) void gather_partial_kernel(
    const float* __restrict__ a, const float* __restrict__ d,
    const int* __restrict__ zb, float* __restrict__ out,
    float* __restrict__ pdot, float* __restrict__ pa2, float* __restrict__ pt2)
{
    int p = blockIdx.x * 256 + threadIdx.x;
    int ch = blockIdx.y;
    int c0 = ch * (C / NCH_OLD);
    int q = zb[p];
    float dot = 0.f, a2 = 0.f, t2 = 0.f;
#pragma unroll
    for (int c = c0; c < c0 + C / NCH_OLD; ++c) {
        float av = a[c * HW + p];
        float tv = d[c * HW + q];
        dot += av * tv; a2 += av * av; t2 += tv * tv;
        out[1 + c * HW + p] = tv;
    }
    pdot[ch * HW + p] = dot;
    pa2[ch * HW + p] = a2;
    pt2[ch * HW + p] = t2;
}

__global__ __launch_bounds__(256) void loss_finalize_kernel(
    const float* __restrict__ pdot, const float* __restrict__ pa2,
    const float* __restrict__ pt2, float* __restrict__ out, int nch)
{
    int p = blockIdx.x * 256 + threadIdx.x;
    float dot = 0.f, a2 = 0.f, t2 = 0.f;
#pragma unroll 12
    for (int ch = 0; ch < nch; ++ch) {
        dot += pdot[ch * HW + p];
        a2  += pa2[ch * HW + p];
        t2  += pt2[ch * HW + p];
    }
    float cs = dot / ((sqrtf(a2) + EPS) * (sqrtf(t2) + EPS));
    float contrib = 1.f - cs;
    __shared__ float red[256];
    red[threadIdx.x] = contrib;
    __syncthreads();
    for (int s = 128; s > 0; s >>= 1) {
        if (threadIdx.x < s) red[threadIdx.x] += red[threadIdx.x + s];
        __syncthreads();
    }
    if (threadIdx.x == 0) atomicAdd(out, red[0] * (1.0f / HW));
}

// ---------------------------------------------------------------------------
// fp32 fallback GEMM path (only if ws too small for bf16 packs)
// ---------------------------------------------------------------------------
__global__ __launch_bounds__(256) void bnorm_partial_fb_kernel(
    const float* __restrict__ b, float* __restrict__ nbp)
{
    int q = blockIdx.x * 256 + threadIdx.x;
    int c0 = blockIdx.y * 32;
    float s = 0.f;
#pragma unroll 8
    for (int c = c0; c < c0 + 32; ++c) { float v = b[c * HW + q]; s += v * v; }
    nbp[blockIdx.y * HW + q] = s;
}

__global__ __launch_bounds__(256) void gemm_argmax_fb_kernel(
    const float* __restrict__ A, const float* __restrict__ B,
    const float* __restrict__ nb,
    float* __restrict__ pval, int* __restrict__ pidx)
{
    __shared__ __align__(16) char smem[16384];
    float (*As)[128] = (float (*)[128])smem;
    float (*Bs)[128] = (float (*)[128])(smem + 4096);
    const int m0 = blockIdx.x * 128, q0 = blockIdx.y * 128;
    const int tid = threadIdx.x;
    const int tx = tid & 15, ty = tid >> 4;
    const int lr = tid >> 5, lc = (tid & 31) * 4;
    float acc[8][8] = {};
    for (int k0 = 0; k0 < C; k0 += 8) {
        *(float4*)&As[lr][lc] = *(const float4*)&A[(k0 + lr) * HW + m0 + lc];
        *(float4*)&Bs[lr][lc] = *(const float4*)&B[(k0 + lr) * HW + q0 + lc];
        __syncthreads();
#pragma unroll
        for (int kk = 0; kk < 8; ++kk) {
            float a8[8], b8[8];
            *(float4*)&a8[0] = *(float4*)&As[kk][ty * 8];
            *(float4*)&a8[4] = *(float4*)&As[kk][ty * 8 + 4];
            *(float4*)&b8[0] = *(float4*)&Bs[kk][tx * 8];
            *(float4*)&b8[4] = *(float4*)&Bs[kk][tx * 8 + 4];
#pragma unroll
            for (int i = 0; i < 8; ++i)
#pragma unroll
                for (int j = 0; j < 8; ++j) acc[i][j] += a8[i] * b8[j];
        }
        __syncthreads();
    }
    float nbv[8];
#pragma unroll
    for (int j = 0; j < 8; ++j) nbv[j] = nb[q0 + tx * 8 + j];
    float (*rv)[16] = (float (*)[16])smem;
    int   (*ri)[16] = (int   (*)[16])(smem + 8192);
#pragma unroll
    for (int i = 0; i < 8; ++i) {
        float bv = -INFINITY; int bi = 0;
#pragma unroll
        for (int j = 0; j < 8; ++j) {
            float s = acc[i][j] / nbv[j];
            int q = q0 + tx * 8 + j;
            if (s > bv) { bv = s; bi = q; }
        }
        rv[ty * 8 + i][tx] = bv;
        ri[ty * 8 + i][tx] = bi;
    }
    __syncthreads();
    if (tid < 128) {
        float bv = rv[tid][0]; int bi = ri[tid][0];
#pragma unroll
        for (int t = 1; t < 16; ++t) {
            float v = rv[tid][t]; int ii = ri[tid][t];
            if (v > bv || (v == bv && ii < bi)) { bv = v; bi = ii; }
        }
        pval[(m0 + tid) * NBN + blockIdx.y] = bv;
        pidx[(m0 + tid) * NBN + blockIdx.y] = bi;
    }
}

__global__ __launch_bounds__(256) void reduce_fb_kernel(
    const float* __restrict__ pval, const int* __restrict__ pidx,
    int* __restrict__ zb, float* __restrict__ out_zbest)
{
    int p = blockIdx.x * 256 + threadIdx.x;
    float bv = pval[p * NBN]; int bi = pidx[p * NBN];
#pragma unroll 8
    for (int t = 1; t < NBN; ++t) {
        float v = pval[p * NBN + t]; int ii = pidx[p * NBN + t];
        if (v > bv || (v == bv && ii < bi)) { bv = v; bi = ii; }
    }
    zb[p] = bi;
    out_zbest[p] = (float)bi;
}

extern "C" void kernel_launch(void* const* d_in, const int* in_sizes, int n_in,
                              void* d_out, int out_size, void* d_ws, size_t ws_size,
                              hipStream_t stream) {
    const float* a = (const float*)d_in[0];
    const float* b = (const float*)d_in[1];
    const float* d = (const float*)d_in[2];
    float* out = (float*)d_out;
    float* out_zbest = out + 1 + (size_t)C * HW;

    char* ws = (char*)d_ws;
    size_t off = 0;
    auto alloc = [&](size_t bytes) { void* p = ws + off; off = (off + bytes + 255) & ~(size_t)255; return p; };

    const size_t PACK = (size_t)C * HW * 2;  // 6.29 MB
    ushort_t* Ah = (ushort_t*)alloc(PACK);
    ushort_t* Al = (ushort_t*)alloc(PACK);
    ushort_t* Bh = (ushort_t*)alloc(PACK);
    ushort_t* Bl = (ushort_t*)alloc(PACK);
    float* nb  = (float*)alloc(HW * 4);
    float* nbp = (float*)alloc((size_t)NKB * HW * 4);
    float* pv1 = (float*)alloc((size_t)HW * NBN * 4);
    int*   pi1 = (int*)alloc((size_t)HW * NBN * 4);
    float* pv2 = (float*)alloc((size_t)HW * NBN * 4);
    int*   pi2 = (int*)alloc((size_t)HW * NBN * 4);
    int*   zb  = (int*)alloc(HW * 4);
    int*   flag = (int*)alloc(HW * 4);
    float* pdot = (float*)alloc((size_t)NCH_OLD * HW * 4);
    float* pa2  = (float*)alloc((size_t)NCH_OLD * HW * 4);
    float* pt2  = (float*)alloc((size_t)NCH_OLD * HW * 4);
    size_t base_end = off;
    float* dT = (float*)alloc((size_t)C * HW * 4);   // 12.6 MB
    bool fast    = base_end <= ws_size;
    bool have_dT = off <= ws_size;

    hipMemsetAsync(d_out, 0, sizeof(float), stream);

    if (fast) {
        pack_kernel<<<dim3(HW / 256, NKB, 2), 256, 0, stream>>>(a, b, Ah, Al, Bh, Bl, nbp);
        bnorm_finalize_kernel<<<HW / 256, 256, 0, stream>>>(nbp, nb);
        gemm_mfma_kernel<<<dim3(HW / 128, HW / 128), 256, 0, stream>>>(
            Ah, Al, Bh, Bl, nb, pv1, pi1, pv2, pi2);
        reduce_top2_kernel<<<HW / 256, 256, 0, stream>>>(pv1, pi1, pv2, zb, out_zbest, flag);
        recheck_kernel<<<HW, 64, 0, stream>>>(a, b, nb, pi1, pi2, flag, zb, out_zbest);
    } else {
        off = 0;
        nb  = (float*)alloc(HW * 4);
        nbp = (float*)alloc((size_t)NKB * HW * 4);
        pv1 = (float*)alloc((size_t)HW * NBN * 4);
        pi1 = (int*)alloc((size_t)HW * NBN * 4);
        zb  = (int*)alloc(HW * 4);
        pdot = (float*)alloc((size_t)NCH_OLD * HW * 4);
        pa2  = (float*)alloc((size_t)NCH_OLD * HW * 4);
        pt2  = (float*)alloc((size_t)NCH_OLD * HW * 4);
        dT = (float*)alloc((size_t)C * HW * 4);
        have_dT = off <= ws_size;
        bnorm_partial_fb_kernel<<<dim3(HW / 256, NKB), 256, 0, stream>>>(b, nbp);
        bnorm_finalize_kernel<<<HW / 256, 256, 0, stream>>>(nbp, nb);
        gemm_argmax_fb_kernel<<<dim3(HW / 128, HW / 128), 256, 0, stream>>>(a, b, nb, pv1, pi1);
        reduce_fb_kernel<<<HW / 256, 256, 0, stream>>>(pv1, pi1, zb, out_zbest);
    }

    if (have_dT) {
        transpose_kernel<<<dim3(C / 64, HW / 64), 256, 0, stream>>>(d, dT);
        gather_loss_kernel<<<dim3(HW / 64, NCH_NEW), 256, 0, stream>>>(
            a, dT, zb, out, pdot, pa2, pt2);
        loss_finalize_kernel<<<HW / 256, 256, 0, stream>>>(pdot, pa2, pt2, out, NCH_NEW);
    } else {
        gather_partial_kernel<<<dim3(HW / 256, NCH_OLD), 256, 0, stream>>>(
            a, d, zb, out, pdot, pa2, pt2);
        loss_finalize_kernel<<<HW / 256, 256, 0, stream>>>(pdot, pa2, pt2, out, NCH_OLD);
    }
}

// Round 5
// 216.845 us; speedup vs baseline: 3.8254x; 1.3354x over previous
//
#include <hip/hip_runtime.h>
#include <math.h>

#define EPS  1e-8f
#define C    768
#define HW   4096
#define NKB  24           // k-blocks of 32 (C/32)
#define NBN  32           // q-tiles of 128 (HW/128)
#define TAU  0.008f       // scaled-sim margin for fp32 recheck (~7 sigma of al*b error)
#define NCH_NEW 12        // c-tiles of 64 for transpose-gather
#define NCH_OLD 48        // c-chunks for backup gather

typedef float  floatx4 __attribute__((ext_vector_type(4)));
typedef short  shortx8 __attribute__((ext_vector_type(8)));
typedef unsigned short ushort_t;
typedef unsigned int   uint_t;
typedef __attribute__((address_space(1))) uint_t as1_uint;
typedef __attribute__((address_space(3))) uint_t as3_uint;

__device__ __forceinline__ ushort_t f2bf(float v) {
    uint_t u = __float_as_uint(v);
    uint_t r = (u + 0x7FFFu + ((u >> 16) & 1u)) >> 16;   // RNE
    return (ushort_t)r;
}
__device__ __forceinline__ float bf2f(ushort_t h) {
    return __uint_as_float(((uint_t)h) << 16);
}
__device__ __forceinline__ void async_cp16(const ushort_t* g, ushort_t* l) {
    __builtin_amdgcn_global_load_lds((const as1_uint*)g, (as3_uint*)l, 16, 0, 0);
}

// ---------------------------------------------------------------------------
// pack: z=0: a -> Ah (bf16-hi). z=1: b -> Bh,Bl + nbp partials.
// Layout [kb][p][kk] with 16B granule w stored at slot w ^ ((p>>1)&3)
// (bank swizzle; DMA in gemm copies this order contiguously into LDS).
// ---------------------------------------------------------------------------
__global__ __launch_bounds__(256) void pack_kernel(
    const float* __restrict__ a, const float* __restrict__ b,
    ushort_t* __restrict__ Ah, ushort_t* __restrict__ Bh,
    ushort_t* __restrict__ Bl, float* __restrict__ nbp)
{
    const int tid = threadIdx.x;
    const int p   = blockIdx.x * 256 + tid;
    const int kb  = blockIdx.y;
    const int z   = blockIdx.z;
    const int sw  = (p >> 1) & 3;

    if (z == 0) {
        ushort_t h[32];
#pragma unroll
        for (int r = 0; r < 32; ++r)
            h[r] = f2bf(a[(kb * 32 + r) * HW + p]);
        uint_t hw_[16];
#pragma unroll
        for (int w = 0; w < 16; ++w)
            hw_[w] = (uint_t)h[2 * w] | ((uint_t)h[2 * w + 1] << 16);
        uint4* oh = (uint4*)(Ah + (size_t)(kb * HW + p) * 32);
#pragma unroll
        for (int w = 0; w < 4; ++w)
            oh[w ^ sw] = make_uint4(hw_[4*w], hw_[4*w+1], hw_[4*w+2], hw_[4*w+3]);
    } else {
        ushort_t h[32], l[32];
        float s = 0.f;
#pragma unroll
        for (int r = 0; r < 32; ++r) {
            float v = b[(kb * 32 + r) * HW + p];
            s += v * v;
            ushort_t hh = f2bf(v);
            h[r] = hh;
            l[r] = f2bf(v - bf2f(hh));
        }
        nbp[kb * HW + p] = s;
        uint_t hw_[16], lw_[16];
#pragma unroll
        for (int w = 0; w < 16; ++w) {
            hw_[w] = (uint_t)h[2 * w] | ((uint_t)h[2 * w + 1] << 16);
            lw_[w] = (uint_t)l[2 * w] | ((uint_t)l[2 * w + 1] << 16);
        }
        uint4* oh = (uint4*)(Bh + (size_t)(kb * HW + p) * 32);
        uint4* ol = (uint4*)(Bl + (size_t)(kb * HW + p) * 32);
#pragma unroll
        for (int w = 0; w < 4; ++w) {
            oh[w ^ sw] = make_uint4(hw_[4*w], hw_[4*w+1], hw_[4*w+2], hw_[4*w+3]);
            ol[w ^ sw] = make_uint4(lw_[4*w], lw_[4*w+1], lw_[4*w+2], lw_[4*w+3]);
        }
    }
}

// ---------------------------------------------------------------------------
// transpose [c][hw] -> [hw][c]: z=0: d->dT, z=1: b->bT
// ---------------------------------------------------------------------------
__global__ __launch_bounds__(256) void transpose_kernel(
    const float* __restrict__ d, const float* __restrict__ b,
    float* __restrict__ dT, float* __restrict__ bT)
{
    __shared__ float tile[64][65];
    const int t = threadIdx.x;
    const int c0 = blockIdx.x * 64;
    const int p0 = blockIdx.y * 64;
    const float* src = blockIdx.z ? b : d;
    float* dst = blockIdx.z ? bT : dT;
    const int x = t & 63, y4 = t >> 6;
#pragma unroll
    for (int i = 0; i < 16; ++i) {
        int c = y4 * 16 + i;
        tile[c][x] = src[(size_t)(c0 + c) * HW + p0 + x];
    }
    __syncthreads();
#pragma unroll
    for (int i = 0; i < 16; ++i) {
        int p = y4 * 16 + i;
        dst[(size_t)(p0 + p) * C + c0 + x] = tile[x][p];
    }
}

// ---------------------------------------------------------------------------
// 2-pass MFMA GEMM (Ah*Bh + Ah*Bl = ah*b): per kb stage 24 KB, one barrier
// pair, 32 MFMA/wave, 12 swizzled ds_read_b128/wave. nb computed in-block
// from nbp. Top-2 epilogue per 128-q tile.
// ---------------------------------------------------------------------------
__global__ __launch_bounds__(256, 3) void gemm_mfma_kernel(
    const ushort_t* __restrict__ Ah, const ushort_t* __restrict__ Bh,
    const ushort_t* __restrict__ Bl, const float* __restrict__ nbp,
    float* __restrict__ pv1, int* __restrict__ pi1,
    float* __restrict__ pv2, int* __restrict__ pi2)
{
    __shared__ __align__(16) char smem[25088];
    ushort_t* sA  = (ushort_t*)smem;             // 8 KB
    ushort_t* sBh = (ushort_t*)(smem + 8192);    // 8 KB
    ushort_t* sBl = (ushort_t*)(smem + 16384);   // 8 KB
    float*    nb_s = (float*)(smem + 24576);     // 512 B (untouched by staging)

    const int tid  = threadIdx.x;
    const int lane = tid & 63;
    const int wave = tid >> 6;
    const int wm = wave >> 1, wn = wave & 1;
    const int bm = blockIdx.x, bn = blockIdx.y;
    const int l15 = lane & 15, l4 = lane >> 4;
    const int swz = (l15 >> 1) & 3;              // bank swizzle for frag reads

    // per-block reciprocal b-norms for q in [bn*128, bn*128+128)
    if (tid < 128) {
        float s = 0.f;
        int q = bn * 128 + tid;
#pragma unroll
        for (int ch = 0; ch < NKB; ++ch) s += nbp[ch * HW + q];
        nb_s[tid] = 1.0f / (sqrtf(s + EPS) + EPS);
    }

    floatx4 acc[4][4];
#pragma unroll
    for (int i = 0; i < 4; ++i)
#pragma unroll
        for (int j = 0; j < 4; ++j) acc[i][j] = (floatx4){0.f, 0.f, 0.f, 0.f};

    for (int kb = 0; kb < NKB; ++kb) {
        const size_t aoff = (size_t)(kb * HW + bm * 128) * 32 + tid * 8;
        const size_t boff = (size_t)(kb * HW + bn * 128) * 32 + tid * 8;
        async_cp16(Ah + aoff,        sA  + tid * 8);
        async_cp16(Ah + aoff + 2048, sA  + tid * 8 + 2048);
        async_cp16(Bh + boff,        sBh + tid * 8);
        async_cp16(Bh + boff + 2048, sBh + tid * 8 + 2048);
        async_cp16(Bl + boff,        sBl + tid * 8);
        async_cp16(Bl + boff + 2048, sBl + tid * 8 + 2048);
        __syncthreads();

        shortx8 af[4], bf_[4];
#pragma unroll
        for (int i = 0; i < 4; ++i)
            af[i] = *(const shortx8*)&sA[((wm * 4 + i) * 16 + l15) * 32 + ((l4 ^ swz) * 8)];
#pragma unroll
        for (int j = 0; j < 4; ++j)
            bf_[j] = *(const shortx8*)&sBh[((wn * 4 + j) * 16 + l15) * 32 + ((l4 ^ swz) * 8)];
#pragma unroll
        for (int i = 0; i < 4; ++i)
#pragma unroll
            for (int j = 0; j < 4; ++j)
                acc[i][j] = __builtin_amdgcn_mfma_f32_16x16x32_bf16(af[i], bf_[j], acc[i][j], 0, 0, 0);
#pragma unroll
        for (int j = 0; j < 4; ++j)
            bf_[j] = *(const shortx8*)&sBl[((wn * 4 + j) * 16 + l15) * 32 + ((l4 ^ swz) * 8)];
#pragma unroll
        for (int i = 0; i < 4; ++i)
#pragma unroll
            for (int j = 0; j < 4; ++j)
                acc[i][j] = __builtin_amdgcn_mfma_f32_16x16x32_bf16(af[i], bf_[j], acc[i][j], 0, 0, 0);
        __syncthreads();
    }

    // ---- epilogue: sim = acc * rnb[q]; per-p top-2 over the block's 128 q
    float rnb[4];
#pragma unroll
    for (int j = 0; j < 4; ++j)
        rnb[j] = nb_s[wn * 64 + j * 16 + l15];

    float* lv1 = (float*)smem;
    int*   li1 = (int*)(smem + 1024);
    float* lv2 = (float*)(smem + 2048);
    int*   li2 = (int*)(smem + 3072);

#pragma unroll
    for (int i = 0; i < 4; ++i) {
#pragma unroll
        for (int r = 0; r < 4; ++r) {
            float v1 = -INFINITY, v2 = -INFINITY; int i1 = 0, i2 = 0;
#pragma unroll
            for (int j = 0; j < 4; ++j) {
                float sv = acc[i][j][r] * rnb[j];
                int q = bn * 128 + wn * 64 + j * 16 + l15;
                if (sv > v1) { v2 = v1; i2 = i1; v1 = sv; i1 = q; }
                else if (sv > v2) { v2 = sv; i2 = q; }
            }
#pragma unroll
            for (int m = 1; m < 16; m <<= 1) {
                float ov1 = __shfl_xor(v1, m, 64);
                int   oi1 = __shfl_xor(i1, m, 64);
                float ov2 = __shfl_xor(v2, m, 64);
                int   oi2 = __shfl_xor(i2, m, 64);
                if (ov1 > v1 || (ov1 == v1 && oi1 < i1)) {
                    if (v1 > ov2 || (v1 == ov2 && i1 < oi2)) { v2 = v1; i2 = i1; }
                    else { v2 = ov2; i2 = oi2; }
                    v1 = ov1; i1 = oi1;
                } else if (ov1 > v2 || (ov1 == v2 && oi1 < i2)) {
                    v2 = ov1; i2 = oi1;
                }
            }
            if (l15 == 0) {
                int pl = wm * 64 + i * 16 + l4 * 4 + r;
                lv1[pl * 2 + wn] = v1; li1[pl * 2 + wn] = i1;
                lv2[pl * 2 + wn] = v2; li2[pl * 2 + wn] = i2;
            }
        }
    }
    __syncthreads();
    if (tid < 128) {
        float v1 = lv1[tid * 2],     v2 = lv2[tid * 2];
        int   i1 = li1[tid * 2],     i2 = li2[tid * 2];
        float w1 = lv1[tid * 2 + 1], w2 = lv2[tid * 2 + 1];
        int   j1 = li1[tid * 2 + 1], j2 = li2[tid * 2 + 1];
        if (w1 > v1 || (w1 == v1 && j1 < i1)) {
            if (v1 > w2 || (v1 == w2 && i1 < j2)) { v2 = v1; i2 = i1; }
            else { v2 = w2; i2 = j2; }
            v1 = w1; i1 = j1;
        } else if (w1 > v2 || (w1 == v2 && j1 < i2)) {
            v2 = w1; i2 = j1;
        }
        int p = bm * 128 + tid;
        pv1[p * NBN + bn] = v1; pi1[p * NBN + bn] = i1;
        pv2[p * NBN + bn] = v2; pi2[p * NBN + bn] = i2;
    }
}

// ---------------------------------------------------------------------------
// fused: merge 32 tile top-2s (one wave per row) -> z_best; flagged rows get
// an exact fp32 recheck over the 64 per-tile top-2 candidates (bT rows are
// contiguous; b-norm recomputed in-loop, so no nb array needed).
// ---------------------------------------------------------------------------
__global__ __launch_bounds__(64) void reduce_recheck_kernel(
    const float* __restrict__ a, const float* __restrict__ b,
    const float* __restrict__ bT, int bt_ok,
    const float* __restrict__ pv1, const int* __restrict__ pi1,
    const float* __restrict__ pv2, const int* __restrict__ pi2,
    int* __restrict__ zb, float* __restrict__ out_zbest)
{
    const int p = blockIdx.x;
    const int l = threadIdx.x;
    const int t = l & 31;

    float v1, v2; int i1, cand;
    if (l < 32) {
        v1 = pv1[p * NBN + t]; i1 = pi1[p * NBN + t]; v2 = pv2[p * NBN + t];
        cand = i1;
    } else {
        v1 = -INFINITY; v2 = -INFINITY; i1 = 0x7fffffff;
        cand = pi2[p * NBN + t];
    }
#pragma unroll
    for (int m = 1; m < 32; m <<= 1) {
        float ov1 = __shfl_xor(v1, m, 64);
        int   oi1 = __shfl_xor(i1, m, 64);
        float ov2 = __shfl_xor(v2, m, 64);
        if (ov1 > v1 || (ov1 == v1 && oi1 < i1)) {
            v2 = fmaxf(v1, ov2); v1 = ov1; i1 = oi1;
        } else {
            v2 = fmaxf(v2, ov1);
        }
    }
    v1 = __shfl(v1, 0, 64); v2 = __shfl(v2, 0, 64); i1 = __shfl(i1, 0, 64);

    if (v1 - v2 >= TAU) {
        if (l == 0) { zb[p] = i1; out_zbest[p] = (float)i1; }
        return;
    }

    // exact fp32 recheck of all 64 candidates (one per lane)
    int q = cand;
    float dot = 0.f, b2 = 0.f;
    if (bt_ok) {
        const float* br = bT + (size_t)q * C;
        const float* ap = a + p;
#pragma unroll 4
        for (int c = 0; c < C; c += 4) {
            float4 bv = *(const float4*)(br + c);
            dot += ap[(size_t)c * HW] * bv.x + ap[(size_t)(c + 1) * HW] * bv.y
                 + ap[(size_t)(c + 2) * HW] * bv.z + ap[(size_t)(c + 3) * HW] * bv.w;
            b2  += bv.x * bv.x + bv.y * bv.y + bv.z * bv.z + bv.w * bv.w;
        }
    } else {
#pragma unroll 8
        for (int c = 0; c < C; ++c) {
            float av = a[c * HW + p];
            float bv = b[c * HW + q];
            dot += av * bv; b2 += bv * bv;
        }
    }
    float s = dot / (sqrtf(b2 + EPS) + EPS);
#pragma unroll
    for (int m = 1; m < 64; m <<= 1) {
        float os = __shfl_xor(s, m, 64);
        int   oq = __shfl_xor(q, m, 64);
        if (os > s || (os == s && oq < q)) { s = os; q = oq; }
    }
    if (l == 0) { zb[p] = q; out_zbest[p] = (float)q; }
}

// ---------------------------------------------------------------------------
// transpose-gather z_new + fused cos-loss partials
// ---------------------------------------------------------------------------
__global__ __launch_bounds__(256) void gather_loss_kernel(
    const float* __restrict__ a, const float* __restrict__ dT,
    const int* __restrict__ zb, float* __restrict__ out,
    float* __restrict__ pdot, float* __restrict__ pa2, float* __restrict__ pt2)
{
    __shared__ float tile[64][65];
    __shared__ int qs[64];
    const int t = threadIdx.x;
    const int p0 = blockIdx.x * 64;
    const int c0 = blockIdx.y * 64;
    if (t < 64) qs[t] = zb[p0 + t];
    __syncthreads();

    {
        const int pl = t >> 2, sub = t & 3;
        const float* src = dT + (size_t)qs[pl] * C + c0 + sub * 16;
        float4 v0 = *(const float4*)(src);
        float4 v1 = *(const float4*)(src + 4);
        float4 v2 = *(const float4*)(src + 8);
        float4 v3 = *(const float4*)(src + 12);
        float* dst = &tile[pl][sub * 16];
        dst[0] = v0.x; dst[1] = v0.y; dst[2]  = v0.z; dst[3]  = v0.w;
        dst[4] = v1.x; dst[5] = v1.y; dst[6]  = v1.z; dst[7]  = v1.w;
        dst[8] = v2.x; dst[9] = v2.y; dst[10] = v2.z; dst[11] = v2.w;
        dst[12] = v3.x; dst[13] = v3.y; dst[14] = v3.z; dst[15] = v3.w;
    }
    __syncthreads();

    const int p = t & 63, cg = t >> 6;
    float dot = 0.f, a2 = 0.f, t2 = 0.f;
#pragma unroll
    for (int i = 0; i < 16; ++i) {
        int cc = cg * 16 + i;
        float tv = tile[p][cc];
        float av = a[(size_t)(c0 + cc) * HW + p0 + p];
        out[1 + (size_t)(c0 + cc) * HW + p0 + p] = tv;
        dot += av * tv; a2 += av * av; t2 += tv * tv;
    }
    __shared__ float r1[256], r2[256], r3[256];
    r1[t] = dot; r2[t] = a2; r3[t] = t2;
    __syncthreads();
    if (t < 64) {
        dot = r1[t] + r1[t + 64] + r1[t + 128] + r1[t + 192];
        a2  = r2[t] + r2[t + 64] + r2[t + 128] + r2[t + 192];
        t2  = r3[t] + r3[t + 64] + r3[t + 128] + r3[t + 192];
        pdot[blockIdx.y * HW + p0 + t] = dot;
        pa2[blockIdx.y * HW + p0 + t]  = a2;
        pt2[blockIdx.y * HW + p0 + t]  = t2;
    }
}

// backup gather (no dT) — only if workspace too small
__global__ __launch_bounds__(256) void gather_partial_kernel(
    const float* __restrict__ a, const float* __restrict__ d,
    const int* __restrict__ zb, float* __restrict__ out,
    float* __restrict__ pdot, float* __restrict__ pa2, float* __restrict__ pt2)
{
    int p = blockIdx.x * 256 + threadIdx.x;
    int ch = blockIdx.y;
    int c0 = ch * (C / NCH_OLD);
    int q = zb[p];
    float dot = 0.f, a2 = 0.f, t2 = 0.f;
#pragma unroll
    for (int c = c0; c < c0 + C / NCH_OLD; ++c) {
        float av = a[c * HW + p];
        float tv = d[c * HW + q];
        dot += av * tv; a2 += av * av; t2 += tv * tv;
        out[1 + c * HW + p] = tv;
    }
    pdot[ch * HW + p] = dot;
    pa2[ch * HW + p] = a2;
    pt2[ch * HW + p] = t2;
}

__global__ __launch_bounds__(256) void loss_finalize_kernel(
    const float* __restrict__ pdot, const float* __restrict__ pa2,
    const float* __restrict__ pt2, float* __restrict__ out, int nch)
{
    int p = blockIdx.x * 256 + threadIdx.x;
    float dot = 0.f, a2 = 0.f, t2 = 0.f;
#pragma unroll 12
    for (int ch = 0; ch < nch; ++ch) {
        dot += pdot[ch * HW + p];
        a2  += pa2[ch * HW + p];
        t2  += pt2[ch * HW + p];
    }
    float cs = dot / ((sqrtf(a2) + EPS) * (sqrtf(t2) + EPS));
    float contrib = 1.f - cs;
    __shared__ float red[256];
    red[threadIdx.x] = contrib;
    __syncthreads();
    for (int s = 128; s > 0; s >>= 1) {
        if (threadIdx.x < s) red[threadIdx.x] += red[threadIdx.x + s];
        __syncthreads();
    }
    if (threadIdx.x == 0) atomicAdd(out, red[0] * (1.0f / HW));
}

// ---------------------------------------------------------------------------
// fp32 fallback GEMM path (only if ws too small for bf16 packs)
// ---------------------------------------------------------------------------
__global__ __launch_bounds__(256) void bnorm_partial_fb_kernel(
    const float* __restrict__ b, float* __restrict__ nbp)
{
    int q = blockIdx.x * 256 + threadIdx.x;
    int c0 = blockIdx.y * 32;
    float s = 0.f;
#pragma unroll 8
    for (int c = c0; c < c0 + 32; ++c) { float v = b[c * HW + q]; s += v * v; }
    nbp[blockIdx.y * HW + q] = s;
}

__global__ __launch_bounds__(256) void bnorm_finalize_fb_kernel(
    const float* __restrict__ nbp, float* __restrict__ nb)
{
    int q = blockIdx.x * 256 + threadIdx.x;
    float s = 0.f;
#pragma unroll
    for (int ch = 0; ch < NKB; ++ch) s += nbp[ch * HW + q];
    nb[q] = sqrtf(s + EPS) + EPS;
}

__global__ __launch_bounds__(256) void gemm_argmax_fb_kernel(
    const float* __restrict__ A, const float* __restrict__ B,
    const float* __restrict__ nb,
    float* __restrict__ pval, int* __restrict__ pidx)
{
    __shared__ __align__(16) char smem[16384];
    float (*As)[128] = (float (*)[128])smem;
    float (*Bs)[128] = (float (*)[128])(smem + 4096);
    const int m0 = blockIdx.x * 128, q0 = blockIdx.y * 128;
    const int tid = threadIdx.x;
    const int tx = tid & 15, ty = tid >> 4;
    const int lr = tid >> 5, lc = (tid & 31) * 4;
    float acc[8][8] = {};
    for (int k0 = 0; k0 < C; k0 += 8) {
        *(float4*)&As[lr][lc] = *(const float4*)&A[(k0 + lr) * HW + m0 + lc];
        *(float4*)&Bs[lr][lc] = *(const float4*)&B[(k0 + lr) * HW + q0 + lc];
        __syncthreads();
#pragma unroll
        for (int kk = 0; kk < 8; ++kk) {
            float a8[8], b8[8];
            *(float4*)&a8[0] = *(float4*)&As[kk][ty * 8];
            *(float4*)&a8[4] = *(float4*)&As[kk][ty * 8 + 4];
            *(float4*)&b8[0] = *(float4*)&Bs[kk][tx * 8];
            *(float4*)&b8[4] = *(float4*)&Bs[kk][tx * 8 + 4];
#pragma unroll
            for (int i = 0; i < 8; ++i)
#pragma unroll
                for (int j = 0; j < 8; ++j) acc[i][j] += a8[i] * b8[j];
        }
        __syncthreads();
    }
    float nbv[8];
#pragma unroll
    for (int j = 0; j < 8; ++j) nbv[j] = nb[q0 + tx * 8 + j];
    float (*rv)[16] = (float (*)[16])smem;
    int   (*ri)[16] = (int   (*)[16])(smem + 8192);
#pragma unroll
    for (int i = 0; i < 8; ++i) {
        float bv = -INFINITY; int bi = 0;
#pragma unroll
        for (int j = 0; j < 8; ++j) {
            float s = acc[i][j] / nbv[j];
            int q = q0 + tx * 8 + j;
            if (s > bv) { bv = s; bi = q; }
        }
        rv[ty * 8 + i][tx] = bv;
        ri[ty * 8 + i][tx] = bi;
    }
    __syncthreads();
    if (tid < 128) {
        float bv = rv[tid][0]; int bi = ri[tid][0];
#pragma unroll
        for (int t = 1; t < 16; ++t) {
            float v = rv[tid][t]; int ii = ri[tid][t];
            if (v > bv || (v == bv && ii < bi)) { bv = v; bi = ii; }
        }
        pval[(m0 + tid) * NBN + blockIdx.y] = bv;
        pidx[(m0 + tid) * NBN + blockIdx.y] = bi;
    }
}

__global__ __launch_bounds__(256) void reduce_fb_kernel(
    const float* __restrict__ pval, const int* __restrict__ pidx,
    int* __restrict__ zb, float* __restrict__ out_zbest)
{
    int p = blockIdx.x * 256 + threadIdx.x;
    float bv = pval[p * NBN]; int bi = pidx[p * NBN];
#pragma unroll 8
    for (int t = 1; t < NBN; ++t) {
        float v = pval[p * NBN + t]; int ii = pidx[p * NBN + t];
        if (v > bv || (v == bv && ii < bi)) { bv = v; bi = ii; }
    }
    zb[p] = bi;
    out_zbest[p] = (float)bi;
}

extern "C" void kernel_launch(void* const* d_in, const int* in_sizes, int n_in,
                              void* d_out, int out_size, void* d_ws, size_t ws_size,
                              hipStream_t stream) {
    const float* a = (const float*)d_in[0];
    const float* b = (const float*)d_in[1];
    const float* d = (const float*)d_in[2];
    float* out = (float*)d_out;
    float* out_zbest = out + 1 + (size_t)C * HW;

    char* ws = (char*)d_ws;
    size_t off = 0;
    auto alloc = [&](size_t bytes) { void* p = ws + off; off = (off + bytes + 255) & ~(size_t)255; return p; };

    const size_t PACK = (size_t)C * HW * 2;  // 6.29 MB
    ushort_t* Ah = (ushort_t*)alloc(PACK);
    ushort_t* Bh = (ushort_t*)alloc(PACK);
    ushort_t* Bl = (ushort_t*)alloc(PACK);
    float* nbp = (float*)alloc((size_t)NKB * HW * 4);
    float* pv1 = (float*)alloc((size_t)HW * NBN * 4);
    int*   pi1 = (int*)alloc((size_t)HW * NBN * 4);
    float* pv2 = (float*)alloc((size_t)HW * NBN * 4);
    int*   pi2 = (int*)alloc((size_t)HW * NBN * 4);
    int*   zb  = (int*)alloc(HW * 4);
    float* pdot = (float*)alloc((size_t)NCH_OLD * HW * 4);
    float* pa2  = (float*)alloc((size_t)NCH_OLD * HW * 4);
    float* pt2  = (float*)alloc((size_t)NCH_OLD * HW * 4);
    size_t base_end = off;
    float* dT = (float*)alloc((size_t)C * HW * 4);   // 12.6 MB
    size_t dT_end = off;
    float* bT = (float*)alloc((size_t)C * HW * 4);   // 12.6 MB
    bool fast    = base_end <= ws_size;
    bool have_dT = dT_end <= ws_size;
    bool have_bT = off <= ws_size;

    hipMemsetAsync(d_out, 0, sizeof(float), stream);

    if (fast) {
        pack_kernel<<<dim3(HW / 256, NKB, 2), 256, 0, stream>>>(a, b, Ah, Bh, Bl, nbp);
        if (have_dT)
            transpose_kernel<<<dim3(C / 64, HW / 64, have_bT ? 2 : 1), 256, 0, stream>>>(d, b, dT, bT);
        gemm_mfma_kernel<<<dim3(HW / 128, HW / 128), 256, 0, stream>>>(
            Ah, Bh, Bl, nbp, pv1, pi1, pv2, pi2);
        reduce_recheck_kernel<<<HW, 64, 0, stream>>>(
            a, b, bT, have_bT ? 1 : 0, pv1, pi1, pv2, pi2, zb, out_zbest);
    } else {
        off = 0;
        float* nb = (float*)alloc(HW * 4);
        nbp = (float*)alloc((size_t)NKB * HW * 4);
        pv1 = (float*)alloc((size_t)HW * NBN * 4);
        pi1 = (int*)alloc((size_t)HW * NBN * 4);
        zb  = (int*)alloc(HW * 4);
        pdot = (float*)alloc((size_t)NCH_OLD * HW * 4);
        pa2  = (float*)alloc((size_t)NCH_OLD * HW * 4);
        pt2  = (float*)alloc((size_t)NCH_OLD * HW * 4);
        dT = (float*)alloc((size_t)C * HW * 4);
        have_dT = off <= ws_size;
        bnorm_partial_fb_kernel<<<dim3(HW / 256, NKB), 256, 0, stream>>>(b, nbp);
        bnorm_finalize_fb_kernel<<<HW / 256, 256, 0, stream>>>(nbp, nb);
        gemm_argmax_fb_kernel<<<dim3(HW / 128, HW / 128), 256, 0, stream>>>(a, b, nb, pv1, pi1);
        reduce_fb_kernel<<<HW / 256, 256, 0, stream>>>(pv1, pi1, zb, out_zbest);
        if (have_dT)
            transpose_kernel<<<dim3(C / 64, HW / 64, 1), 256, 0, stream>>>(d, b, dT, dT);
    }

    if (have_dT) {
        gather_loss_kernel<<<dim3(HW / 64, NCH_NEW), 256, 0, stream>>>(
            a, dT, zb, out, pdot, pa2, pt2);
        loss_finalize_kernel<<<HW / 256, 256, 0, stream>>>(pdot, pa2, pt2, out, NCH_NEW);
    } else {
        gather_partial_kernel<<<dim3(HW / 256, NCH_OLD), 256, 0, stream>>>(
            a, d, zb, out, pdot, pa2, pt2);
        loss_finalize_kernel<<<HW / 256, 256, 0, stream>>>(pdot, pa2, pt2, out, NCH_OLD);
    }
}

// Round 6
// 208.254 us; speedup vs baseline: 3.9832x; 1.0413x over previous
//
#include <hip/hip_runtime.h>
#include <math.h>

#define EPS  1e-8f
#define C    768
#define HW   4096
#define NKB  24           // k-blocks of 32 (C/32)
#define NBN  32           // q-tiles of 128 (HW/128)
#define TAU  0.016f       // scaled-sim margin for fp32 recheck (~7 sigma of 1-pass err)
#define NCH_OLD 48        // c-chunks for fallback gather

typedef float  floatx4 __attribute__((ext_vector_type(4)));
typedef short  shortx8 __attribute__((ext_vector_type(8)));
typedef unsigned short ushort_t;
typedef unsigned int   uint_t;
typedef __attribute__((address_space(1))) uint_t as1_uint;
typedef __attribute__((address_space(3))) uint_t as3_uint;

__device__ __forceinline__ ushort_t f2bf(float v) {
    uint_t u = __float_as_uint(v);
    uint_t r = (u + 0x7FFFu + ((u >> 16) & 1u)) >> 16;   // RNE
    return (ushort_t)r;
}
__device__ __forceinline__ void async_cp16(const ushort_t* g, ushort_t* l) {
    __builtin_amdgcn_global_load_lds((const as1_uint*)g, (as3_uint*)l, 16, 0, 0);
}

// ---------------------------------------------------------------------------
// pack: z=0: a -> Ah (bf16 hi). z=1: b -> Bh + nbp partials.
// Layout [kb][p][kk], 16B granule w stored at slot w ^ ((p>>1)&3) (bank
// swizzle; gemm's DMA copies this order contiguously into LDS).
// ---------------------------------------------------------------------------
__global__ __launch_bounds__(256) void pack_kernel(
    const float* __restrict__ a, const float* __restrict__ b,
    ushort_t* __restrict__ Ah, ushort_t* __restrict__ Bh,
    float* __restrict__ nbp)
{
    const int tid = threadIdx.x;
    const int p   = blockIdx.x * 256 + tid;
    const int kb  = blockIdx.y;
    const int z   = blockIdx.z;
    const int sw  = (p >> 1) & 3;
    const float* src = z ? b : a;
    ushort_t* dst = z ? Bh : Ah;

    ushort_t h[32];
    float s = 0.f;
#pragma unroll
    for (int r = 0; r < 32; ++r) {
        float v = src[(kb * 32 + r) * HW + p];
        s += v * v;
        h[r] = f2bf(v);
    }
    if (z) nbp[kb * HW + p] = s;

    uint_t hw_[16];
#pragma unroll
    for (int w = 0; w < 16; ++w)
        hw_[w] = (uint_t)h[2 * w] | ((uint_t)h[2 * w + 1] << 16);
    uint4* oh = (uint4*)(dst + (size_t)(kb * HW + p) * 32);
#pragma unroll
    for (int w = 0; w < 4; ++w)
        oh[w ^ sw] = make_uint4(hw_[4*w], hw_[4*w+1], hw_[4*w+2], hw_[4*w+3]);
}

// ---------------------------------------------------------------------------
// transpose [c][hw] -> [hw][c]: z=0: d->dT, z=1: b->bT
// ---------------------------------------------------------------------------
__global__ __launch_bounds__(256) void transpose_kernel(
    const float* __restrict__ d, const float* __restrict__ b,
    float* __restrict__ dT, float* __restrict__ bT)
{
    __shared__ float tile[64][65];
    const int t = threadIdx.x;
    const int c0 = blockIdx.x * 64;
    const int p0 = blockIdx.y * 64;
    const float* src = blockIdx.z ? b : d;
    float* dst = blockIdx.z ? bT : dT;
    const int x = t & 63, y4 = t >> 6;
#pragma unroll
    for (int i = 0; i < 16; ++i) {
        int c = y4 * 16 + i;
        tile[c][x] = src[(size_t)(c0 + c) * HW + p0 + x];
    }
    __syncthreads();
#pragma unroll
    for (int i = 0; i < 16; ++i) {
        int p = y4 * 16 + i;
        dst[(size_t)(p0 + p) * C + c0 + x] = tile[x][p];
    }
}

// ---------------------------------------------------------------------------
// 1-pass MFMA GEMM (Ah*Bh): 128x128 tile, per kb stage 16 KB, 16 MFMA/wave,
// 8 swizzled ds_read_b128/wave. nb from nbp in-block. Top-2 epilogue.
// ---------------------------------------------------------------------------
__global__ __launch_bounds__(256, 4) void gemm_mfma_kernel(
    const ushort_t* __restrict__ Ah, const ushort_t* __restrict__ Bh,
    const float* __restrict__ nbp,
    float* __restrict__ pv1, int* __restrict__ pi1,
    float* __restrict__ pv2, int* __restrict__ pi2)
{
    __shared__ __align__(16) char smem[16896];
    ushort_t* sA  = (ushort_t*)smem;             // 8 KB
    ushort_t* sB  = (ushort_t*)(smem + 8192);    // 8 KB
    float*    nb_s = (float*)(smem + 16384);     // 512 B

    const int tid  = threadIdx.x;
    const int lane = tid & 63;
    const int wave = tid >> 6;
    const int wm = wave >> 1, wn = wave & 1;
    const int bm = blockIdx.x, bn = blockIdx.y;
    const int l15 = lane & 15, l4 = lane >> 4;
    const int swz = (l15 >> 1) & 3;

    if (tid < 128) {
        float s = 0.f;
        int q = bn * 128 + tid;
#pragma unroll
        for (int ch = 0; ch < NKB; ++ch) s += nbp[ch * HW + q];
        nb_s[tid] = 1.0f / (sqrtf(s + EPS) + EPS);
    }

    floatx4 acc[4][4];
#pragma unroll
    for (int i = 0; i < 4; ++i)
#pragma unroll
        for (int j = 0; j < 4; ++j) acc[i][j] = (floatx4){0.f, 0.f, 0.f, 0.f};

    for (int kb = 0; kb < NKB; ++kb) {
        const size_t aoff = (size_t)(kb * HW + bm * 128) * 32 + tid * 8;
        const size_t boff = (size_t)(kb * HW + bn * 128) * 32 + tid * 8;
        async_cp16(Ah + aoff,        sA + tid * 8);
        async_cp16(Ah + aoff + 2048, sA + tid * 8 + 2048);
        async_cp16(Bh + boff,        sB + tid * 8);
        async_cp16(Bh + boff + 2048, sB + tid * 8 + 2048);
        __syncthreads();

        shortx8 af[4], bf_[4];
#pragma unroll
        for (int i = 0; i < 4; ++i)
            af[i] = *(const shortx8*)&sA[((wm * 4 + i) * 16 + l15) * 32 + ((l4 ^ swz) * 8)];
#pragma unroll
        for (int j = 0; j < 4; ++j)
            bf_[j] = *(const shortx8*)&sB[((wn * 4 + j) * 16 + l15) * 32 + ((l4 ^ swz) * 8)];
#pragma unroll
        for (int i = 0; i < 4; ++i)
#pragma unroll
            for (int j = 0; j < 4; ++j)
                acc[i][j] = __builtin_amdgcn_mfma_f32_16x16x32_bf16(af[i], bf_[j], acc[i][j], 0, 0, 0);
        __syncthreads();
    }

    float rnb[4];
#pragma unroll
    for (int j = 0; j < 4; ++j)
        rnb[j] = nb_s[wn * 64 + j * 16 + l15];

    float* lv1 = (float*)smem;
    int*   li1 = (int*)(smem + 1024);
    float* lv2 = (float*)(smem + 2048);
    int*   li2 = (int*)(smem + 3072);

#pragma unroll
    for (int i = 0; i < 4; ++i) {
#pragma unroll
        for (int r = 0; r < 4; ++r) {
            float v1 = -INFINITY, v2 = -INFINITY; int i1 = 0, i2 = 0;
#pragma unroll
            for (int j = 0; j < 4; ++j) {
                float sv = acc[i][j][r] * rnb[j];
                int q = bn * 128 + wn * 64 + j * 16 + l15;
                if (sv > v1) { v2 = v1; i2 = i1; v1 = sv; i1 = q; }
                else if (sv > v2) { v2 = sv; i2 = q; }
            }
#pragma unroll
            for (int m = 1; m < 16; m <<= 1) {
                float ov1 = __shfl_xor(v1, m, 64);
                int   oi1 = __shfl_xor(i1, m, 64);
                float ov2 = __shfl_xor(v2, m, 64);
                int   oi2 = __shfl_xor(i2, m, 64);
                if (ov1 > v1 || (ov1 == v1 && oi1 < i1)) {
                    if (v1 > ov2 || (v1 == ov2 && i1 < oi2)) { v2 = v1; i2 = i1; }
                    else { v2 = ov2; i2 = oi2; }
                    v1 = ov1; i1 = oi1;
                } else if (ov1 > v2 || (ov1 == v2 && oi1 < i2)) {
                    v2 = ov1; i2 = oi1;
                }
            }
            if (l15 == 0) {
                int pl = wm * 64 + i * 16 + l4 * 4 + r;
                lv1[pl * 2 + wn] = v1; li1[pl * 2 + wn] = i1;
                lv2[pl * 2 + wn] = v2; li2[pl * 2 + wn] = i2;
            }
        }
    }
    __syncthreads();
    if (tid < 128) {
        float v1 = lv1[tid * 2],     v2 = lv2[tid * 2];
        int   i1 = li1[tid * 2],     i2 = li2[tid * 2];
        float w1 = lv1[tid * 2 + 1], w2 = lv2[tid * 2 + 1];
        int   j1 = li1[tid * 2 + 1], j2 = li2[tid * 2 + 1];
        if (w1 > v1 || (w1 == v1 && j1 < i1)) {
            if (v1 > w2 || (v1 == w2 && i1 < j2)) { v2 = v1; i2 = i1; }
            else { v2 = w2; i2 = j2; }
            v1 = w1; i1 = j1;
        } else if (w1 > v2 || (w1 == v2 && j1 < i2)) {
            v2 = w1; i2 = j1;
        }
        int p = bm * 128 + tid;
        pv1[p * NBN + bn] = v1; pi1[p * NBN + bn] = i1;
        pv2[p * NBN + bn] = v2; pi2[p * NBN + bn] = i2;
    }
}

// ---------------------------------------------------------------------------
// finish: per block, 16 rows. Phase A: top-2 merge over 32 tiles + exact fp32
// recheck of flagged rows -> zb (+ float zbest out). Phase B: gather z_new
// from dT (coalesced), write coalesced, full cos-loss, one atomicAdd.
// ---------------------------------------------------------------------------
__global__ __launch_bounds__(256) void finish_kernel(
    const float* __restrict__ a, const float* __restrict__ b,
    const float* __restrict__ bT, int bt_ok,
    const float* __restrict__ dT,
    const float* __restrict__ pv1, const int* __restrict__ pi1,
    const float* __restrict__ pv2, const int* __restrict__ pi2,
    float* __restrict__ out)
{
    __shared__ int   qs[16];
    __shared__ float tile[16][65];      // 4.2 KB
    __shared__ float rd_[16][64];       // 4 KB
    __shared__ float ra_[16][64];
    __shared__ float rt_[16][64];

    const int t = threadIdx.x;
    const int wave = t >> 6, lane = t & 63;
    const int p0 = blockIdx.x * 16;
    float* out_zbest = out + 1 + (size_t)C * HW;

    // ---- phase A: zb for 4 rows per wave
    for (int r = 0; r < 4; ++r) {
        const int p = p0 + wave * 4 + r;
        const int tq = lane & 31;
        float v1, v2; int i1, cand;
        if (lane < 32) {
            v1 = pv1[p * NBN + tq]; i1 = pi1[p * NBN + tq]; v2 = pv2[p * NBN + tq];
            cand = i1;
        } else {
            v1 = -INFINITY; v2 = -INFINITY; i1 = 0x7fffffff;
            cand = pi2[p * NBN + tq];
        }
#pragma unroll
        for (int m = 1; m < 32; m <<= 1) {
            float ov1 = __shfl_xor(v1, m, 64);
            int   oi1 = __shfl_xor(i1, m, 64);
            float ov2 = __shfl_xor(v2, m, 64);
            if (ov1 > v1 || (ov1 == v1 && oi1 < i1)) {
                v2 = fmaxf(v1, ov2); v1 = ov1; i1 = oi1;
            } else {
                v2 = fmaxf(v2, ov1);
            }
        }
        v1 = __shfl(v1, 0, 64); v2 = __shfl(v2, 0, 64); i1 = __shfl(i1, 0, 64);

        int zq = i1;
        if (v1 - v2 < TAU) {
            int q = cand;
            float dot = 0.f, b2 = 0.f;
            if (bt_ok) {
                const float* br = bT + (size_t)q * C;
                const float* ap = a + p;
#pragma unroll 4
                for (int c = 0; c < C; c += 4) {
                    float4 bv = *(const float4*)(br + c);
                    dot += ap[(size_t)c * HW] * bv.x + ap[(size_t)(c + 1) * HW] * bv.y
                         + ap[(size_t)(c + 2) * HW] * bv.z + ap[(size_t)(c + 3) * HW] * bv.w;
                    b2  += bv.x * bv.x + bv.y * bv.y + bv.z * bv.z + bv.w * bv.w;
                }
            } else {
#pragma unroll 8
                for (int c = 0; c < C; ++c) {
                    float av = a[c * HW + p];
                    float bv = b[c * HW + q];
                    dot += av * bv; b2 += bv * bv;
                }
            }
            float s = dot / (sqrtf(b2 + EPS) + EPS);
#pragma unroll
            for (int m = 1; m < 64; m <<= 1) {
                float os = __shfl_xor(s, m, 64);
                int   oq = __shfl_xor(q, m, 64);
                if (os > s || (os == s && oq < q)) { s = os; q = oq; }
            }
            zq = q;
        }
        if (lane == 0) { qs[wave * 4 + r] = zq; out_zbest[p] = (float)zq; }
    }
    __syncthreads();

    // ---- phase B: gather + z_new write + loss partials
    const int cthr = t >> 2;   // 0..63 (c within tile)
    const int pq   = t & 3;    // p-quad
    float fd[4] = {0.f, 0.f, 0.f, 0.f};
    float fa[4] = {0.f, 0.f, 0.f, 0.f};
    float ft[4] = {0.f, 0.f, 0.f, 0.f};

    for (int ct = 0; ct < C / 64; ++ct) {
        const int c0 = ct * 64;
        {   // load dT tile: 16 threads per row, float4 each
            const int pl = t >> 4, s16 = t & 15;
            float4 v = *(const float4*)&dT[(size_t)qs[pl] * C + c0 + s16 * 4];
            tile[pl][s16 * 4 + 0] = v.x; tile[pl][s16 * 4 + 1] = v.y;
            tile[pl][s16 * 4 + 2] = v.z; tile[pl][s16 * 4 + 3] = v.w;
        }
        __syncthreads();
        const size_t row = (size_t)(c0 + cthr) * HW + p0 + pq * 4;
        float4 av = *(const float4*)&a[row];
        float tv0 = tile[pq * 4 + 0][cthr];
        float tv1 = tile[pq * 4 + 1][cthr];
        float tv2 = tile[pq * 4 + 2][cthr];
        float tv3 = tile[pq * 4 + 3][cthr];
        *(float4*)&out[1 + row] = make_float4(tv0, tv1, tv2, tv3);
        fd[0] += av.x * tv0; fa[0] += av.x * av.x; ft[0] += tv0 * tv0;
        fd[1] += av.y * tv1; fa[1] += av.y * av.y; ft[1] += tv1 * tv1;
        fd[2] += av.z * tv2; fa[2] += av.z * av.z; ft[2] += tv2 * tv2;
        fd[3] += av.w * tv3; fa[3] += av.w * av.w; ft[3] += tv3 * tv3;
        __syncthreads();
    }

#pragma unroll
    for (int i = 0; i < 4; ++i) {
        rd_[pq * 4 + i][cthr] = fd[i];
        ra_[pq * 4 + i][cthr] = fa[i];
        rt_[pq * 4 + i][cthr] = ft[i];
    }
    __syncthreads();
    if (t < 16) {
        float dot = 0.f, A2 = 0.f, T2 = 0.f;
        for (int c = 0; c < 64; ++c) {
            dot += rd_[t][c]; A2 += ra_[t][c]; T2 += rt_[t][c];
        }
        float cs = dot / ((sqrtf(A2) + EPS) * (sqrtf(T2) + EPS));
        tile[0][t] = 1.f - cs;
    }
    __syncthreads();
    if (t == 0) {
        float s = 0.f;
#pragma unroll
        for (int i = 0; i < 16; ++i) s += tile[0][i];
        atomicAdd(out, s * (1.0f / HW));
    }
}

// ---------------------------------------------------------------------------
// fp32 fallback path (only if workspace is unexpectedly small)
// ---------------------------------------------------------------------------
__global__ __launch_bounds__(256) void bnorm_partial_fb_kernel(
    const float* __restrict__ b, float* __restrict__ nbp)
{
    int q = blockIdx.x * 256 + threadIdx.x;
    int c0 = blockIdx.y * 32;
    float s = 0.f;
#pragma unroll 8
    for (int c = c0; c < c0 + 32; ++c) { float v = b[c * HW + q]; s += v * v; }
    nbp[blockIdx.y * HW + q] = s;
}

__global__ __launch_bounds__(256) void bnorm_finalize_fb_kernel(
    const float* __restrict__ nbp, float* __restrict__ nb)
{
    int q = blockIdx.x * 256 + threadIdx.x;
    float s = 0.f;
#pragma unroll
    for (int ch = 0; ch < NKB; ++ch) s += nbp[ch * HW + q];
    nb[q] = sqrtf(s + EPS) + EPS;
}

__global__ __launch_bounds__(256) void gemm_argmax_fb_kernel(
    const float* __restrict__ A, const float* __restrict__ B,
    const float* __restrict__ nb,
    float* __restrict__ pval, int* __restrict__ pidx)
{
    __shared__ __align__(16) char smem[16384];
    float (*As)[128] = (float (*)[128])smem;
    float (*Bs)[128] = (float (*)[128])(smem + 4096);
    const int m0 = blockIdx.x * 128, q0 = blockIdx.y * 128;
    const int tid = threadIdx.x;
    const int tx = tid & 15, ty = tid >> 4;
    const int lr = tid >> 5, lc = (tid & 31) * 4;
    float acc[8][8] = {};
    for (int k0 = 0; k0 < C; k0 += 8) {
        *(float4*)&As[lr][lc] = *(const float4*)&A[(k0 + lr) * HW + m0 + lc];
        *(float4*)&Bs[lr][lc] = *(const float4*)&B[(k0 + lr) * HW + q0 + lc];
        __syncthreads();
#pragma unroll
        for (int kk = 0; kk < 8; ++kk) {
            float a8[8], b8[8];
            *(float4*)&a8[0] = *(float4*)&As[kk][ty * 8];
            *(float4*)&a8[4] = *(float4*)&As[kk][ty * 8 + 4];
            *(float4*)&b8[0] = *(float4*)&Bs[kk][tx * 8];
            *(float4*)&b8[4] = *(float4*)&Bs[kk][tx * 8 + 4];
#pragma unroll
            for (int i = 0; i < 8; ++i)
#pragma unroll
                for (int j = 0; j < 8; ++j) acc[i][j] += a8[i] * b8[j];
        }
        __syncthreads();
    }
    float nbv[8];
#pragma unroll
    for (int j = 0; j < 8; ++j) nbv[j] = nb[q0 + tx * 8 + j];
    float (*rv)[16] = (float (*)[16])smem;
    int   (*ri)[16] = (int   (*)[16])(smem + 8192);
#pragma unroll
    for (int i = 0; i < 8; ++i) {
        float bv = -INFINITY; int bi = 0;
#pragma unroll
        for (int j = 0; j < 8; ++j) {
            float s = acc[i][j] / nbv[j];
            int q = q0 + tx * 8 + j;
            if (s > bv) { bv = s; bi = q; }
        }
        rv[ty * 8 + i][tx] = bv;
        ri[ty * 8 + i][tx] = bi;
    }
    __syncthreads();
    if (tid < 128) {
        float bv = rv[tid][0]; int bi = ri[tid][0];
#pragma unroll
        for (int t = 1; t < 16; ++t) {
            float v = rv[tid][t]; int ii = ri[tid][t];
            if (v > bv || (v == bv && ii < bi)) { bv = v; bi = ii; }
        }
        pval[(m0 + tid) * NBN + blockIdx.y] = bv;
        pidx[(m0 + tid) * NBN + blockIdx.y] = bi;
    }
}

__global__ __launch_bounds__(256) void reduce_fb_kernel(
    const float* __restrict__ pval, const int* __restrict__ pidx,
    int* __restrict__ zb, float* __restrict__ out_zbest)
{
    int p = blockIdx.x * 256 + threadIdx.x;
    float bv = pval[p * NBN]; int bi = pidx[p * NBN];
#pragma unroll 8
    for (int t = 1; t < NBN; ++t) {
        float v = pval[p * NBN + t]; int ii = pidx[p * NBN + t];
        if (v > bv || (v == bv && ii < bi)) { bv = v; bi = ii; }
    }
    zb[p] = bi;
    out_zbest[p] = (float)bi;
}

__global__ __launch_bounds__(256) void gather_partial_kernel(
    const float* __restrict__ a, const float* __restrict__ d,
    const int* __restrict__ zb, float* __restrict__ out,
    float* __restrict__ pdot, float* __restrict__ pa2, float* __restrict__ pt2)
{
    int p = blockIdx.x * 256 + threadIdx.x;
    int ch = blockIdx.y;
    int c0 = ch * (C / NCH_OLD);
    int q = zb[p];
    float dot = 0.f, a2 = 0.f, t2 = 0.f;
#pragma unroll
    for (int c = c0; c < c0 + C / NCH_OLD; ++c) {
        float av = a[c * HW + p];
        float tv = d[c * HW + q];
        dot += av * tv; a2 += av * av; t2 += tv * tv;
        out[1 + c * HW + p] = tv;
    }
    pdot[ch * HW + p] = dot;
    pa2[ch * HW + p] = a2;
    pt2[ch * HW + p] = t2;
}

__global__ __launch_bounds__(256) void loss_finalize_kernel(
    const float* __restrict__ pdot, const float* __restrict__ pa2,
    const float* __restrict__ pt2, float* __restrict__ out, int nch)
{
    int p = blockIdx.x * 256 + threadIdx.x;
    float dot = 0.f, a2 = 0.f, t2 = 0.f;
    for (int ch = 0; ch < nch; ++ch) {
        dot += pdot[ch * HW + p];
        a2  += pa2[ch * HW + p];
        t2  += pt2[ch * HW + p];
    }
    float cs = dot / ((sqrtf(a2) + EPS) * (sqrtf(t2) + EPS));
    float contrib = 1.f - cs;
    __shared__ float red[256];
    red[threadIdx.x] = contrib;
    __syncthreads();
    for (int s = 128; s > 0; s >>= 1) {
        if (threadIdx.x < s) red[threadIdx.x] += red[threadIdx.x + s];
        __syncthreads();
    }
    if (threadIdx.x == 0) atomicAdd(out, red[0] * (1.0f / HW));
}

extern "C" void kernel_launch(void* const* d_in, const int* in_sizes, int n_in,
                              void* d_out, int out_size, void* d_ws, size_t ws_size,
                              hipStream_t stream) {
    const float* a = (const float*)d_in[0];
    const float* b = (const float*)d_in[1];
    const float* d = (const float*)d_in[2];
    float* out = (float*)d_out;
    float* out_zbest = out + 1 + (size_t)C * HW;

    char* ws = (char*)d_ws;
    size_t off = 0;
    auto alloc = [&](size_t bytes) { void* p = ws + off; off = (off + bytes + 255) & ~(size_t)255; return p; };

    const size_t PACK = (size_t)C * HW * 2;  // 6.29 MB
    ushort_t* Ah = (ushort_t*)alloc(PACK);
    ushort_t* Bh = (ushort_t*)alloc(PACK);
    float* nbp = (float*)alloc((size_t)NKB * HW * 4);
    float* pv1 = (float*)alloc((size_t)HW * NBN * 4);
    int*   pi1 = (int*)alloc((size_t)HW * NBN * 4);
    float* pv2 = (float*)alloc((size_t)HW * NBN * 4);
    int*   pi2 = (int*)alloc((size_t)HW * NBN * 4);
    float* dT  = (float*)alloc((size_t)C * HW * 4);   // 12.6 MB
    size_t dT_end = off;
    float* bT  = (float*)alloc((size_t)C * HW * 4);   // 12.6 MB
    bool fast    = dT_end <= ws_size;                 // ~28.3 MB
    bool have_bT = off <= ws_size;                    // ~40.9 MB

    hipMemsetAsync(d_out, 0, sizeof(float), stream);

    if (fast) {
        pack_kernel<<<dim3(HW / 256, NKB, 2), 256, 0, stream>>>(a, b, Ah, Bh, nbp);
        transpose_kernel<<<dim3(C / 64, HW / 64, have_bT ? 2 : 1), 256, 0, stream>>>(d, b, dT, bT);
        gemm_mfma_kernel<<<dim3(HW / 128, HW / 128), 256, 0, stream>>>(
            Ah, Bh, nbp, pv1, pi1, pv2, pi2);
        finish_kernel<<<HW / 16, 256, 0, stream>>>(
            a, b, bT, have_bT ? 1 : 0, dT, pv1, pi1, pv2, pi2, out);
    } else {
        // compact fp32 fallback
        off = 0;
        float* nb = (float*)alloc(HW * 4);
        nbp = (float*)alloc((size_t)NKB * HW * 4);
        pv1 = (float*)alloc((size_t)HW * NBN * 4);
        pi1 = (int*)alloc((size_t)HW * NBN * 4);
        int* zb = (int*)alloc(HW * 4);
        float* pdot = (float*)alloc((size_t)NCH_OLD * HW * 4);
        float* pa2  = (float*)alloc((size_t)NCH_OLD * HW * 4);
        float* pt2  = (float*)alloc((size_t)NCH_OLD * HW * 4);
        bnorm_partial_fb_kernel<<<dim3(HW / 256, NKB), 256, 0, stream>>>(b, nbp);
        bnorm_finalize_fb_kernel<<<HW / 256, 256, 0, stream>>>(nbp, nb);
        gemm_argmax_fb_kernel<<<dim3(HW / 128, HW / 128), 256, 0, stream>>>(a, b, nb, pv1, pi1);
        reduce_fb_kernel<<<HW / 256, 256, 0, stream>>>(pv1, pi1, zb, out_zbest);
        gather_partial_kernel<<<dim3(HW / 256, NCH_OLD), 256, 0, stream>>>(
            a, d, zb, out, pdot, pa2, pt2);
        loss_finalize_kernel<<<HW / 256, 256, 0, stream>>>(pdot, pa2, pt2, out, NCH_OLD);
    }
}

// Round 7
// 185.586 us; speedup vs baseline: 4.4698x; 1.1221x over previous
//
#include <hip/hip_runtime.h>
#include <math.h>

#define EPS  1e-8f
#define C    768
#define HW   4096
#define NKB  24           // k-blocks of 32 (C/32)
#define NBN  32           // q-tiles of 128 (HW/128)
#define TAU  0.016f       // scaled-sim margin for fp32 recheck (~7 sigma of 1-pass err)
#define NCH_NEW 12        // c-tiles of 64 for transpose-gather
#define NCH_OLD 48        // c-chunks for fallback gather

typedef float  floatx4 __attribute__((ext_vector_type(4)));
typedef short  shortx8 __attribute__((ext_vector_type(8)));
typedef unsigned short ushort_t;
typedef unsigned int   uint_t;
typedef __attribute__((address_space(1))) uint_t as1_uint;
typedef __attribute__((address_space(3))) uint_t as3_uint;

__device__ __forceinline__ ushort_t f2bf(float v) {
    uint_t u = __float_as_uint(v);
    uint_t r = (u + 0x7FFFu + ((u >> 16) & 1u)) >> 16;   // RNE
    return (ushort_t)r;
}
__device__ __forceinline__ void async_cp16(const ushort_t* g, ushort_t* l) {
    __builtin_amdgcn_global_load_lds((const as1_uint*)g, (as3_uint*)l, 16, 0, 0);
}

// ---------------------------------------------------------------------------
// pack: z=0: a -> Ah (bf16 hi). z=1: b -> Bh + nbp partials.
// Layout [kb][p][kk], 16B granule w stored at slot w ^ ((p>>1)&3) (bank
// swizzle; gemm's DMA copies this order contiguously into LDS).
// ---------------------------------------------------------------------------
__global__ __launch_bounds__(256) void pack_kernel(
    const float* __restrict__ a, const float* __restrict__ b,
    ushort_t* __restrict__ Ah, ushort_t* __restrict__ Bh,
    float* __restrict__ nbp)
{
    const int tid = threadIdx.x;
    const int p   = blockIdx.x * 256 + tid;
    const int kb  = blockIdx.y;
    const int z   = blockIdx.z;
    const int sw  = (p >> 1) & 3;
    const float* src = z ? b : a;
    ushort_t* dst = z ? Bh : Ah;

    ushort_t h[32];
    float s = 0.f;
#pragma unroll
    for (int r = 0; r < 32; ++r) {
        float v = src[(kb * 32 + r) * HW + p];
        s += v * v;
        h[r] = f2bf(v);
    }
    if (z) nbp[kb * HW + p] = s;

    uint_t hw_[16];
#pragma unroll
    for (int w = 0; w < 16; ++w)
        hw_[w] = (uint_t)h[2 * w] | ((uint_t)h[2 * w + 1] << 16);
    uint4* oh = (uint4*)(dst + (size_t)(kb * HW + p) * 32);
#pragma unroll
    for (int w = 0; w < 4; ++w)
        oh[w ^ sw] = make_uint4(hw_[4*w], hw_[4*w+1], hw_[4*w+2], hw_[4*w+3]);
}

// ---------------------------------------------------------------------------
// transpose [c][hw] -> [hw][c]: z=0: d->dT, z=1: b->bT
// ---------------------------------------------------------------------------
__global__ __launch_bounds__(256) void transpose_kernel(
    const float* __restrict__ d, const float* __restrict__ b,
    float* __restrict__ dT, float* __restrict__ bT)
{
    __shared__ float tile[64][65];
    const int t = threadIdx.x;
    const int c0 = blockIdx.x * 64;
    const int p0 = blockIdx.y * 64;
    const float* src = blockIdx.z ? b : d;
    float* dst = blockIdx.z ? bT : dT;
    const int x = t & 63, y4 = t >> 6;
#pragma unroll
    for (int i = 0; i < 16; ++i) {
        int c = y4 * 16 + i;
        tile[c][x] = src[(size_t)(c0 + c) * HW + p0 + x];
    }
    __syncthreads();
#pragma unroll
    for (int i = 0; i < 16; ++i) {
        int p = y4 * 16 + i;
        dst[(size_t)(p0 + p) * C + c0 + x] = tile[x][p];
    }
}

// ---------------------------------------------------------------------------
// 1-pass MFMA GEMM (Ah*Bh): 128x128 tile, per kb stage 16 KB, 16 MFMA/wave,
// 8 swizzled ds_read_b128/wave. nb from nbp in-block. Top-2 epilogue.
// ---------------------------------------------------------------------------
__global__ __launch_bounds__(256, 4) void gemm_mfma_kernel(
    const ushort_t* __restrict__ Ah, const ushort_t* __restrict__ Bh,
    const float* __restrict__ nbp,
    float* __restrict__ pv1, int* __restrict__ pi1,
    float* __restrict__ pv2, int* __restrict__ pi2)
{
    __shared__ __align__(16) char smem[16896];
    ushort_t* sA  = (ushort_t*)smem;             // 8 KB
    ushort_t* sB  = (ushort_t*)(smem + 8192);    // 8 KB
    float*    nb_s = (float*)(smem + 16384);     // 512 B

    const int tid  = threadIdx.x;
    const int lane = tid & 63;
    const int wave = tid >> 6;
    const int wm = wave >> 1, wn = wave & 1;
    const int bm = blockIdx.x, bn = blockIdx.y;
    const int l15 = lane & 15, l4 = lane >> 4;
    const int swz = (l15 >> 1) & 3;

    if (tid < 128) {
        float s = 0.f;
        int q = bn * 128 + tid;
#pragma unroll
        for (int ch = 0; ch < NKB; ++ch) s += nbp[ch * HW + q];
        nb_s[tid] = 1.0f / (sqrtf(s + EPS) + EPS);
    }

    floatx4 acc[4][4];
#pragma unroll
    for (int i = 0; i < 4; ++i)
#pragma unroll
        for (int j = 0; j < 4; ++j) acc[i][j] = (floatx4){0.f, 0.f, 0.f, 0.f};

    for (int kb = 0; kb < NKB; ++kb) {
        const size_t aoff = (size_t)(kb * HW + bm * 128) * 32 + tid * 8;
        const size_t boff = (size_t)(kb * HW + bn * 128) * 32 + tid * 8;
        async_cp16(Ah + aoff,        sA + tid * 8);
        async_cp16(Ah + aoff + 2048, sA + tid * 8 + 2048);
        async_cp16(Bh + boff,        sB + tid * 8);
        async_cp16(Bh + boff + 2048, sB + tid * 8 + 2048);
        __syncthreads();

        shortx8 af[4], bf_[4];
#pragma unroll
        for (int i = 0; i < 4; ++i)
            af[i] = *(const shortx8*)&sA[((wm * 4 + i) * 16 + l15) * 32 + ((l4 ^ swz) * 8)];
#pragma unroll
        for (int j = 0; j < 4; ++j)
            bf_[j] = *(const shortx8*)&sB[((wn * 4 + j) * 16 + l15) * 32 + ((l4 ^ swz) * 8)];
#pragma unroll
        for (int i = 0; i < 4; ++i)
#pragma unroll
            for (int j = 0; j < 4; ++j)
                acc[i][j] = __builtin_amdgcn_mfma_f32_16x16x32_bf16(af[i], bf_[j], acc[i][j], 0, 0, 0);
        __syncthreads();
    }

    float rnb[4];
#pragma unroll
    for (int j = 0; j < 4; ++j)
        rnb[j] = nb_s[wn * 64 + j * 16 + l15];

    float* lv1 = (float*)smem;
    int*   li1 = (int*)(smem + 1024);
    float* lv2 = (float*)(smem + 2048);
    int*   li2 = (int*)(smem + 3072);

#pragma unroll
    for (int i = 0; i < 4; ++i) {
#pragma unroll
        for (int r = 0; r < 4; ++r) {
            float v1 = -INFINITY, v2 = -INFINITY; int i1 = 0, i2 = 0;
#pragma unroll
            for (int j = 0; j < 4; ++j) {
                float sv = acc[i][j][r] * rnb[j];
                int q = bn * 128 + wn * 64 + j * 16 + l15;
                if (sv > v1) { v2 = v1; i2 = i1; v1 = sv; i1 = q; }
                else if (sv > v2) { v2 = sv; i2 = q; }
            }
#pragma unroll
            for (int m = 1; m < 16; m <<= 1) {
                float ov1 = __shfl_xor(v1, m, 64);
                int   oi1 = __shfl_xor(i1, m, 64);
                float ov2 = __shfl_xor(v2, m, 64);
                int   oi2 = __shfl_xor(i2, m, 64);
                if (ov1 > v1 || (ov1 == v1 && oi1 < i1)) {
                    if (v1 > ov2 || (v1 == ov2 && i1 < oi2)) { v2 = v1; i2 = i1; }
                    else { v2 = ov2; i2 = oi2; }
                    v1 = ov1; i1 = oi1;
                } else if (ov1 > v2 || (ov1 == v2 && oi1 < i2)) {
                    v2 = ov1; i2 = oi1;
                }
            }
            if (l15 == 0) {
                int pl = wm * 64 + i * 16 + l4 * 4 + r;
                lv1[pl * 2 + wn] = v1; li1[pl * 2 + wn] = i1;
                lv2[pl * 2 + wn] = v2; li2[pl * 2 + wn] = i2;
            }
        }
    }
    __syncthreads();
    if (tid < 128) {
        float v1 = lv1[tid * 2],     v2 = lv2[tid * 2];
        int   i1 = li1[tid * 2],     i2 = li2[tid * 2];
        float w1 = lv1[tid * 2 + 1], w2 = lv2[tid * 2 + 1];
        int   j1 = li1[tid * 2 + 1], j2 = li2[tid * 2 + 1];
        if (w1 > v1 || (w1 == v1 && j1 < i1)) {
            if (v1 > w2 || (v1 == w2 && i1 < j2)) { v2 = v1; i2 = i1; }
            else { v2 = w2; i2 = j2; }
            v1 = w1; i1 = j1;
        } else if (w1 > v2 || (w1 == v2 && j1 < i2)) {
            v2 = w1; i2 = j1;
        }
        int p = bm * 128 + tid;
        pv1[p * NBN + bn] = v1; pi1[p * NBN + bn] = i1;
        pv2[p * NBN + bn] = v2; pi2[p * NBN + bn] = i2;
    }
}

// ---------------------------------------------------------------------------
// reduce+recheck: 4 rows per block (1 per wave). Top-2 merge over 32 tiles;
// flagged rows get exact fp32 recheck over the 64 per-tile top-2 candidates.
// ---------------------------------------------------------------------------
__global__ __launch_bounds__(256) void reduce_recheck_kernel(
    const float* __restrict__ a, const float* __restrict__ b,
    const float* __restrict__ bT, int bt_ok,
    const float* __restrict__ pv1, const int* __restrict__ pi1,
    const float* __restrict__ pv2, const int* __restrict__ pi2,
    int* __restrict__ zb, float* __restrict__ out_zbest)
{
    const int wave = threadIdx.x >> 6, lane = threadIdx.x & 63;
    const int p = blockIdx.x * 4 + wave;
    const int tq = lane & 31;

    float v1, v2; int i1, cand;
    if (lane < 32) {
        v1 = pv1[p * NBN + tq]; i1 = pi1[p * NBN + tq]; v2 = pv2[p * NBN + tq];
        cand = i1;
    } else {
        v1 = -INFINITY; v2 = -INFINITY; i1 = 0x7fffffff;
        cand = pi2[p * NBN + tq];
    }
#pragma unroll
    for (int m = 1; m < 32; m <<= 1) {
        float ov1 = __shfl_xor(v1, m, 64);
        int   oi1 = __shfl_xor(i1, m, 64);
        float ov2 = __shfl_xor(v2, m, 64);
        if (ov1 > v1 || (ov1 == v1 && oi1 < i1)) {
            v2 = fmaxf(v1, ov2); v1 = ov1; i1 = oi1;
        } else {
            v2 = fmaxf(v2, ov1);
        }
    }
    v1 = __shfl(v1, 0, 64); v2 = __shfl(v2, 0, 64); i1 = __shfl(i1, 0, 64);

    if (v1 - v2 >= TAU) {
        if (lane == 0) { zb[p] = i1; out_zbest[p] = (float)i1; }
        return;
    }

    int q = cand;
    float dot = 0.f, b2 = 0.f;
    if (bt_ok) {
        const float* br = bT + (size_t)q * C;
        const float* ap = a + p;
#pragma unroll 4
        for (int c = 0; c < C; c += 4) {
            float4 bv = *(const float4*)(br + c);
            dot += ap[(size_t)c * HW] * bv.x + ap[(size_t)(c + 1) * HW] * bv.y
                 + ap[(size_t)(c + 2) * HW] * bv.z + ap[(size_t)(c + 3) * HW] * bv.w;
            b2  += bv.x * bv.x + bv.y * bv.y + bv.z * bv.z + bv.w * bv.w;
        }
    } else {
#pragma unroll 8
        for (int c = 0; c < C; ++c) {
            float av = a[c * HW + p];
            float bv = b[c * HW + q];
            dot += av * bv; b2 += bv * bv;
        }
    }
    float s = dot / (sqrtf(b2 + EPS) + EPS);
#pragma unroll
    for (int m = 1; m < 64; m <<= 1) {
        float os = __shfl_xor(s, m, 64);
        int   oq = __shfl_xor(q, m, 64);
        if (os > s || (os == s && oq < q)) { s = os; q = oq; }
    }
    if (lane == 0) { zb[p] = q; out_zbest[p] = (float)q; }
}

// ---------------------------------------------------------------------------
// transpose-gather z_new + fused cos-loss partials (64p x 64c tile per block)
// ---------------------------------------------------------------------------
__global__ __launch_bounds__(256) void gather_loss_kernel(
    const float* __restrict__ a, const float* __restrict__ dT,
    const int* __restrict__ zb, float* __restrict__ out,
    float* __restrict__ pdot, float* __restrict__ pa2, float* __restrict__ pt2)
{
    __shared__ float tile[64][65];
    __shared__ int qs[64];
    const int t = threadIdx.x;
    const int p0 = blockIdx.x * 64;
    const int c0 = blockIdx.y * 64;
    if (t < 64) qs[t] = zb[p0 + t];
    __syncthreads();

    {
        const int pl = t >> 2, sub = t & 3;
        const float* src = dT + (size_t)qs[pl] * C + c0 + sub * 16;
        float4 v0 = *(const float4*)(src);
        float4 v1 = *(const float4*)(src + 4);
        float4 v2 = *(const float4*)(src + 8);
        float4 v3 = *(const float4*)(src + 12);
        float* dst = &tile[pl][sub * 16];
        dst[0] = v0.x; dst[1] = v0.y; dst[2]  = v0.z; dst[3]  = v0.w;
        dst[4] = v1.x; dst[5] = v1.y; dst[6]  = v1.z; dst[7]  = v1.w;
        dst[8] = v2.x; dst[9] = v2.y; dst[10] = v2.z; dst[11] = v2.w;
        dst[12] = v3.x; dst[13] = v3.y; dst[14] = v3.z; dst[15] = v3.w;
    }
    __syncthreads();

    const int p = t & 63, cg = t >> 6;
    float dot = 0.f, a2 = 0.f, t2 = 0.f;
#pragma unroll
    for (int i = 0; i < 16; ++i) {
        int cc = cg * 16 + i;
        float tv = tile[p][cc];
        float av = a[(size_t)(c0 + cc) * HW + p0 + p];
        out[1 + (size_t)(c0 + cc) * HW + p0 + p] = tv;
        dot += av * tv; a2 += av * av; t2 += tv * tv;
    }
    __shared__ float r1[256], r2[256], r3[256];
    r1[t] = dot; r2[t] = a2; r3[t] = t2;
    __syncthreads();
    if (t < 64) {
        dot = r1[t] + r1[t + 64] + r1[t + 128] + r1[t + 192];
        a2  = r2[t] + r2[t + 64] + r2[t + 128] + r2[t + 192];
        t2  = r3[t] + r3[t + 64] + r3[t + 128] + r3[t + 192];
        pdot[blockIdx.y * HW + p0 + t] = dot;
        pa2[blockIdx.y * HW + p0 + t]  = a2;
        pt2[blockIdx.y * HW + p0 + t]  = t2;
    }
}

__global__ __launch_bounds__(256) void loss_finalize_kernel(
    const float* __restrict__ pdot, const float* __restrict__ pa2,
    const float* __restrict__ pt2, float* __restrict__ out, int nch)
{
    int p = blockIdx.x * 256 + threadIdx.x;
    float dot = 0.f, a2 = 0.f, t2 = 0.f;
#pragma unroll 12
    for (int ch = 0; ch < nch; ++ch) {
        dot += pdot[ch * HW + p];
        a2  += pa2[ch * HW + p];
        t2  += pt2[ch * HW + p];
    }
    float cs = dot / ((sqrtf(a2) + EPS) * (sqrtf(t2) + EPS));
    float contrib = 1.f - cs;
    __shared__ float red[256];
    red[threadIdx.x] = contrib;
    __syncthreads();
    for (int s = 128; s > 0; s >>= 1) {
        if (threadIdx.x < s) red[threadIdx.x] += red[threadIdx.x + s];
        __syncthreads();
    }
    if (threadIdx.x == 0) atomicAdd(out, red[0] * (1.0f / HW));
}

// ---------------------------------------------------------------------------
// fp32 fallback path (only if workspace is unexpectedly small)
// ---------------------------------------------------------------------------
__global__ __launch_bounds__(256) void bnorm_partial_fb_kernel(
    const float* __restrict__ b, float* __restrict__ nbp)
{
    int q = blockIdx.x * 256 + threadIdx.x;
    int c0 = blockIdx.y * 32;
    float s = 0.f;
#pragma unroll 8
    for (int c = c0; c < c0 + 32; ++c) { float v = b[c * HW + q]; s += v * v; }
    nbp[blockIdx.y * HW + q] = s;
}

__global__ __launch_bounds__(256) void bnorm_finalize_fb_kernel(
    const float* __restrict__ nbp, float* __restrict__ nb)
{
    int q = blockIdx.x * 256 + threadIdx.x;
    float s = 0.f;
#pragma unroll
    for (int ch = 0; ch < NKB; ++ch) s += nbp[ch * HW + q];
    nb[q] = sqrtf(s + EPS) + EPS;
}

__global__ __launch_bounds__(256) void gemm_argmax_fb_kernel(
    const float* __restrict__ A, const float* __restrict__ B,
    const float* __restrict__ nb,
    float* __restrict__ pval, int* __restrict__ pidx)
{
    __shared__ __align__(16) char smem[16384];
    float (*As)[128] = (float (*)[128])smem;
    float (*Bs)[128] = (float (*)[128])(smem + 4096);
    const int m0 = blockIdx.x * 128, q0 = blockIdx.y * 128;
    const int tid = threadIdx.x;
    const int tx = tid & 15, ty = tid >> 4;
    const int lr = tid >> 5, lc = (tid & 31) * 4;
    float acc[8][8] = {};
    for (int k0 = 0; k0 < C; k0 += 8) {
        *(float4*)&As[lr][lc] = *(const float4*)&A[(k0 + lr) * HW + m0 + lc];
        *(float4*)&Bs[lr][lc] = *(const float4*)&B[(k0 + lr) * HW + q0 + lc];
        __syncthreads();
#pragma unroll
        for (int kk = 0; kk < 8; ++kk) {
            float a8[8], b8[8];
            *(float4*)&a8[0] = *(float4*)&As[kk][ty * 8];
            *(float4*)&a8[4] = *(float4*)&As[kk][ty * 8 + 4];
            *(float4*)&b8[0] = *(float4*)&Bs[kk][tx * 8];
            *(float4*)&b8[4] = *(float4*)&Bs[kk][tx * 8 + 4];
#pragma unroll
            for (int i = 0; i < 8; ++i)
#pragma unroll
                for (int j = 0; j < 8; ++j) acc[i][j] += a8[i] * b8[j];
        }
        __syncthreads();
    }
    float nbv[8];
#pragma unroll
    for (int j = 0; j < 8; ++j) nbv[j] = nb[q0 + tx * 8 + j];
    float (*rv)[16] = (float (*)[16])smem;
    int   (*ri)[16] = (int   (*)[16])(smem + 8192);
#pragma unroll
    for (int i = 0; i < 8; ++i) {
        float bv = -INFINITY; int bi = 0;
#pragma unroll
        for (int j = 0; j < 8; ++j) {
            float s = acc[i][j] / nbv[j];
            int q = q0 + tx * 8 + j;
            if (s > bv) { bv = s; bi = q; }
        }
        rv[ty * 8 + i][tx] = bv;
        ri[ty * 8 + i][tx] = bi;
    }
    __syncthreads();
    if (tid < 128) {
        float bv = rv[tid][0]; int bi = ri[tid][0];
#pragma unroll
        for (int t = 1; t < 16; ++t) {
            float v = rv[tid][t]; int ii = ri[tid][t];
            if (v > bv || (v == bv && ii < bi)) { bv = v; bi = ii; }
        }
        pval[(m0 + tid) * NBN + blockIdx.y] = bv;
        pidx[(m0 + tid) * NBN + blockIdx.y] = bi;
    }
}

__global__ __launch_bounds__(256) void reduce_fb_kernel(
    const float* __restrict__ pval, const int* __restrict__ pidx,
    int* __restrict__ zb, float* __restrict__ out_zbest)
{
    int p = blockIdx.x * 256 + threadIdx.x;
    float bv = pval[p * NBN]; int bi = pidx[p * NBN];
#pragma unroll 8
    for (int t = 1; t < NBN; ++t) {
        float v = pval[p * NBN + t]; int ii = pidx[p * NBN + t];
        if (v > bv || (v == bv && ii < bi)) { bv = v; bi = ii; }
    }
    zb[p] = bi;
    out_zbest[p] = (float)bi;
}

__global__ __launch_bounds__(256) void gather_partial_kernel(
    const float* __restrict__ a, const float* __restrict__ d,
    const int* __restrict__ zb, float* __restrict__ out,
    float* __restrict__ pdot, float* __restrict__ pa2, float* __restrict__ pt2)
{
    int p = blockIdx.x * 256 + threadIdx.x;
    int ch = blockIdx.y;
    int c0 = ch * (C / NCH_OLD);
    int q = zb[p];
    float dot = 0.f, a2 = 0.f, t2 = 0.f;
#pragma unroll
    for (int c = c0; c < c0 + C / NCH_OLD; ++c) {
        float av = a[c * HW + p];
        float tv = d[c * HW + q];
        dot += av * tv; a2 += av * av; t2 += tv * tv;
        out[1 + c * HW + p] = tv;
    }
    pdot[ch * HW + p] = dot;
    pa2[ch * HW + p] = a2;
    pt2[ch * HW + p] = t2;
}

extern "C" void kernel_launch(void* const* d_in, const int* in_sizes, int n_in,
                              void* d_out, int out_size, void* d_ws, size_t ws_size,
                              hipStream_t stream) {
    const float* a = (const float*)d_in[0];
    const float* b = (const float*)d_in[1];
    const float* d = (const float*)d_in[2];
    float* out = (float*)d_out;
    float* out_zbest = out + 1 + (size_t)C * HW;

    char* ws = (char*)d_ws;
    size_t off = 0;
    auto alloc = [&](size_t bytes) { void* p = ws + off; off = (off + bytes + 255) & ~(size_t)255; return p; };

    const size_t PACK = (size_t)C * HW * 2;  // 6.29 MB
    ushort_t* Ah = (ushort_t*)alloc(PACK);
    ushort_t* Bh = (ushort_t*)alloc(PACK);
    float* nbp = (float*)alloc((size_t)NKB * HW * 4);
    float* pv1 = (float*)alloc((size_t)HW * NBN * 4);
    int*   pi1 = (int*)alloc((size_t)HW * NBN * 4);
    float* pv2 = (float*)alloc((size_t)HW * NBN * 4);
    int*   pi2 = (int*)alloc((size_t)HW * NBN * 4);
    int*   zb  = (int*)alloc(HW * 4);
    float* pdot = (float*)alloc((size_t)NCH_NEW * HW * 4);
    float* pa2  = (float*)alloc((size_t)NCH_NEW * HW * 4);
    float* pt2  = (float*)alloc((size_t)NCH_NEW * HW * 4);
    float* dT  = (float*)alloc((size_t)C * HW * 4);   // 12.6 MB
    size_t dT_end = off;
    float* bT  = (float*)alloc((size_t)C * HW * 4);   // 12.6 MB
    bool fast    = dT_end <= ws_size;                 // ~29 MB
    bool have_bT = off <= ws_size;                    // ~41 MB

    hipMemsetAsync(d_out, 0, sizeof(float), stream);

    if (fast) {
        pack_kernel<<<dim3(HW / 256, NKB, 2), 256, 0, stream>>>(a, b, Ah, Bh, nbp);
        transpose_kernel<<<dim3(C / 64, HW / 64, have_bT ? 2 : 1), 256, 0, stream>>>(d, b, dT, bT);
        gemm_mfma_kernel<<<dim3(HW / 128, HW / 128), 256, 0, stream>>>(
            Ah, Bh, nbp, pv1, pi1, pv2, pi2);
        reduce_recheck_kernel<<<HW / 4, 256, 0, stream>>>(
            a, b, bT, have_bT ? 1 : 0, pv1, pi1, pv2, pi2, zb, out_zbest);
        gather_loss_kernel<<<dim3(HW / 64, NCH_NEW), 256, 0, stream>>>(
            a, dT, zb, out, pdot, pa2, pt2);
        loss_finalize_kernel<<<HW / 256, 256, 0, stream>>>(pdot, pa2, pt2, out, NCH_NEW);
    } else {
        // compact fp32 fallback
        off = 0;
        float* nb = (float*)alloc(HW * 4);
        nbp = (float*)alloc((size_t)NKB * HW * 4);
        pv1 = (float*)alloc((size_t)HW * NBN * 4);
        pi1 = (int*)alloc((size_t)HW * NBN * 4);
        zb  = (int*)alloc(HW * 4);
        float* pdot2 = (float*)alloc((size_t)NCH_OLD * HW * 4);
        float* pa22  = (float*)alloc((size_t)NCH_OLD * HW * 4);
        float* pt22  = (float*)alloc((size_t)NCH_OLD * HW * 4);
        bnorm_partial_fb_kernel<<<dim3(HW / 256, NKB), 256, 0, stream>>>(b, nbp);
        bnorm_finalize_fb_kernel<<<HW / 256, 256, 0, stream>>>(nbp, nb);
        gemm_argmax_fb_kernel<<<dim3(HW / 128, HW / 128), 256, 0, stream>>>(a, b, nb, pv1, pi1);
        reduce_fb_kernel<<<HW / 256, 256, 0, stream>>>(pv1, pi1, zb, out_zbest);
        gather_partial_kernel<<<dim3(HW / 256, NCH_OLD), 256, 0, stream>>>(
            a, d, zb, out, pdot2, pa22, pt22);
        loss_finalize_kernel<<<HW / 256, 256, 0, stream>>>(pdot2, pa22, pt22, out, NCH_OLD);
    }
}

// Round 8
// 185.371 us; speedup vs baseline: 4.4749x; 1.0012x over previous
//
#include <hip/hip_runtime.h>
#include <math.h>

#define EPS  1e-8f
#define C    768
#define HW   4096
#define NKB  24           // k-blocks of 32 (C/32)
#define NNB  12           // nbp2 chunks of 64 c (fast path)
#define NBN  32           // q-tiles of 128 (HW/128)
#define TAU  0.016f       // scaled-sim margin for fp32 recheck (~7 sigma of 1-pass err)
#define NCH_NEW 12        // c-tiles of 64 for transpose-gather
#define NCH_OLD 48        // c-chunks for fallback gather

typedef float  floatx4 __attribute__((ext_vector_type(4)));
typedef short  shortx8 __attribute__((ext_vector_type(8)));
typedef unsigned short ushort_t;
typedef unsigned int   uint_t;
typedef __attribute__((address_space(1))) uint_t as1_uint;
typedef __attribute__((address_space(3))) uint_t as3_uint;

__device__ __forceinline__ ushort_t f2bf(float v) {
    uint_t u = __float_as_uint(v);
    uint_t r = (u + 0x7FFFu + ((u >> 16) & 1u)) >> 16;   // RNE
    return (ushort_t)r;
}
__device__ __forceinline__ void async_cp16(const ushort_t* g, ushort_t* l) {
    __builtin_amdgcn_global_load_lds((const as1_uint*)g, (as3_uint*)l, 16, 0, 0);
}

// ---------------------------------------------------------------------------
// prep: one pass over a,b,d per 64p x 64c tile.
//   d -> dT (fp32 transpose)
//   b -> bT (fp32 transpose) + Bh (bf16 [kb][p][kk], XOR-swizzled granules)
//        + nbp2 partial (sum b^2 over the tile's 64 c)
//   a -> Ah (bf16 packed, same layout)
// ---------------------------------------------------------------------------
__global__ __launch_bounds__(256) void prep_kernel(
    const float* __restrict__ a, const float* __restrict__ b,
    const float* __restrict__ d,
    ushort_t* __restrict__ Ah, ushort_t* __restrict__ Bh,
    float* __restrict__ dT, float* __restrict__ bT,
    float* __restrict__ nbp2)
{
    __shared__ float tile[64][65];
    const int t = threadIdx.x;
    const int p0 = blockIdx.x * 64;
    const int c0 = blockIdx.y * 64;
    const int x = t & 63, y4 = t >> 6;
    const int pl = t >> 2, g = t & 3;          // pack: thread -> (p-local, granule)
    const int pg = p0 + pl;
    const int sw = (pg >> 1) & 3;

    // ---- d -> dT
#pragma unroll
    for (int i = 0; i < 16; ++i) {
        int c = y4 * 16 + i;
        tile[c][x] = d[(size_t)(c0 + c) * HW + p0 + x];
    }
    __syncthreads();
#pragma unroll
    for (int i = 0; i < 16; ++i) {
        int p = y4 * 16 + i;
        dT[(size_t)(p0 + p) * C + c0 + x] = tile[x][p];
    }
    __syncthreads();

    // ---- b -> bT + Bh + nbp2
#pragma unroll
    for (int i = 0; i < 16; ++i) {
        int c = y4 * 16 + i;
        tile[c][x] = b[(size_t)(c0 + c) * HW + p0 + x];
    }
    __syncthreads();
#pragma unroll
    for (int i = 0; i < 16; ++i) {
        int p = y4 * 16 + i;
        bT[(size_t)(p0 + p) * C + c0 + x] = tile[x][p];
    }
#pragma unroll
    for (int h = 0; h < 2; ++h) {
        const int kb = (c0 >> 5) + h;
        uint_t w[4];
#pragma unroll
        for (int u = 0; u < 4; ++u) {
            ushort_t lo = f2bf(tile[h * 32 + g * 8 + 2 * u][pl]);
            ushort_t hi = f2bf(tile[h * 32 + g * 8 + 2 * u + 1][pl]);
            w[u] = (uint_t)lo | ((uint_t)hi << 16);
        }
        uint4* oh = (uint4*)(Bh + ((size_t)kb * HW + pg) * 32);
        oh[g ^ sw] = make_uint4(w[0], w[1], w[2], w[3]);
    }
    if (t < 64) {
        float s = 0.f;
#pragma unroll
        for (int c = 0; c < 64; ++c) { float v = tile[c][t]; s += v * v; }
        nbp2[blockIdx.y * HW + p0 + t] = s;
    }
    __syncthreads();

    // ---- a -> Ah
#pragma unroll
    for (int i = 0; i < 16; ++i) {
        int c = y4 * 16 + i;
        tile[c][x] = a[(size_t)(c0 + c) * HW + p0 + x];
    }
    __syncthreads();
#pragma unroll
    for (int h = 0; h < 2; ++h) {
        const int kb = (c0 >> 5) + h;
        uint_t w[4];
#pragma unroll
        for (int u = 0; u < 4; ++u) {
            ushort_t lo = f2bf(tile[h * 32 + g * 8 + 2 * u][pl]);
            ushort_t hi = f2bf(tile[h * 32 + g * 8 + 2 * u + 1][pl]);
            w[u] = (uint_t)lo | ((uint_t)hi << 16);
        }
        uint4* oh = (uint4*)(Ah + ((size_t)kb * HW + pg) * 32);
        oh[g ^ sw] = make_uint4(w[0], w[1], w[2], w[3]);
    }
}

// ---------------------------------------------------------------------------
// 1-pass MFMA GEMM, BK=64: per iteration stage 2 consecutive kb's (32 KB),
// one barrier pair, 32 MFMA/wave, 16 swizzled ds_read_b128/wave.
// nb from nbp2 (12 chunks) in-block. Top-2 epilogue per 128-q tile.
// ---------------------------------------------------------------------------
__global__ __launch_bounds__(256, 4) void gemm_mfma_kernel(
    const ushort_t* __restrict__ Ah, const ushort_t* __restrict__ Bh,
    const float* __restrict__ nbp2,
    float* __restrict__ pv1, int* __restrict__ pi1,
    float* __restrict__ pv2, int* __restrict__ pi2)
{
    __shared__ __align__(16) char smem[33280];
    ushort_t* sA  = (ushort_t*)smem;             // 16 KB (2 kb-halves)
    ushort_t* sB  = (ushort_t*)(smem + 16384);   // 16 KB
    float*    nb_s = (float*)(smem + 32768);     // 512 B

    const int tid  = threadIdx.x;
    const int lane = tid & 63;
    const int wave = tid >> 6;
    const int wm = wave >> 1, wn = wave & 1;
    const int bm = blockIdx.x, bn = blockIdx.y;
    const int l15 = lane & 15, l4 = lane >> 4;
    const int swz = (l15 >> 1) & 3;

    if (tid < 128) {
        float s = 0.f;
        int q = bn * 128 + tid;
#pragma unroll
        for (int ch = 0; ch < NNB; ++ch) s += nbp2[ch * HW + q];
        nb_s[tid] = 1.0f / (sqrtf(s + EPS) + EPS);
    }

    floatx4 acc[4][4];
#pragma unroll
    for (int i = 0; i < 4; ++i)
#pragma unroll
        for (int j = 0; j < 4; ++j) acc[i][j] = (floatx4){0.f, 0.f, 0.f, 0.f};

    for (int kb = 0; kb < NKB; kb += 2) {
#pragma unroll
        for (int h = 0; h < 2; ++h) {
            const size_t aoff = (size_t)((kb + h) * HW + bm * 128) * 32 + tid * 8;
            const size_t boff = (size_t)((kb + h) * HW + bn * 128) * 32 + tid * 8;
            async_cp16(Ah + aoff,        sA + h * 4096 + tid * 8);
            async_cp16(Ah + aoff + 2048, sA + h * 4096 + tid * 8 + 2048);
            async_cp16(Bh + boff,        sB + h * 4096 + tid * 8);
            async_cp16(Bh + boff + 2048, sB + h * 4096 + tid * 8 + 2048);
        }
        __syncthreads();

#pragma unroll
        for (int h = 0; h < 2; ++h) {
            shortx8 af[4], bf_[4];
#pragma unroll
            for (int i = 0; i < 4; ++i)
                af[i] = *(const shortx8*)&sA[h * 4096 + ((wm * 4 + i) * 16 + l15) * 32 + ((l4 ^ swz) * 8)];
#pragma unroll
            for (int j = 0; j < 4; ++j)
                bf_[j] = *(const shortx8*)&sB[h * 4096 + ((wn * 4 + j) * 16 + l15) * 32 + ((l4 ^ swz) * 8)];
#pragma unroll
            for (int i = 0; i < 4; ++i)
#pragma unroll
                for (int j = 0; j < 4; ++j)
                    acc[i][j] = __builtin_amdgcn_mfma_f32_16x16x32_bf16(af[i], bf_[j], acc[i][j], 0, 0, 0);
        }
        __syncthreads();
    }

    float rnb[4];
#pragma unroll
    for (int j = 0; j < 4; ++j)
        rnb[j] = nb_s[wn * 64 + j * 16 + l15];

    float* lv1 = (float*)smem;
    int*   li1 = (int*)(smem + 1024);
    float* lv2 = (float*)(smem + 2048);
    int*   li2 = (int*)(smem + 3072);

#pragma unroll
    for (int i = 0; i < 4; ++i) {
#pragma unroll
        for (int r = 0; r < 4; ++r) {
            float v1 = -INFINITY, v2 = -INFINITY; int i1 = 0, i2 = 0;
#pragma unroll
            for (int j = 0; j < 4; ++j) {
                float sv = acc[i][j][r] * rnb[j];
                int q = bn * 128 + wn * 64 + j * 16 + l15;
                if (sv > v1) { v2 = v1; i2 = i1; v1 = sv; i1 = q; }
                else if (sv > v2) { v2 = sv; i2 = q; }
            }
#pragma unroll
            for (int m = 1; m < 16; m <<= 1) {
                float ov1 = __shfl_xor(v1, m, 64);
                int   oi1 = __shfl_xor(i1, m, 64);
                float ov2 = __shfl_xor(v2, m, 64);
                int   oi2 = __shfl_xor(i2, m, 64);
                if (ov1 > v1 || (ov1 == v1 && oi1 < i1)) {
                    if (v1 > ov2 || (v1 == ov2 && i1 < oi2)) { v2 = v1; i2 = i1; }
                    else { v2 = ov2; i2 = oi2; }
                    v1 = ov1; i1 = oi1;
                } else if (ov1 > v2 || (ov1 == v2 && oi1 < i2)) {
                    v2 = ov1; i2 = oi1;
                }
            }
            if (l15 == 0) {
                int pl = wm * 64 + i * 16 + l4 * 4 + r;
                lv1[pl * 2 + wn] = v1; li1[pl * 2 + wn] = i1;
                lv2[pl * 2 + wn] = v2; li2[pl * 2 + wn] = i2;
            }
        }
    }
    __syncthreads();
    if (tid < 128) {
        float v1 = lv1[tid * 2],     v2 = lv2[tid * 2];
        int   i1 = li1[tid * 2],     i2 = li2[tid * 2];
        float w1 = lv1[tid * 2 + 1], w2 = lv2[tid * 2 + 1];
        int   j1 = li1[tid * 2 + 1], j2 = li2[tid * 2 + 1];
        if (w1 > v1 || (w1 == v1 && j1 < i1)) {
            if (v1 > w2 || (v1 == w2 && i1 < j2)) { v2 = v1; i2 = i1; }
            else { v2 = w2; i2 = j2; }
            v1 = w1; i1 = j1;
        } else if (w1 > v2 || (w1 == v2 && j1 < i2)) {
            v2 = w1; i2 = j1;
        }
        int p = bm * 128 + tid;
        pv1[p * NBN + bn] = v1; pi1[p * NBN + bn] = i1;
        pv2[p * NBN + bn] = v2; pi2[p * NBN + bn] = i2;
    }
}

// ---------------------------------------------------------------------------
// reduce+recheck: 4 rows per block (1 per wave). Top-2 merge over 32 tiles;
// flagged rows get exact fp32 recheck over the 64 per-tile top-2 candidates.
// ---------------------------------------------------------------------------
__global__ __launch_bounds__(256) void reduce_recheck_kernel(
    const float* __restrict__ a, const float* __restrict__ b,
    const float* __restrict__ bT, int bt_ok,
    const float* __restrict__ pv1, const int* __restrict__ pi1,
    const float* __restrict__ pv2, const int* __restrict__ pi2,
    int* __restrict__ zb, float* __restrict__ out_zbest)
{
    const int wave = threadIdx.x >> 6, lane = threadIdx.x & 63;
    const int p = blockIdx.x * 4 + wave;
    const int tq = lane & 31;

    float v1, v2; int i1, cand;
    if (lane < 32) {
        v1 = pv1[p * NBN + tq]; i1 = pi1[p * NBN + tq]; v2 = pv2[p * NBN + tq];
        cand = i1;
    } else {
        v1 = -INFINITY; v2 = -INFINITY; i1 = 0x7fffffff;
        cand = pi2[p * NBN + tq];
    }
#pragma unroll
    for (int m = 1; m < 32; m <<= 1) {
        float ov1 = __shfl_xor(v1, m, 64);
        int   oi1 = __shfl_xor(i1, m, 64);
        float ov2 = __shfl_xor(v2, m, 64);
        if (ov1 > v1 || (ov1 == v1 && oi1 < i1)) {
            v2 = fmaxf(v1, ov2); v1 = ov1; i1 = oi1;
        } else {
            v2 = fmaxf(v2, ov1);
        }
    }
    v1 = __shfl(v1, 0, 64); v2 = __shfl(v2, 0, 64); i1 = __shfl(i1, 0, 64);

    if (v1 - v2 >= TAU) {
        if (lane == 0) { zb[p] = i1; out_zbest[p] = (float)i1; }
        return;
    }

    int q = cand;
    float dot = 0.f, b2 = 0.f;
    if (bt_ok) {
        const float* br = bT + (size_t)q * C;
        const float* ap = a + p;
#pragma unroll 4
        for (int c = 0; c < C; c += 4) {
            float4 bv = *(const float4*)(br + c);
            dot += ap[(size_t)c * HW] * bv.x + ap[(size_t)(c + 1) * HW] * bv.y
                 + ap[(size_t)(c + 2) * HW] * bv.z + ap[(size_t)(c + 3) * HW] * bv.w;
            b2  += bv.x * bv.x + bv.y * bv.y + bv.z * bv.z + bv.w * bv.w;
        }
    } else {
#pragma unroll 8
        for (int c = 0; c < C; ++c) {
            float av = a[c * HW + p];
            float bv = b[c * HW + q];
            dot += av * bv; b2 += bv * bv;
        }
    }
    float s = dot / (sqrtf(b2 + EPS) + EPS);
#pragma unroll
    for (int m = 1; m < 64; m <<= 1) {
        float os = __shfl_xor(s, m, 64);
        int   oq = __shfl_xor(q, m, 64);
        if (os > s || (os == s && oq < q)) { s = os; q = oq; }
    }
    if (lane == 0) { zb[p] = q; out_zbest[p] = (float)q; }
}

// ---------------------------------------------------------------------------
// transpose-gather z_new + fused cos-loss partials (64p x 64c tile per block)
// ---------------------------------------------------------------------------
__global__ __launch_bounds__(256) void gather_loss_kernel(
    const float* __restrict__ a, const float* __restrict__ dT,
    const int* __restrict__ zb, float* __restrict__ out,
    float* __restrict__ pdot, float* __restrict__ pa2, float* __restrict__ pt2)
{
    __shared__ float tile[64][65];
    __shared__ int qs[64];
    const int t = threadIdx.x;
    const int p0 = blockIdx.x * 64;
    const int c0 = blockIdx.y * 64;
    if (t < 64) qs[t] = zb[p0 + t];
    __syncthreads();

    {
        const int pl = t >> 2, sub = t & 3;
        const float* src = dT + (size_t)qs[pl] * C + c0 + sub * 16;
        float4 v0 = *(const float4*)(src);
        float4 v1 = *(const float4*)(src + 4);
        float4 v2 = *(const float4*)(src + 8);
        float4 v3 = *(const float4*)(src + 12);
        float* dst = &tile[pl][sub * 16];
        dst[0] = v0.x; dst[1] = v0.y; dst[2]  = v0.z; dst[3]  = v0.w;
        dst[4] = v1.x; dst[5] = v1.y; dst[6]  = v1.z; dst[7]  = v1.w;
        dst[8] = v2.x; dst[9] = v2.y; dst[10] = v2.z; dst[11] = v2.w;
        dst[12] = v3.x; dst[13] = v3.y; dst[14] = v3.z; dst[15] = v3.w;
    }
    __syncthreads();

    const int p = t & 63, cg = t >> 6;
    float dot = 0.f, a2 = 0.f, t2 = 0.f;
#pragma unroll
    for (int i = 0; i < 16; ++i) {
        int cc = cg * 16 + i;
        float tv = tile[p][cc];
        float av = a[(size_t)(c0 + cc) * HW + p0 + p];
        out[1 + (size_t)(c0 + cc) * HW + p0 + p] = tv;
        dot += av * tv; a2 += av * av; t2 += tv * tv;
    }
    __shared__ float r1[256], r2[256], r3[256];
    r1[t] = dot; r2[t] = a2; r3[t] = t2;
    __syncthreads();
    if (t < 64) {
        dot = r1[t] + r1[t + 64] + r1[t + 128] + r1[t + 192];
        a2  = r2[t] + r2[t + 64] + r2[t + 128] + r2[t + 192];
        t2  = r3[t] + r3[t + 64] + r3[t + 128] + r3[t + 192];
        pdot[blockIdx.y * HW + p0 + t] = dot;
        pa2[blockIdx.y * HW + p0 + t]  = a2;
        pt2[blockIdx.y * HW + p0 + t]  = t2;
    }
}

__global__ __launch_bounds__(256) void loss_finalize_kernel(
    const float* __restrict__ pdot, const float* __restrict__ pa2,
    const float* __restrict__ pt2, float* __restrict__ out, int nch)
{
    int p = blockIdx.x * 256 + threadIdx.x;
    float dot = 0.f, a2 = 0.f, t2 = 0.f;
#pragma unroll 12
    for (int ch = 0; ch < nch; ++ch) {
        dot += pdot[ch * HW + p];
        a2  += pa2[ch * HW + p];
        t2  += pt2[ch * HW + p];
    }
    float cs = dot / ((sqrtf(a2) + EPS) * (sqrtf(t2) + EPS));
    float contrib = 1.f - cs;
    __shared__ float red[256];
    red[threadIdx.x] = contrib;
    __syncthreads();
    for (int s = 128; s > 0; s >>= 1) {
        if (threadIdx.x < s) red[threadIdx.x] += red[threadIdx.x + s];
        __syncthreads();
    }
    if (threadIdx.x == 0) atomicAdd(out, red[0] * (1.0f / HW));
}

// ---------------------------------------------------------------------------
// fp32 fallback path (only if workspace is unexpectedly small)
// ---------------------------------------------------------------------------
__global__ __launch_bounds__(256) void bnorm_partial_fb_kernel(
    const float* __restrict__ b, float* __restrict__ nbp)
{
    int q = blockIdx.x * 256 + threadIdx.x;
    int c0 = blockIdx.y * 32;
    float s = 0.f;
#pragma unroll 8
    for (int c = c0; c < c0 + 32; ++c) { float v = b[c * HW + q]; s += v * v; }
    nbp[blockIdx.y * HW + q] = s;
}

__global__ __launch_bounds__(256) void bnorm_finalize_fb_kernel(
    const float* __restrict__ nbp, float* __restrict__ nb)
{
    int q = blockIdx.x * 256 + threadIdx.x;
    float s = 0.f;
#pragma unroll
    for (int ch = 0; ch < NKB; ++ch) s += nbp[ch * HW + q];
    nb[q] = sqrtf(s + EPS) + EPS;
}

__global__ __launch_bounds__(256) void gemm_argmax_fb_kernel(
    const float* __restrict__ A, const float* __restrict__ B,
    const float* __restrict__ nb,
    float* __restrict__ pval, int* __restrict__ pidx)
{
    __shared__ __align__(16) char smem[16384];
    float (*As)[128] = (float (*)[128])smem;
    float (*Bs)[128] = (float (*)[128])(smem + 4096);
    const int m0 = blockIdx.x * 128, q0 = blockIdx.y * 128;
    const int tid = threadIdx.x;
    const int tx = tid & 15, ty = tid >> 4;
    const int lr = tid >> 5, lc = (tid & 31) * 4;
    float acc[8][8] = {};
    for (int k0 = 0; k0 < C; k0 += 8) {
        *(float4*)&As[lr][lc] = *(const float4*)&A[(k0 + lr) * HW + m0 + lc];
        *(float4*)&Bs[lr][lc] = *(const float4*)&B[(k0 + lr) * HW + q0 + lc];
        __syncthreads();
#pragma unroll
        for (int kk = 0; kk < 8; ++kk) {
            float a8[8], b8[8];
            *(float4*)&a8[0] = *(float4*)&As[kk][ty * 8];
            *(float4*)&a8[4] = *(float4*)&As[kk][ty * 8 + 4];
            *(float4*)&b8[0] = *(float4*)&Bs[kk][tx * 8];
            *(float4*)&b8[4] = *(float4*)&Bs[kk][tx * 8 + 4];
#pragma unroll
            for (int i = 0; i < 8; ++i)
#pragma unroll
                for (int j = 0; j < 8; ++j) acc[i][j] += a8[i] * b8[j];
        }
        __syncthreads();
    }
    float nbv[8];
#pragma unroll
    for (int j = 0; j < 8; ++j) nbv[j] = nb[q0 + tx * 8 + j];
    float (*rv)[16] = (float (*)[16])smem;
    int   (*ri)[16] = (int   (*)[16])(smem + 8192);
#pragma unroll
    for (int i = 0; i < 8; ++i) {
        float bv = -INFINITY; int bi = 0;
#pragma unroll
        for (int j = 0; j < 8; ++j) {
            float s = acc[i][j] / nbv[j];
            int q = q0 + tx * 8 + j;
            if (s > bv) { bv = s; bi = q; }
        }
        rv[ty * 8 + i][tx] = bv;
        ri[ty * 8 + i][tx] = bi;
    }
    __syncthreads();
    if (tid < 128) {
        float bv = rv[tid][0]; int bi = ri[tid][0];
#pragma unroll
        for (int t = 1; t < 16; ++t) {
            float v = rv[tid][t]; int ii = ri[tid][t];
            if (v > bv || (v == bv && ii < bi)) { bv = v; bi = ii; }
        }
        pval[(m0 + tid) * NBN + blockIdx.y] = bv;
        pidx[(m0 + tid) * NBN + blockIdx.y] = bi;
    }
}

__global__ __launch_bounds__(256) void reduce_fb_kernel(
    const float* __restrict__ pval, const int* __restrict__ pidx,
    int* __restrict__ zb, float* __restrict__ out_zbest)
{
    int p = blockIdx.x * 256 + threadIdx.x;
    float bv = pval[p * NBN]; int bi = pidx[p * NBN];
#pragma unroll 8
    for (int t = 1; t < NBN; ++t) {
        float v = pval[p * NBN + t]; int ii = pidx[p * NBN + t];
        if (v > bv || (v == bv && ii < bi)) { bv = v; bi = ii; }
    }
    zb[p] = bi;
    out_zbest[p] = (float)bi;
}

__global__ __launch_bounds__(256) void gather_partial_kernel(
    const float* __restrict__ a, const float* __restrict__ d,
    const int* __restrict__ zb, float* __restrict__ out,
    float* __restrict__ pdot, float* __restrict__ pa2, float* __restrict__ pt2)
{
    int p = blockIdx.x * 256 + threadIdx.x;
    int ch = blockIdx.y;
    int c0 = ch * (C / NCH_OLD);
    int q = zb[p];
    float dot = 0.f, a2 = 0.f, t2 = 0.f;
#pragma unroll
    for (int c = c0; c < c0 + C / NCH_OLD; ++c) {
        float av = a[c * HW + p];
        float tv = d[c * HW + q];
        dot += av * tv; a2 += av * av; t2 += tv * tv;
        out[1 + c * HW + p] = tv;
    }
    pdot[ch * HW + p] = dot;
    pa2[ch * HW + p] = a2;
    pt2[ch * HW + p] = t2;
}

extern "C" void kernel_launch(void* const* d_in, const int* in_sizes, int n_in,
                              void* d_out, int out_size, void* d_ws, size_t ws_size,
                              hipStream_t stream) {
    const float* a = (const float*)d_in[0];
    const float* b = (const float*)d_in[1];
    const float* d = (const float*)d_in[2];
    float* out = (float*)d_out;
    float* out_zbest = out + 1 + (size_t)C * HW;

    char* ws = (char*)d_ws;
    size_t off = 0;
    auto alloc = [&](size_t bytes) { void* p = ws + off; off = (off + bytes + 255) & ~(size_t)255; return p; };

    const size_t PACK = (size_t)C * HW * 2;  // 6.29 MB
    ushort_t* Ah = (ushort_t*)alloc(PACK);
    ushort_t* Bh = (ushort_t*)alloc(PACK);
    float* nbp = (float*)alloc((size_t)NKB * HW * 4);
    float* pv1 = (float*)alloc((size_t)HW * NBN * 4);
    int*   pi1 = (int*)alloc((size_t)HW * NBN * 4);
    float* pv2 = (float*)alloc((size_t)HW * NBN * 4);
    int*   pi2 = (int*)alloc((size_t)HW * NBN * 4);
    int*   zb  = (int*)alloc(HW * 4);
    float* pdot = (float*)alloc((size_t)NCH_NEW * HW * 4);
    float* pa2  = (float*)alloc((size_t)NCH_NEW * HW * 4);
    float* pt2  = (float*)alloc((size_t)NCH_NEW * HW * 4);
    float* dT  = (float*)alloc((size_t)C * HW * 4);   // 12.6 MB
    float* bT  = (float*)alloc((size_t)C * HW * 4);   // 12.6 MB
    bool fast = off <= ws_size;                       // ~41 MB

    hipMemsetAsync(d_out, 0, sizeof(float), stream);

    if (fast) {
        prep_kernel<<<dim3(HW / 64, C / 64), 256, 0, stream>>>(
            a, b, d, Ah, Bh, dT, bT, nbp);
        gemm_mfma_kernel<<<dim3(HW / 128, HW / 128), 256, 0, stream>>>(
            Ah, Bh, nbp, pv1, pi1, pv2, pi2);
        reduce_recheck_kernel<<<HW / 4, 256, 0, stream>>>(
            a, b, bT, 1, pv1, pi1, pv2, pi2, zb, out_zbest);
        gather_loss_kernel<<<dim3(HW / 64, NCH_NEW), 256, 0, stream>>>(
            a, dT, zb, out, pdot, pa2, pt2);
        loss_finalize_kernel<<<HW / 256, 256, 0, stream>>>(pdot, pa2, pt2, out, NCH_NEW);
    } else {
        // compact fp32 fallback
        off = 0;
        float* nb = (float*)alloc(HW * 4);
        nbp = (float*)alloc((size_t)NKB * HW * 4);
        pv1 = (float*)alloc((size_t)HW * NBN * 4);
        pi1 = (int*)alloc((size_t)HW * NBN * 4);
        zb  = (int*)alloc(HW * 4);
        float* pdot2 = (float*)alloc((size_t)NCH_OLD * HW * 4);
        float* pa22  = (float*)alloc((size_t)NCH_OLD * HW * 4);
        float* pt22  = (float*)alloc((size_t)NCH_OLD * HW * 4);
        bnorm_partial_fb_kernel<<<dim3(HW / 256, NKB), 256, 0, stream>>>(b, nbp);
        bnorm_finalize_fb_kernel<<<HW / 256, 256, 0, stream>>>(nbp, nb);
        gemm_argmax_fb_kernel<<<dim3(HW / 128, HW / 128), 256, 0, stream>>>(a, b, nb, pv1, pi1);
        reduce_fb_kernel<<<HW / 256, 256, 0, stream>>>(pv1, pi1, zb, out_zbest);
        gather_partial_kernel<<<dim3(HW / 256, NCH_OLD), 256, 0, stream>>>(
            a, d, zb, out, pdot2, pa22, pt22);
        loss_finalize_kernel<<<HW / 256, 256, 0, stream>>>(pdot2, pa22, pt22, out, NCH_OLD);
    }
}

// Round 9
// 178.345 us; speedup vs baseline: 4.6512x; 1.0394x over previous
//
#include <hip/hip_runtime.h>
#include <math.h>

#define EPS  1e-8f
#define C    768
#define HW   4096
#define NKB  24           // k-blocks of 32 (C/32)
#define NNB  12           // nbp2 chunks of 64 c (fast path)
#define NBN  32           // q-tiles of 128 (HW/128)
#define TAU  0.016f       // scaled-sim margin for fp32 recheck (~7 sigma of 1-pass err)
#define NCH_NEW 12        // c-tiles of 64 for transpose-gather
#define NCH_OLD 48        // c-chunks for fallback gather

typedef float  floatx4 __attribute__((ext_vector_type(4)));
typedef short  shortx8 __attribute__((ext_vector_type(8)));
typedef unsigned short ushort_t;
typedef unsigned int   uint_t;
typedef __attribute__((address_space(1))) uint_t as1_uint;
typedef __attribute__((address_space(3))) uint_t as3_uint;

__device__ __forceinline__ ushort_t f2bf(float v) {
    uint_t u = __float_as_uint(v);
    uint_t r = (u + 0x7FFFu + ((u >> 16) & 1u)) >> 16;   // RNE
    return (ushort_t)r;
}
__device__ __forceinline__ void async_cp16(const ushort_t* g, ushort_t* l) {
    __builtin_amdgcn_global_load_lds((const as1_uint*)g, (as3_uint*)l, 16, 0, 0);
}

// ---------------------------------------------------------------------------
// prep: one pass over a,b,d per 64p x 64c tile.
//   d -> dT; b -> bT + Bh (bf16, XOR-swizzled granules) + nbp2; a -> Ah.
//   Block (0,0) also zeroes the loss accumulator (out[0]).
// ---------------------------------------------------------------------------
__global__ __launch_bounds__(256) void prep_kernel(
    const float* __restrict__ a, const float* __restrict__ b,
    const float* __restrict__ d,
    ushort_t* __restrict__ Ah, ushort_t* __restrict__ Bh,
    float* __restrict__ dT, float* __restrict__ bT,
    float* __restrict__ nbp2, float* __restrict__ out)
{
    __shared__ float tile[64][65];
    const int t = threadIdx.x;
    const int p0 = blockIdx.x * 64;
    const int c0 = blockIdx.y * 64;
    const int x = t & 63, y4 = t >> 6;
    const int pl = t >> 2, g = t & 3;          // pack: thread -> (p-local, granule)
    const int pg = p0 + pl;
    const int sw = (pg >> 1) & 3;

    if (blockIdx.x == 0 && blockIdx.y == 0 && t == 0) out[0] = 0.f;

    // ---- d -> dT
#pragma unroll
    for (int i = 0; i < 16; ++i) {
        int c = y4 * 16 + i;
        tile[c][x] = d[(size_t)(c0 + c) * HW + p0 + x];
    }
    __syncthreads();
#pragma unroll
    for (int i = 0; i < 16; ++i) {
        int p = y4 * 16 + i;
        dT[(size_t)(p0 + p) * C + c0 + x] = tile[x][p];
    }
    __syncthreads();

    // ---- b -> bT + Bh + nbp2
#pragma unroll
    for (int i = 0; i < 16; ++i) {
        int c = y4 * 16 + i;
        tile[c][x] = b[(size_t)(c0 + c) * HW + p0 + x];
    }
    __syncthreads();
#pragma unroll
    for (int i = 0; i < 16; ++i) {
        int p = y4 * 16 + i;
        bT[(size_t)(p0 + p) * C + c0 + x] = tile[x][p];
    }
#pragma unroll
    for (int h = 0; h < 2; ++h) {
        const int kb = (c0 >> 5) + h;
        uint_t w[4];
#pragma unroll
        for (int u = 0; u < 4; ++u) {
            ushort_t lo = f2bf(tile[h * 32 + g * 8 + 2 * u][pl]);
            ushort_t hi = f2bf(tile[h * 32 + g * 8 + 2 * u + 1][pl]);
            w[u] = (uint_t)lo | ((uint_t)hi << 16);
        }
        uint4* oh = (uint4*)(Bh + ((size_t)kb * HW + pg) * 32);
        oh[g ^ sw] = make_uint4(w[0], w[1], w[2], w[3]);
    }
    if (t < 64) {
        float s = 0.f;
#pragma unroll
        for (int c = 0; c < 64; ++c) { float v = tile[c][t]; s += v * v; }
        nbp2[blockIdx.y * HW + p0 + t] = s;
    }
    __syncthreads();

    // ---- a -> Ah
#pragma unroll
    for (int i = 0; i < 16; ++i) {
        int c = y4 * 16 + i;
        tile[c][x] = a[(size_t)(c0 + c) * HW + p0 + x];
    }
    __syncthreads();
#pragma unroll
    for (int h = 0; h < 2; ++h) {
        const int kb = (c0 >> 5) + h;
        uint_t w[4];
#pragma unroll
        for (int u = 0; u < 4; ++u) {
            ushort_t lo = f2bf(tile[h * 32 + g * 8 + 2 * u][pl]);
            ushort_t hi = f2bf(tile[h * 32 + g * 8 + 2 * u + 1][pl]);
            w[u] = (uint_t)lo | ((uint_t)hi << 16);
        }
        uint4* oh = (uint4*)(Ah + ((size_t)kb * HW + pg) * 32);
        oh[g ^ sw] = make_uint4(w[0], w[1], w[2], w[3]);
    }
}

// ---------------------------------------------------------------------------
// 1-pass MFMA GEMM (Ah*Bh), BK=32 (the proven R7 config): per kb stage 16 KB,
// one barrier pair, 16 MFMA/wave, 8 swizzled ds_read_b128/wave. nb from nbp2
// in-block. Top-2 epilogue per 128-q tile.
// ---------------------------------------------------------------------------
__global__ __launch_bounds__(256, 4) void gemm_mfma_kernel(
    const ushort_t* __restrict__ Ah, const ushort_t* __restrict__ Bh,
    const float* __restrict__ nbp2,
    float* __restrict__ pv1, int* __restrict__ pi1,
    float* __restrict__ pv2, int* __restrict__ pi2)
{
    __shared__ __align__(16) char smem[16896];
    ushort_t* sA  = (ushort_t*)smem;             // 8 KB
    ushort_t* sB  = (ushort_t*)(smem + 8192);    // 8 KB
    float*    nb_s = (float*)(smem + 16384);     // 512 B

    const int tid  = threadIdx.x;
    const int lane = tid & 63;
    const int wave = tid >> 6;
    const int wm = wave >> 1, wn = wave & 1;
    const int bm = blockIdx.x, bn = blockIdx.y;
    const int l15 = lane & 15, l4 = lane >> 4;
    const int swz = (l15 >> 1) & 3;

    if (tid < 128) {
        float s = 0.f;
        int q = bn * 128 + tid;
#pragma unroll
        for (int ch = 0; ch < NNB; ++ch) s += nbp2[ch * HW + q];
        nb_s[tid] = 1.0f / (sqrtf(s + EPS) + EPS);
    }

    floatx4 acc[4][4];
#pragma unroll
    for (int i = 0; i < 4; ++i)
#pragma unroll
        for (int j = 0; j < 4; ++j) acc[i][j] = (floatx4){0.f, 0.f, 0.f, 0.f};

    for (int kb = 0; kb < NKB; ++kb) {
        const size_t aoff = (size_t)(kb * HW + bm * 128) * 32 + tid * 8;
        const size_t boff = (size_t)(kb * HW + bn * 128) * 32 + tid * 8;
        async_cp16(Ah + aoff,        sA + tid * 8);
        async_cp16(Ah + aoff + 2048, sA + tid * 8 + 2048);
        async_cp16(Bh + boff,        sB + tid * 8);
        async_cp16(Bh + boff + 2048, sB + tid * 8 + 2048);
        __syncthreads();

        shortx8 af[4], bf_[4];
#pragma unroll
        for (int i = 0; i < 4; ++i)
            af[i] = *(const shortx8*)&sA[((wm * 4 + i) * 16 + l15) * 32 + ((l4 ^ swz) * 8)];
#pragma unroll
        for (int j = 0; j < 4; ++j)
            bf_[j] = *(const shortx8*)&sB[((wn * 4 + j) * 16 + l15) * 32 + ((l4 ^ swz) * 8)];
#pragma unroll
        for (int i = 0; i < 4; ++i)
#pragma unroll
            for (int j = 0; j < 4; ++j)
                acc[i][j] = __builtin_amdgcn_mfma_f32_16x16x32_bf16(af[i], bf_[j], acc[i][j], 0, 0, 0);
        __syncthreads();
    }

    float rnb[4];
#pragma unroll
    for (int j = 0; j < 4; ++j)
        rnb[j] = nb_s[wn * 64 + j * 16 + l15];

    float* lv1 = (float*)smem;
    int*   li1 = (int*)(smem + 1024);
    float* lv2 = (float*)(smem + 2048);
    int*   li2 = (int*)(smem + 3072);

#pragma unroll
    for (int i = 0; i < 4; ++i) {
#pragma unroll
        for (int r = 0; r < 4; ++r) {
            float v1 = -INFINITY, v2 = -INFINITY; int i1 = 0, i2 = 0;
#pragma unroll
            for (int j = 0; j < 4; ++j) {
                float sv = acc[i][j][r] * rnb[j];
                int q = bn * 128 + wn * 64 + j * 16 + l15;
                if (sv > v1) { v2 = v1; i2 = i1; v1 = sv; i1 = q; }
                else if (sv > v2) { v2 = sv; i2 = q; }
            }
#pragma unroll
            for (int m = 1; m < 16; m <<= 1) {
                float ov1 = __shfl_xor(v1, m, 64);
                int   oi1 = __shfl_xor(i1, m, 64);
                float ov2 = __shfl_xor(v2, m, 64);
                int   oi2 = __shfl_xor(i2, m, 64);
                if (ov1 > v1 || (ov1 == v1 && oi1 < i1)) {
                    if (v1 > ov2 || (v1 == ov2 && i1 < oi2)) { v2 = v1; i2 = i1; }
                    else { v2 = ov2; i2 = oi2; }
                    v1 = ov1; i1 = oi1;
                } else if (ov1 > v2 || (ov1 == v2 && oi1 < i2)) {
                    v2 = ov1; i2 = oi1;
                }
            }
            if (l15 == 0) {
                int pl = wm * 64 + i * 16 + l4 * 4 + r;
                lv1[pl * 2 + wn] = v1; li1[pl * 2 + wn] = i1;
                lv2[pl * 2 + wn] = v2; li2[pl * 2 + wn] = i2;
            }
        }
    }
    __syncthreads();
    if (tid < 128) {
        float v1 = lv1[tid * 2],     v2 = lv2[tid * 2];
        int   i1 = li1[tid * 2],     i2 = li2[tid * 2];
        float w1 = lv1[tid * 2 + 1], w2 = lv2[tid * 2 + 1];
        int   j1 = li1[tid * 2 + 1], j2 = li2[tid * 2 + 1];
        if (w1 > v1 || (w1 == v1 && j1 < i1)) {
            if (v1 > w2 || (v1 == w2 && i1 < j2)) { v2 = v1; i2 = i1; }
            else { v2 = w2; i2 = j2; }
            v1 = w1; i1 = j1;
        } else if (w1 > v2 || (w1 == v2 && j1 < i2)) {
            v2 = w1; i2 = j1;
        }
        int p = bm * 128 + tid;
        pv1[p * NBN + bn] = v1; pi1[p * NBN + bn] = i1;
        pv2[p * NBN + bn] = v2; pi2[p * NBN + bn] = i2;
    }
}

// ---------------------------------------------------------------------------
// reduce+recheck: 4 rows per block (1 per wave). Top-2 merge over 32 tiles;
// flagged rows get exact fp32 recheck over the 64 per-tile top-2 candidates.
// ---------------------------------------------------------------------------
__global__ __launch_bounds__(256) void reduce_recheck_kernel(
    const float* __restrict__ a, const float* __restrict__ b,
    const float* __restrict__ bT, int bt_ok,
    const float* __restrict__ pv1, const int* __restrict__ pi1,
    const float* __restrict__ pv2, const int* __restrict__ pi2,
    int* __restrict__ zb, float* __restrict__ out_zbest)
{
    const int wave = threadIdx.x >> 6, lane = threadIdx.x & 63;
    const int p = blockIdx.x * 4 + wave;
    const int tq = lane & 31;

    float v1, v2; int i1, cand;
    if (lane < 32) {
        v1 = pv1[p * NBN + tq]; i1 = pi1[p * NBN + tq]; v2 = pv2[p * NBN + tq];
        cand = i1;
    } else {
        v1 = -INFINITY; v2 = -INFINITY; i1 = 0x7fffffff;
        cand = pi2[p * NBN + tq];
    }
#pragma unroll
    for (int m = 1; m < 32; m <<= 1) {
        float ov1 = __shfl_xor(v1, m, 64);
        int   oi1 = __shfl_xor(i1, m, 64);
        float ov2 = __shfl_xor(v2, m, 64);
        if (ov1 > v1 || (ov1 == v1 && oi1 < i1)) {
            v2 = fmaxf(v1, ov2); v1 = ov1; i1 = oi1;
        } else {
            v2 = fmaxf(v2, ov1);
        }
    }
    v1 = __shfl(v1, 0, 64); v2 = __shfl(v2, 0, 64); i1 = __shfl(i1, 0, 64);

    if (v1 - v2 >= TAU) {
        if (lane == 0) { zb[p] = i1; out_zbest[p] = (float)i1; }
        return;
    }

    int q = cand;
    float dot = 0.f, b2 = 0.f;
    if (bt_ok) {
        const float* br = bT + (size_t)q * C;
        const float* ap = a + p;
#pragma unroll 4
        for (int c = 0; c < C; c += 4) {
            float4 bv = *(const float4*)(br + c);
            dot += ap[(size_t)c * HW] * bv.x + ap[(size_t)(c + 1) * HW] * bv.y
                 + ap[(size_t)(c + 2) * HW] * bv.z + ap[(size_t)(c + 3) * HW] * bv.w;
            b2  += bv.x * bv.x + bv.y * bv.y + bv.z * bv.z + bv.w * bv.w;
        }
    } else {
#pragma unroll 8
        for (int c = 0; c < C; ++c) {
            float av = a[c * HW + p];
            float bv = b[c * HW + q];
            dot += av * bv; b2 += bv * bv;
        }
    }
    float s = dot / (sqrtf(b2 + EPS) + EPS);
#pragma unroll
    for (int m = 1; m < 64; m <<= 1) {
        float os = __shfl_xor(s, m, 64);
        int   oq = __shfl_xor(q, m, 64);
        if (os > s || (os == s && oq < q)) { s = os; q = oq; }
    }
    if (lane == 0) { zb[p] = q; out_zbest[p] = (float)q; }
}

// ---------------------------------------------------------------------------
// transpose-gather z_new + fused cos-loss partials (64p x 64c tile per block)
// ---------------------------------------------------------------------------
__global__ __launch_bounds__(256) void gather_loss_kernel(
    const float* __restrict__ a, const float* __restrict__ dT,
    const int* __restrict__ zb, float* __restrict__ out,
    float* __restrict__ pdot, float* __restrict__ pa2, float* __restrict__ pt2)
{
    __shared__ float tile[64][65];
    __shared__ int qs[64];
    const int t = threadIdx.x;
    const int p0 = blockIdx.x * 64;
    const int c0 = blockIdx.y * 64;
    if (t < 64) qs[t] = zb[p0 + t];
    __syncthreads();

    {
        const int pl = t >> 2, sub = t & 3;
        const float* src = dT + (size_t)qs[pl] * C + c0 + sub * 16;
        float4 v0 = *(const float4*)(src);
        float4 v1 = *(const float4*)(src + 4);
        float4 v2 = *(const float4*)(src + 8);
        float4 v3 = *(const float4*)(src + 12);
        float* dst = &tile[pl][sub * 16];
        dst[0] = v0.x; dst[1] = v0.y; dst[2]  = v0.z; dst[3]  = v0.w;
        dst[4] = v1.x; dst[5] = v1.y; dst[6]  = v1.z; dst[7]  = v1.w;
        dst[8] = v2.x; dst[9] = v2.y; dst[10] = v2.z; dst[11] = v2.w;
        dst[12] = v3.x; dst[13] = v3.y; dst[14] = v3.z; dst[15] = v3.w;
    }
    __syncthreads();

    const int p = t & 63, cg = t >> 6;
    float dot = 0.f, a2 = 0.f, t2 = 0.f;
#pragma unroll
    for (int i = 0; i < 16; ++i) {
        int cc = cg * 16 + i;
        float tv = tile[p][cc];
        float av = a[(size_t)(c0 + cc) * HW + p0 + p];
        out[1 + (size_t)(c0 + cc) * HW + p0 + p] = tv;
        dot += av * tv; a2 += av * av; t2 += tv * tv;
    }
    __shared__ float r1[256], r2[256], r3[256];
    r1[t] = dot; r2[t] = a2; r3[t] = t2;
    __syncthreads();
    if (t < 64) {
        dot = r1[t] + r1[t + 64] + r1[t + 128] + r1[t + 192];
        a2  = r2[t] + r2[t + 64] + r2[t + 128] + r2[t + 192];
        t2  = r3[t] + r3[t + 64] + r3[t + 128] + r3[t + 192];
        pdot[blockIdx.y * HW + p0 + t] = dot;
        pa2[blockIdx.y * HW + p0 + t]  = a2;
        pt2[blockIdx.y * HW + p0 + t]  = t2;
    }
}

__global__ __launch_bounds__(256) void loss_finalize_kernel(
    const float* __restrict__ pdot, const float* __restrict__ pa2,
    const float* __restrict__ pt2, float* __restrict__ out, int nch)
{
    int p = blockIdx.x * 256 + threadIdx.x;
    float dot = 0.f, a2 = 0.f, t2 = 0.f;
#pragma unroll 12
    for (int ch = 0; ch < nch; ++ch) {
        dot += pdot[ch * HW + p];
        a2  += pa2[ch * HW + p];
        t2  += pt2[ch * HW + p];
    }
    float cs = dot / ((sqrtf(a2) + EPS) * (sqrtf(t2) + EPS));
    float contrib = 1.f - cs;
    __shared__ float red[256];
    red[threadIdx.x] = contrib;
    __syncthreads();
    for (int s = 128; s > 0; s >>= 1) {
        if (threadIdx.x < s) red[threadIdx.x] += red[threadIdx.x + s];
        __syncthreads();
    }
    if (threadIdx.x == 0) atomicAdd(out, red[0] * (1.0f / HW));
}

// ---------------------------------------------------------------------------
// fp32 fallback path (only if workspace is unexpectedly small)
// ---------------------------------------------------------------------------
__global__ __launch_bounds__(256) void bnorm_partial_fb_kernel(
    const float* __restrict__ b, float* __restrict__ nbp)
{
    int q = blockIdx.x * 256 + threadIdx.x;
    int c0 = blockIdx.y * 32;
    float s = 0.f;
#pragma unroll 8
    for (int c = c0; c < c0 + 32; ++c) { float v = b[c * HW + q]; s += v * v; }
    nbp[blockIdx.y * HW + q] = s;
}

__global__ __launch_bounds__(256) void bnorm_finalize_fb_kernel(
    const float* __restrict__ nbp, float* __restrict__ nb)
{
    int q = blockIdx.x * 256 + threadIdx.x;
    float s = 0.f;
#pragma unroll
    for (int ch = 0; ch < NKB; ++ch) s += nbp[ch * HW + q];
    nb[q] = sqrtf(s + EPS) + EPS;
}

__global__ __launch_bounds__(256) void gemm_argmax_fb_kernel(
    const float* __restrict__ A, const float* __restrict__ B,
    const float* __restrict__ nb,
    float* __restrict__ pval, int* __restrict__ pidx)
{
    __shared__ __align__(16) char smem[16384];
    float (*As)[128] = (float (*)[128])smem;
    float (*Bs)[128] = (float (*)[128])(smem + 4096);
    const int m0 = blockIdx.x * 128, q0 = blockIdx.y * 128;
    const int tid = threadIdx.x;
    const int tx = tid & 15, ty = tid >> 4;
    const int lr = tid >> 5, lc = (tid & 31) * 4;
    float acc[8][8] = {};
    for (int k0 = 0; k0 < C; k0 += 8) {
        *(float4*)&As[lr][lc] = *(const float4*)&A[(k0 + lr) * HW + m0 + lc];
        *(float4*)&Bs[lr][lc] = *(const float4*)&B[(k0 + lr) * HW + q0 + lc];
        __syncthreads();
#pragma unroll
        for (int kk = 0; kk < 8; ++kk) {
            float a8[8], b8[8];
            *(float4*)&a8[0] = *(float4*)&As[kk][ty * 8];
            *(float4*)&a8[4] = *(float4*)&As[kk][ty * 8 + 4];
            *(float4*)&b8[0] = *(float4*)&Bs[kk][tx * 8];
            *(float4*)&b8[4] = *(float4*)&Bs[kk][tx * 8 + 4];
#pragma unroll
            for (int i = 0; i < 8; ++i)
#pragma unroll
                for (int j = 0; j < 8; ++j) acc[i][j] += a8[i] * b8[j];
        }
        __syncthreads();
    }
    float nbv[8];
#pragma unroll
    for (int j = 0; j < 8; ++j) nbv[j] = nb[q0 + tx * 8 + j];
    float (*rv)[16] = (float (*)[16])smem;
    int   (*ri)[16] = (int   (*)[16])(smem + 8192);
#pragma unroll
    for (int i = 0; i < 8; ++i) {
        float bv = -INFINITY; int bi = 0;
#pragma unroll
        for (int j = 0; j < 8; ++j) {
            float s = acc[i][j] / nbv[j];
            int q = q0 + tx * 8 + j;
            if (s > bv) { bv = s; bi = q; }
        }
        rv[ty * 8 + i][tx] = bv;
        ri[ty * 8 + i][tx] = bi;
    }
    __syncthreads();
    if (tid < 128) {
        float bv = rv[tid][0]; int bi = ri[tid][0];
#pragma unroll
        for (int t = 1; t < 16; ++t) {
            float v = rv[tid][t]; int ii = ri[tid][t];
            if (v > bv || (v == bv && ii < bi)) { bv = v; bi = ii; }
        }
        pval[(m0 + tid) * NBN + blockIdx.y] = bv;
        pidx[(m0 + tid) * NBN + blockIdx.y] = bi;
    }
}

__global__ __launch_bounds__(256) void reduce_fb_kernel(
    const float* __restrict__ pval, const int* __restrict__ pidx,
    int* __restrict__ zb, float* __restrict__ out_zbest)
{
    int p = blockIdx.x * 256 + threadIdx.x;
    float bv = pval[p * NBN]; int bi = pidx[p * NBN];
#pragma unroll 8
    for (int t = 1; t < NBN; ++t) {
        float v = pval[p * NBN + t]; int ii = pidx[p * NBN + t];
        if (v > bv || (v == bv && ii < bi)) { bv = v; bi = ii; }
    }
    zb[p] = bi;
    out_zbest[p] = (float)bi;
}

__global__ __launch_bounds__(256) void gather_partial_kernel(
    const float* __restrict__ a, const float* __restrict__ d,
    const int* __restrict__ zb, float* __restrict__ out,
    float* __restrict__ pdot, float* __restrict__ pa2, float* __restrict__ pt2)
{
    int p = blockIdx.x * 256 + threadIdx.x;
    int ch = blockIdx.y;
    int c0 = ch * (C / NCH_OLD);
    int q = zb[p];
    float dot = 0.f, a2 = 0.f, t2 = 0.f;
#pragma unroll
    for (int c = c0; c < c0 + C / NCH_OLD; ++c) {
        float av = a[c * HW + p];
        float tv = d[c * HW + q];
        dot += av * tv; a2 += av * av; t2 += tv * tv;
        out[1 + c * HW + p] = tv;
    }
    pdot[ch * HW + p] = dot;
    pa2[ch * HW + p] = a2;
    pt2[ch * HW + p] = t2;
}

extern "C" void kernel_launch(void* const* d_in, const int* in_sizes, int n_in,
                              void* d_out, int out_size, void* d_ws, size_t ws_size,
                              hipStream_t stream) {
    const float* a = (const float*)d_in[0];
    const float* b = (const float*)d_in[1];
    const float* d = (const float*)d_in[2];
    float* out = (float*)d_out;
    float* out_zbest = out + 1 + (size_t)C * HW;

    char* ws = (char*)d_ws;
    size_t off = 0;
    auto alloc = [&](size_t bytes) { void* p = ws + off; off = (off + bytes + 255) & ~(size_t)255; return p; };

    const size_t PACK = (size_t)C * HW * 2;  // 6.29 MB
    ushort_t* Ah = (ushort_t*)alloc(PACK);
    ushort_t* Bh = (ushort_t*)alloc(PACK);
    float* nbp = (float*)alloc((size_t)NKB * HW * 4);
    float* pv1 = (float*)alloc((size_t)HW * NBN * 4);
    int*   pi1 = (int*)alloc((size_t)HW * NBN * 4);
    float* pv2 = (float*)alloc((size_t)HW * NBN * 4);
    int*   pi2 = (int*)alloc((size_t)HW * NBN * 4);
    int*   zb  = (int*)alloc(HW * 4);
    float* pdot = (float*)alloc((size_t)NCH_NEW * HW * 4);
    float* pa2  = (float*)alloc((size_t)NCH_NEW * HW * 4);
    float* pt2  = (float*)alloc((size_t)NCH_NEW * HW * 4);
    float* dT  = (float*)alloc((size_t)C * HW * 4);   // 12.6 MB
    float* bT  = (float*)alloc((size_t)C * HW * 4);   // 12.6 MB
    bool fast = off <= ws_size;                       // ~41 MB

    if (fast) {
        prep_kernel<<<dim3(HW / 64, C / 64), 256, 0, stream>>>(
            a, b, d, Ah, Bh, dT, bT, nbp, out);
        gemm_mfma_kernel<<<dim3(HW / 128, HW / 128), 256, 0, stream>>>(
            Ah, Bh, nbp, pv1, pi1, pv2, pi2);
        reduce_recheck_kernel<<<HW / 4, 256, 0, stream>>>(
            a, b, bT, 1, pv1, pi1, pv2, pi2, zb, out_zbest);
        gather_loss_kernel<<<dim3(HW / 64, NCH_NEW), 256, 0, stream>>>(
            a, dT, zb, out, pdot, pa2, pt2);
        loss_finalize_kernel<<<HW / 256, 256, 0, stream>>>(pdot, pa2, pt2, out, NCH_NEW);
    } else {
        // compact fp32 fallback
        off = 0;
        float* nb = (float*)alloc(HW * 4);
        nbp = (float*)alloc((size_t)NKB * HW * 4);
        pv1 = (float*)alloc((size_t)HW * NBN * 4);
        pi1 = (int*)alloc((size_t)HW * NBN * 4);
        zb  = (int*)alloc(HW * 4);
        float* pdot2 = (float*)alloc((size_t)NCH_OLD * HW * 4);
        float* pa22  = (float*)alloc((size_t)NCH_OLD * HW * 4);
        float* pt22  = (float*)alloc((size_t)NCH_OLD * HW * 4);
        hipMemsetAsync(d_out, 0, sizeof(float), stream);
        bnorm_partial_fb_kernel<<<dim3(HW / 256, NKB), 256, 0, stream>>>(b, nbp);
        bnorm_finalize_fb_kernel<<<HW / 256, 256, 0, stream>>>(nbp, nb);
        gemm_argmax_fb_kernel<<<dim3(HW / 128, HW / 128), 256, 0, stream>>>(a, b, nb, pv1, pi1);
        reduce_fb_kernel<<<HW / 256, 256, 0, stream>>>(pv1, pi1, zb, out_zbest);
        gather_partial_kernel<<<dim3(HW / 256, NCH_OLD), 256, 0, stream>>>(
            a, d, zb, out, pdot2, pa22, pt22);
        loss_finalize_kernel<<<HW / 256, 256, 0, stream>>>(pdot2, pa22, pt22, out, NCH_OLD);
    }
}